// Round 7
// baseline (1318.941 us; speedup 1.0000x reference)
//
#include <hip/hip_runtime.h>
#include <hip/hip_bf16.h>

typedef __hip_bfloat16 bf16;
typedef unsigned short u16;
typedef __attribute__((ext_vector_type(8))) short s8v;   // 8 bf16 = 4 VGPR
typedef __attribute__((ext_vector_type(4))) float f4v;   // MFMA accumulator

#define MFMA16(a, b, c) __builtin_amdgcn_mfma_f32_16x16x32_bf16((a), (b), (c), 0, 0, 0)

__device__ __forceinline__ float b2f(bf16 v) { return __bfloat162float(v); }
__device__ __forceinline__ float sigm(float x) { return 1.0f / (1.0f + __expf(-x)); }
__device__ __forceinline__ float u2f(u16 u) {
  union { float f; unsigned int i; } v; v.i = ((unsigned int)u) << 16; return v.f;
}
__device__ __forceinline__ u16 f2u(float f) {
  bf16 b = __float2bfloat16(f);
  union { bf16 b; u16 u; } v; v.b = b; return v.u;
}

// async global -> LDS, 16B per lane (global_load_lds_dwordx4)
__device__ __forceinline__ void gl16(void* lds, const void* g) {
  __builtin_amdgcn_global_load_lds(
      (const __attribute__((address_space(1))) unsigned int*)g,
      (__attribute__((address_space(3))) unsigned int*)lds, 16, 0, 0);
}

// ---------------- small utility kernels ----------------
__global__ __launch_bounds__(256) void k_cast(const float* __restrict__ s,
                                              bf16* __restrict__ d, int n) {
  int i = blockIdx.x * 256 + threadIdx.x;
  if (i < n) d[i] = __float2bfloat16(s[i]);
}

__global__ __launch_bounds__(256) void k_embed(const int* __restrict__ x,
                                               const float* __restrict__ emb,
                                               bf16* __restrict__ h, int N, int H) {
  int idx = blockIdx.x * 256 + threadIdx.x;
  if (idx >= N * H) return;
  int n = idx / H, c = idx - n * H;
  h[idx] = __float2bfloat16(emb[(size_t)x[n] * H + c]);
}

// catA[r][k] = k<H ? h[gidx[r]][k] : bf16(enc[r][k-H])
__global__ __launch_bounds__(256) void k_cat(const bf16* __restrict__ h,
                                             const int* __restrict__ gidx,
                                             const float* __restrict__ enc,
                                             bf16* __restrict__ catA, int BL, int H) {
  int i = blockIdx.x * 256 + threadIdx.x;
  if (i >= BL * 2 * H) return;
  int r = i / (2 * H), k = i - r * 2 * H;
  catA[i] = (k < H) ? h[(size_t)gidx[r] * H + k]
                    : __float2bfloat16(enc[(size_t)r * H + (k - H)]);
}

// ---------------- CSR build (once per call) ----------------
__global__ __launch_bounds__(256) void k_zero_i32(int* __restrict__ p, int n) {
  int i = blockIdx.x * 256 + threadIdx.x;
  if (i < n) p[i] = 0;
}
__global__ __launch_bounds__(256) void k_hist(const int* __restrict__ ei,
                                              int* __restrict__ deg, int E) {
  int e = blockIdx.x * 256 + threadIdx.x;
  if (e < E) atomicAdd(&deg[ei[E + e]], 1);
}

// hierarchical exclusive scan of deg[N] -> rowptr[N+1] and cursor[N]
__global__ __launch_bounds__(256) void k_scan1(const int* __restrict__ deg,
                                               int* __restrict__ bsum, int N) {
  int t = threadIdx.x;
  int i = blockIdx.x * 256 + t;
  int v = (i < N) ? deg[i] : 0;
#pragma unroll
  for (int o = 32; o > 0; o >>= 1) v += __shfl_down(v, o, 64);
  __shared__ int ws[4];
  if ((t & 63) == 0) ws[t >> 6] = v;
  __syncthreads();
  if (t == 0) bsum[blockIdx.x] = ws[0] + ws[1] + ws[2] + ws[3];
}
__global__ __launch_bounds__(256) void k_scan2(const int* __restrict__ bsum,
                                               int* __restrict__ boff, int nb) {
  __shared__ int s[256];
  int t = threadIdx.x;
  int carry = 0;
  for (int base = 0; base < nb; base += 256) {
    int v = (base + t < nb) ? bsum[base + t] : 0;
    s[t] = v;
    __syncthreads();
    for (int o = 1; o < 256; o <<= 1) {
      int u = (t >= o) ? s[t - o] : 0;
      __syncthreads();
      s[t] += u;
      __syncthreads();
    }
    if (base + t < nb) boff[base + t] = carry + s[t] - v;
    carry += s[255];
    __syncthreads();
  }
}
__global__ __launch_bounds__(256) void k_scan3(const int* __restrict__ deg,
                                               const int* __restrict__ boff,
                                               int* __restrict__ rowptr,
                                               int* __restrict__ cursor, int N) {
  __shared__ int s[256];
  int t = threadIdx.x;
  int i = blockIdx.x * 256 + t;
  int v = (i < N) ? deg[i] : 0;
  s[t] = v;
  __syncthreads();
  for (int o = 1; o < 256; o <<= 1) {
    int u = (t >= o) ? s[t - o] : 0;
    __syncthreads();
    s[t] += u;
    __syncthreads();
  }
  int ex = boff[blockIdx.x] + s[t] - v;
  if (i < N) { rowptr[i] = ex; cursor[i] = ex; }
  if (i == N - 1) rowptr[N] = ex + v;
}

__global__ __launch_bounds__(256) void k_fill(const int* __restrict__ ei,
                                              const float* __restrict__ ew,
                                              int* __restrict__ cursor,
                                              int* __restrict__ srcs,
                                              float* __restrict__ wts, int E) {
  int e = blockIdx.x * 256 + threadIdx.x;
  if (e >= E) return;
  int d = ei[E + e];
  int pos = atomicAdd(&cursor[d], 1);
  srcs[pos] = ei[e];
  wts[pos] = ew[e];
}

// sh[d][:] = sum_e wts[e] * h[srcs[e]][:]
__global__ __launch_bounds__(256) void k_aggregate(const int* __restrict__ rowptr,
                                                   const int* __restrict__ srcs,
                                                   const float* __restrict__ wts,
                                                   const bf16* __restrict__ hsrc,
                                                   bf16* __restrict__ sh,
                                                   int N, int H) {
  int wv = threadIdx.x >> 6, lane = threadIdx.x & 63;
  int d = blockIdx.x * 4 + wv;
  if (d >= N) return;
  int beg = rowptr[d], end = rowptr[d + 1];
  const u16* hp = (const u16*)hsrc;
  for (int c0 = lane * 4; c0 < H; c0 += 256) {
    float a0 = 0.f, a1 = 0.f, a2 = 0.f, a3 = 0.f;
    int i = beg;
    for (; i + 4 <= end; i += 4) {
      int s0 = srcs[i], s1 = srcs[i + 1], s2 = srcs[i + 2], s3 = srcs[i + 3];
      float w0 = wts[i], w1 = wts[i + 1], w2 = wts[i + 2], w3 = wts[i + 3];
      ushort4 r0 = *(const ushort4*)(hp + (size_t)s0 * H + c0);
      ushort4 r1 = *(const ushort4*)(hp + (size_t)s1 * H + c0);
      ushort4 r2 = *(const ushort4*)(hp + (size_t)s2 * H + c0);
      ushort4 r3 = *(const ushort4*)(hp + (size_t)s3 * H + c0);
      a0 += w0 * u2f(r0.x) + w1 * u2f(r1.x) + w2 * u2f(r2.x) + w3 * u2f(r3.x);
      a1 += w0 * u2f(r0.y) + w1 * u2f(r1.y) + w2 * u2f(r2.y) + w3 * u2f(r3.y);
      a2 += w0 * u2f(r0.z) + w1 * u2f(r1.z) + w2 * u2f(r2.z) + w3 * u2f(r3.z);
      a3 += w0 * u2f(r0.w) + w1 * u2f(r1.w) + w2 * u2f(r2.w) + w3 * u2f(r3.w);
    }
    for (; i < end; i++) {
      int s0 = srcs[i];
      float w0 = wts[i];
      ushort4 r0 = *(const ushort4*)(hp + (size_t)s0 * H + c0);
      a0 += w0 * u2f(r0.x); a1 += w0 * u2f(r0.y);
      a2 += w0 * u2f(r0.z); a3 += w0 * u2f(r0.w);
    }
    ushort4 o;
    o.x = f2u(a0); o.y = f2u(a1); o.z = f2u(a2); o.w = f2u(a3);
    *(ushort4*)((u16*)sh + (size_t)d * H + c0) = o;
  }
}

// ---------------- MFMA GEMM: C[M,Nc] = A[M,K] @ Bt[Nc,K]^T ----------------
template <int OUT_F32>
__global__ __launch_bounds__(256) void k_gemm(const bf16* __restrict__ A,
                                              const bf16* __restrict__ Bt,
                                              void* __restrict__ Cv,
                                              const float* __restrict__ bias,
                                              int M, int K, int Nc,
                                              size_t sBt, size_t sC) {
  __shared__ short As[128][40];
  __shared__ short Bs[64][40];
  int gm = blockIdx.x * 128, gn = blockIdx.y * 64;
  Bt += (size_t)blockIdx.z * sBt;
  size_t zc = (size_t)blockIdx.z * sC;
  int tid = threadIdx.x, w = tid >> 6, lane = tid & 63;
  int l15 = lane & 15, koff = (lane >> 4) * 8;
  f4v acc[2][4];
#pragma unroll
  for (int i = 0; i < 2; i++)
#pragma unroll
    for (int j = 0; j < 4; j++) acc[i][j] = (f4v)0.f;

  for (int kt = 0; kt < K; kt += 32) {
#pragma unroll
    for (int c = 0; c < 2; c++) {
      int ch = tid + c * 256;
      int row = ch >> 2, seg = ch & 3;
      *(float4*)&As[row][seg * 8] =
          *(const float4*)(A + (size_t)(gm + row) * K + kt + seg * 8);
    }
    {
      int row = tid >> 2, seg = tid & 3;
      *(float4*)&Bs[row][seg * 8] =
          *(const float4*)(Bt + (size_t)(gn + row) * K + kt + seg * 8);
    }
    __syncthreads();
    s8v af[2], bf[4];
#pragma unroll
    for (int rt = 0; rt < 2; rt++) af[rt] = *(const s8v*)&As[w * 32 + rt * 16 + l15][koff];
#pragma unroll
    for (int ct = 0; ct < 4; ct++) bf[ct] = *(const s8v*)&Bs[ct * 16 + l15][koff];
#pragma unroll
    for (int rt = 0; rt < 2; rt++)
#pragma unroll
      for (int ct = 0; ct < 4; ct++) acc[rt][ct] = MFMA16(af[rt], bf[ct], acc[rt][ct]);
    __syncthreads();
  }
#pragma unroll
  for (int rt = 0; rt < 2; rt++)
#pragma unroll
    for (int ct = 0; ct < 4; ct++)
#pragma unroll
      for (int r = 0; r < 4; r++) {
        int row = gm + w * 32 + rt * 16 + (lane >> 4) * 4 + r;
        int col = gn + ct * 16 + l15;
        float v = acc[rt][ct][r];
        if (OUT_F32) ((float*)Cv)[zc + (size_t)row * Nc + col] = v + bias[col];
        else         ((bf16*)Cv)[zc + (size_t)row * Nc + col] = __float2bfloat16(v);
      }
}

// ---------------- fused GRU: B-only LDS staging, A/H direct from L2 ---------
// LDS-volume analysis (r6): kernel is LDS-read-bound; A/H fragments are
// wave-exclusive rows and L2-resident (T1 swizzle) -> read them straight from
// global into registers (16B/lane; the 4 lane-quartiles of a row cover one
// 64B line -> coalesced). Only the wave-shared B tile (6 mats) stays in LDS.
// LDS 80->48 KB -> 3 blocks/CU. Register-double-buffered fa/fh across the
// proven 2-phase loop. Bank-conflict counter = inherent b128 phases; no swizzle.
#define GRU_STAGE_B(Barr, kt)                             \
  {                                                       \
    gl16(&Barr[tid * 8],            BiP + (kt));          \
    gl16(&Barr[2048 + tid * 8],     BiP + HH + (kt));     \
    gl16(&Barr[2 * 2048 + tid * 8], BiP + 2 * HH + (kt)); \
    gl16(&Barr[3 * 2048 + tid * 8], BhP + (kt));          \
    gl16(&Barr[4 * 2048 + tid * 8], BhP + HH + (kt));     \
    gl16(&Barr[5 * 2048 + tid * 8], BhP + 2 * HH + (kt)); \
  }

#define GRU_LOADA(fa, fh, kt)                             \
  {                                                       \
    fa[0] = *(const s8v*)(ApF + (kt));                    \
    fa[1] = *(const s8v*)(ApF + rtF + (kt));              \
    fh[0] = *(const s8v*)(HpF + (kt));                    \
    fh[1] = *(const s8v*)(HpF + rtF + (kt));              \
  }

#define GRU_COMPUTE(Barr, fa, fh)                                           \
  {                                                                         \
    _Pragma("unroll")                                                       \
    for (int ct = 0; ct < 4; ct++) {                                        \
      int brow = (ct * 16 + l15) * 32 + koff;                               \
      s8v bRi = *(const s8v*)&Barr[brow];                                   \
      s8v bZi = *(const s8v*)&Barr[2048 + brow];                            \
      s8v bNi = *(const s8v*)&Barr[2 * 2048 + brow];                        \
      s8v bRh = *(const s8v*)&Barr[3 * 2048 + brow];                        \
      s8v bZh = *(const s8v*)&Barr[4 * 2048 + brow];                        \
      s8v bNh = *(const s8v*)&Barr[5 * 2048 + brow];                        \
      _Pragma("unroll")                                                     \
      for (int rt = 0; rt < 2; rt++) {                                      \
        accR[rt][ct]  = MFMA16(fa[rt], bRi, accR[rt][ct]);                  \
        accR[rt][ct]  = MFMA16(fh[rt], bRh, accR[rt][ct]);                  \
        accZ[rt][ct]  = MFMA16(fa[rt], bZi, accZ[rt][ct]);                  \
        accZ[rt][ct]  = MFMA16(fh[rt], bZh, accZ[rt][ct]);                  \
        accNi[rt][ct] = MFMA16(fa[rt], bNi, accNi[rt][ct]);                 \
        accNh[rt][ct] = MFMA16(fh[rt], bNh, accNh[rt][ct]);                 \
      }                                                                     \
    }                                                                       \
  }

__global__ __launch_bounds__(256, 3) void k_gru_mfma(const bf16* __restrict__ Ash,
                                                     const bf16* __restrict__ Ah,
                                                     const bf16* __restrict__ Wi,  // Ucomb_l [3H][H]
                                                     const bf16* __restrict__ Wh,  // w_hh [3H][H]
                                                     const float* __restrict__ bi,
                                                     const float* __restrict__ bh,
                                                     bf16* __restrict__ hn,
                                                     int M, int H) {
  __shared__ __align__(16) short Bs0[6 * 64 * 32], Bs1[6 * 64 * 32];

  // XCD-chunked bijective swizzle (grid is 1D: nwgx * nwgy blocks)
  int nwgx = H >> 6;                      // gcol blocks (4)
  int nwg = gridDim.x;
  int bid = blockIdx.x;
  int wg = bid;
  if ((nwg & 7) == 0) { int cpx = nwg >> 3; wg = (bid & 7) * cpx + (bid >> 3); }
  int gcol = (wg % nwgx) * 64;
  int gm = (wg / nwgx) * 128;

  int tid = threadIdx.x, w = tid >> 6, lane = tid & 63;
  int l15 = lane & 15, koff = (lane >> 4) * 8;
  f4v accR[2][4], accZ[2][4], accNi[2][4], accNh[2][4];
#pragma unroll
  for (int rt = 0; rt < 2; rt++)
#pragma unroll
    for (int ct = 0; ct < 4; ct++) {
      accR[rt][ct] = (f4v)0.f; accZ[rt][ct] = (f4v)0.f;
      accNi[rt][ct] = (f4v)0.f; accNh[rt][ct] = (f4v)0.f;
    }

  // B staging source pointers (per-lane, 16B slots; row = tid>>2, seg = tid&3)
  int arow = tid >> 2, aseg = tid & 3;
  const bf16* BiP = Wi + (size_t)(gcol + arow) * H + aseg * 8;
  const bf16* BhP = Wh + (size_t)(gcol + arow) * H + aseg * 8;
  size_t HH = (size_t)H * H;

  // A/H fragment pointers (per-lane; row = gm + w*32 + l15, 16B at koff)
  const bf16* ApF = Ash + (size_t)(gm + w * 32 + l15) * H + koff;
  const bf16* HpF = Ah  + (size_t)(gm + w * 32 + l15) * H + koff;
  size_t rtF = (size_t)16 * H;            // rt row-tile stride

  int nk = H >> 5;                        // K-steps (8)
  s8v faA[2], fhA[2], faB[2], fhB[2];

  GRU_STAGE_B(Bs0, 0);
  GRU_LOADA(faA, fhA, 0);
  __syncthreads();                        // drains vmcnt: tile 0 + frags ready
  for (int t = 0; t < nk; t += 2) {
    int kt = t << 5;
    if (t + 1 < nk) { GRU_STAGE_B(Bs1, kt + 32); GRU_LOADA(faB, fhB, kt + 32); }
    GRU_COMPUTE(Bs0, faA, fhA);           // overlaps with in-flight loads
    __syncthreads();
    if (t + 2 < nk) { GRU_STAGE_B(Bs0, kt + 64); GRU_LOADA(faA, fhA, kt + 64); }
    if (t + 1 < nk) GRU_COMPUTE(Bs1, faB, fhB);
    __syncthreads();
  }

#pragma unroll
  for (int ct = 0; ct < 4; ct++) {
    int col = gcol + ct * 16 + l15;
    float br  = bi[col] + bh[col];
    float bz  = bi[H + col] + bh[H + col];
    float bin = bi[2 * H + col], bhn = bh[2 * H + col];
#pragma unroll
    for (int rt = 0; rt < 2; rt++)
#pragma unroll
      for (int r = 0; r < 4; r++) {
        int row = gm + w * 32 + rt * 16 + (lane >> 4) * 4 + r;
        float rr = sigm(accR[rt][ct][r] + br);
        float zz = sigm(accZ[rt][ct][r] + bz);
        float nn = tanhf(accNi[rt][ct][r] + bin + rr * (accNh[rt][ct][r] + bhn));
        float hv = b2f(Ah[(size_t)row * H + col]);
        hn[(size_t)row * H + col] = __float2bfloat16((1.f - zz) * nn + zz * hv);
      }
  }
}

static inline size_t alg(size_t x) { return (x + 255) & ~(size_t)255; }
static inline int cdiv(int a, int b) { return (a + b - 1) / b; }

extern "C" void kernel_launch(void* const* d_in, const int* in_sizes, int n_in,
                              void* d_out, int out_size, void* d_ws, size_t ws_size,
                              hipStream_t stream) {
  (void)out_size; (void)ws_size;
  int s = (n_in >= 14) ? 0 : -1;
  const int*   x     = (const int*)d_in[0];
  const int*   ei    = (const int*)d_in[1];
  const float* ew    = (const float*)d_in[2];
  const int*   gidx  = (const int*)d_in[3];
  const float* enc   = (const float*)d_in[5 + s];
  const float* emb   = (const float*)d_in[6 + s];
  const float* ggcw  = (const float*)d_in[7 + s];
  const float* w_ih  = (const float*)d_in[8 + s];
  const float* w_hh  = (const float*)d_in[9 + s];
  const float* b_ih  = (const float*)d_in[10 + s];
  const float* b_hh  = (const float*)d_in[11 + s];
  const float* out_w = (const float*)d_in[12 + s];
  const float* out_b = (const float*)d_in[13 + s];
  float* out = (float*)d_out;

  int N   = in_sizes[0];
  int E   = in_sizes[2];
  int BL  = in_sizes[3];
  int H   = in_sizes[5 + s] / BL;
  int LG  = in_sizes[7 + s] / (H * H);
  int OUT = in_sizes[12 + s] / (2 * H);

  size_t nh = (size_t)N * H;
  size_t hh3 = (size_t)3 * H * H;
  int nb = cdiv(N, 256);
  char* p = (char*)d_ws;
  size_t off = 0;
  bf16* wihB  = (bf16*)(p + off); off = alg(off + hh3 * 2);
  bf16* whhB  = (bf16*)(p + off); off = alg(off + hh3 * 2);
  bf16* outwB = (bf16*)(p + off); off = alg(off + (size_t)OUT * 2 * H * 2);
  bf16* ggcwB = (bf16*)(p + off); off = alg(off + (size_t)LG * H * H * 2);
  bf16* Ucomb = (bf16*)(p + off); off = alg(off + (size_t)LG * hh3 * 2);
  bf16* hA    = (bf16*)(p + off); off = alg(off + nh * 2);
  bf16* hB    = (bf16*)(p + off); off = alg(off + nh * 2);
  bf16* shB   = (bf16*)(p + off); off = alg(off + nh * 2);
  bf16* catA  = (bf16*)(p + off); off = alg(off + (size_t)BL * 2 * H * 2);
  int* deg    = (int*)(p + off);  off = alg(off + (size_t)N * 4);
  int* rowptr = (int*)(p + off);  off = alg(off + (size_t)(N + 1) * 4);
  int* cursor = (int*)(p + off);  off = alg(off + (size_t)N * 4);
  int* srcs   = (int*)(p + off);  off = alg(off + (size_t)E * 4);
  float* wts  = (float*)(p + off); off = alg(off + (size_t)E * 4);
  int* bsum   = (int*)(p + off);  off = alg(off + (size_t)nb * 4);
  int* boff   = (int*)(p + off);  off = alg(off + (size_t)nb * 4);

  // weight prep
  k_cast<<<cdiv((int)hh3, 256), 256, 0, stream>>>(w_ih, wihB, (int)hh3);
  k_cast<<<cdiv((int)hh3, 256), 256, 0, stream>>>(w_hh, whhB, (int)hh3);
  k_cast<<<cdiv(OUT * 2 * H, 256), 256, 0, stream>>>(out_w, outwB, OUT * 2 * H);
  k_cast<<<cdiv(LG * H * H, 256), 256, 0, stream>>>(ggcw, ggcwB, LG * H * H);
  // Ucomb_l[c][k] = sum_p w_ih[c][p] * ggcw_l[k][p] -- all LG layers in ONE launch
  k_gemm<0><<<dim3(3 * H / 128, H / 64, LG), 256, 0, stream>>>(
      wihB, ggcwB, Ucomb, nullptr, 3 * H, H, H, (size_t)H * H, hh3);

  // embedding + CSR build (parallel hierarchical scan)
  k_embed<<<cdiv(N * H, 256), 256, 0, stream>>>(x, emb, hA, N, H);
  k_zero_i32<<<cdiv(N, 256), 256, 0, stream>>>(deg, N);
  k_hist<<<cdiv(E, 256), 256, 0, stream>>>(ei, deg, E);
  k_scan1<<<nb, 256, 0, stream>>>(deg, bsum, N);
  k_scan2<<<1, 256, 0, stream>>>(bsum, boff, nb);
  k_scan3<<<nb, 256, 0, stream>>>(deg, boff, rowptr, cursor, N);
  k_fill<<<cdiv(E, 256), 256, 0, stream>>>(ei, ew, cursor, srcs, wts, E);

  bf16* h = hA;
  bf16* hn = hB;
  for (int l = 0; l < LG; l++) {
    k_aggregate<<<cdiv(N, 4), 256, 0, stream>>>(rowptr, srcs, wts, h, shB, N, H);
    k_gru_mfma<<<dim3((H / 64) * (N / 128)), 256, 0, stream>>>(
        shB, h, Ucomb + (size_t)l * hh3, whhB, b_ih, b_hh, hn, N, H);
    bf16* t = h; h = hn; hn = t;
  }
  k_cat<<<cdiv(BL * 2 * H, 256), 256, 0, stream>>>(h, gidx, enc, catA, BL, H);
  k_gemm<1><<<dim3(BL / 128, OUT / 64, 1), 256, 0, stream>>>(
      catA, outwB, out, out_b, BL, 2 * H, OUT, 0, 0);
}

// Round 8
// 935.767 us; speedup vs baseline: 1.4095x; 1.4095x over previous
//
#include <hip/hip_runtime.h>
#include <hip/hip_bf16.h>

typedef __hip_bfloat16 bf16;
typedef unsigned short u16;
typedef __attribute__((ext_vector_type(8))) short s8v;   // 8 bf16 = 4 VGPR
typedef __attribute__((ext_vector_type(4))) float f4v;   // MFMA accumulator

#define MFMA16(a, b, c) __builtin_amdgcn_mfma_f32_16x16x32_bf16((a), (b), (c), 0, 0, 0)

__device__ __forceinline__ float b2f(bf16 v) { return __bfloat162float(v); }
__device__ __forceinline__ float sigm(float x) { return 1.0f / (1.0f + __expf(-x)); }
__device__ __forceinline__ float u2f(u16 u) {
  union { float f; unsigned int i; } v; v.i = ((unsigned int)u) << 16; return v.f;
}
__device__ __forceinline__ u16 f2u(float f) {
  bf16 b = __float2bfloat16(f);
  union { bf16 b; u16 u; } v; v.b = b; return v.u;
}

// async global -> LDS, 16B per lane (global_load_lds_dwordx4)
__device__ __forceinline__ void gl16(void* lds, const void* g) {
  __builtin_amdgcn_global_load_lds(
      (const __attribute__((address_space(1))) unsigned int*)g,
      (__attribute__((address_space(3))) unsigned int*)lds, 16, 0, 0);
}

// ---------------- small utility kernels ----------------
__global__ __launch_bounds__(256) void k_cast(const float* __restrict__ s,
                                              bf16* __restrict__ d, int n) {
  int i = blockIdx.x * 256 + threadIdx.x;
  if (i < n) d[i] = __float2bfloat16(s[i]);
}

__global__ __launch_bounds__(256) void k_embed(const int* __restrict__ x,
                                               const float* __restrict__ emb,
                                               bf16* __restrict__ h, int N, int H) {
  int idx = blockIdx.x * 256 + threadIdx.x;
  if (idx >= N * H) return;
  int n = idx / H, c = idx - n * H;
  h[idx] = __float2bfloat16(emb[(size_t)x[n] * H + c]);
}

// catA[r][k] = k<H ? h[gidx[r]][k] : bf16(enc[r][k-H])
__global__ __launch_bounds__(256) void k_cat(const bf16* __restrict__ h,
                                             const int* __restrict__ gidx,
                                             const float* __restrict__ enc,
                                             bf16* __restrict__ catA, int BL, int H) {
  int i = blockIdx.x * 256 + threadIdx.x;
  if (i >= BL * 2 * H) return;
  int r = i / (2 * H), k = i - r * 2 * H;
  catA[i] = (k < H) ? h[(size_t)gidx[r] * H + k]
                    : __float2bfloat16(enc[(size_t)r * H + (k - H)]);
}

// ---------------- CSR build (once per call) ----------------
__global__ __launch_bounds__(256) void k_zero_i32(int* __restrict__ p, int n) {
  int i = blockIdx.x * 256 + threadIdx.x;
  if (i < n) p[i] = 0;
}
__global__ __launch_bounds__(256) void k_hist(const int* __restrict__ ei,
                                              int* __restrict__ deg, int E) {
  int e = blockIdx.x * 256 + threadIdx.x;
  if (e < E) atomicAdd(&deg[ei[E + e]], 1);
}

// hierarchical exclusive scan of deg[N] -> rowptr[N+1] and cursor[N]
__global__ __launch_bounds__(256) void k_scan1(const int* __restrict__ deg,
                                               int* __restrict__ bsum, int N) {
  int t = threadIdx.x;
  int i = blockIdx.x * 256 + t;
  int v = (i < N) ? deg[i] : 0;
#pragma unroll
  for (int o = 32; o > 0; o >>= 1) v += __shfl_down(v, o, 64);
  __shared__ int ws[4];
  if ((t & 63) == 0) ws[t >> 6] = v;
  __syncthreads();
  if (t == 0) bsum[blockIdx.x] = ws[0] + ws[1] + ws[2] + ws[3];
}
__global__ __launch_bounds__(256) void k_scan2(const int* __restrict__ bsum,
                                               int* __restrict__ boff, int nb) {
  __shared__ int s[256];
  int t = threadIdx.x;
  int carry = 0;
  for (int base = 0; base < nb; base += 256) {
    int v = (base + t < nb) ? bsum[base + t] : 0;
    s[t] = v;
    __syncthreads();
    for (int o = 1; o < 256; o <<= 1) {
      int u = (t >= o) ? s[t - o] : 0;
      __syncthreads();
      s[t] += u;
      __syncthreads();
    }
    if (base + t < nb) boff[base + t] = carry + s[t] - v;
    carry += s[255];
    __syncthreads();
  }
}
__global__ __launch_bounds__(256) void k_scan3(const int* __restrict__ deg,
                                               const int* __restrict__ boff,
                                               int* __restrict__ rowptr,
                                               int* __restrict__ cursor, int N) {
  __shared__ int s[256];
  int t = threadIdx.x;
  int i = blockIdx.x * 256 + t;
  int v = (i < N) ? deg[i] : 0;
  s[t] = v;
  __syncthreads();
  for (int o = 1; o < 256; o <<= 1) {
    int u = (t >= o) ? s[t - o] : 0;
    __syncthreads();
    s[t] += u;
    __syncthreads();
  }
  int ex = boff[blockIdx.x] + s[t] - v;
  if (i < N) { rowptr[i] = ex; cursor[i] = ex; }
  if (i == N - 1) rowptr[N] = ex + v;
}

__global__ __launch_bounds__(256) void k_fill(const int* __restrict__ ei,
                                              const float* __restrict__ ew,
                                              int* __restrict__ cursor,
                                              int* __restrict__ srcs,
                                              float* __restrict__ wts, int E) {
  int e = blockIdx.x * 256 + threadIdx.x;
  if (e >= E) return;
  int d = ei[E + e];
  int pos = atomicAdd(&cursor[d], 1);
  srcs[pos] = ei[e];
  wts[pos] = ew[e];
}

// sh[d][:] = sum_e wts[e] * h[srcs[e]][:]
__global__ __launch_bounds__(256) void k_aggregate(const int* __restrict__ rowptr,
                                                   const int* __restrict__ srcs,
                                                   const float* __restrict__ wts,
                                                   const bf16* __restrict__ hsrc,
                                                   bf16* __restrict__ sh,
                                                   int N, int H) {
  int wv = threadIdx.x >> 6, lane = threadIdx.x & 63;
  int d = blockIdx.x * 4 + wv;
  if (d >= N) return;
  int beg = rowptr[d], end = rowptr[d + 1];
  const u16* hp = (const u16*)hsrc;
  for (int c0 = lane * 4; c0 < H; c0 += 256) {
    float a0 = 0.f, a1 = 0.f, a2 = 0.f, a3 = 0.f;
    int i = beg;
    for (; i + 4 <= end; i += 4) {
      int s0 = srcs[i], s1 = srcs[i + 1], s2 = srcs[i + 2], s3 = srcs[i + 3];
      float w0 = wts[i], w1 = wts[i + 1], w2 = wts[i + 2], w3 = wts[i + 3];
      ushort4 r0 = *(const ushort4*)(hp + (size_t)s0 * H + c0);
      ushort4 r1 = *(const ushort4*)(hp + (size_t)s1 * H + c0);
      ushort4 r2 = *(const ushort4*)(hp + (size_t)s2 * H + c0);
      ushort4 r3 = *(const ushort4*)(hp + (size_t)s3 * H + c0);
      a0 += w0 * u2f(r0.x) + w1 * u2f(r1.x) + w2 * u2f(r2.x) + w3 * u2f(r3.x);
      a1 += w0 * u2f(r0.y) + w1 * u2f(r1.y) + w2 * u2f(r2.y) + w3 * u2f(r3.y);
      a2 += w0 * u2f(r0.z) + w1 * u2f(r1.z) + w2 * u2f(r2.z) + w3 * u2f(r3.z);
      a3 += w0 * u2f(r0.w) + w1 * u2f(r1.w) + w2 * u2f(r2.w) + w3 * u2f(r3.w);
    }
    for (; i < end; i++) {
      int s0 = srcs[i];
      float w0 = wts[i];
      ushort4 r0 = *(const ushort4*)(hp + (size_t)s0 * H + c0);
      a0 += w0 * u2f(r0.x); a1 += w0 * u2f(r0.y);
      a2 += w0 * u2f(r0.z); a3 += w0 * u2f(r0.w);
    }
    ushort4 o;
    o.x = f2u(a0); o.y = f2u(a1); o.z = f2u(a2); o.w = f2u(a3);
    *(ushort4*)((u16*)sh + (size_t)d * H + c0) = o;
  }
}

// ---------------- MFMA GEMM: C[M,Nc] = A[M,K] @ Bt[Nc,K]^T ----------------
template <int OUT_F32>
__global__ __launch_bounds__(256) void k_gemm(const bf16* __restrict__ A,
                                              const bf16* __restrict__ Bt,
                                              void* __restrict__ Cv,
                                              const float* __restrict__ bias,
                                              int M, int K, int Nc,
                                              size_t sBt, size_t sC) {
  __shared__ short As[128][40];
  __shared__ short Bs[64][40];
  int gm = blockIdx.x * 128, gn = blockIdx.y * 64;
  Bt += (size_t)blockIdx.z * sBt;
  size_t zc = (size_t)blockIdx.z * sC;
  int tid = threadIdx.x, w = tid >> 6, lane = tid & 63;
  int l15 = lane & 15, koff = (lane >> 4) * 8;
  f4v acc[2][4];
#pragma unroll
  for (int i = 0; i < 2; i++)
#pragma unroll
    for (int j = 0; j < 4; j++) acc[i][j] = (f4v)0.f;

  for (int kt = 0; kt < K; kt += 32) {
#pragma unroll
    for (int c = 0; c < 2; c++) {
      int ch = tid + c * 256;
      int row = ch >> 2, seg = ch & 3;
      *(float4*)&As[row][seg * 8] =
          *(const float4*)(A + (size_t)(gm + row) * K + kt + seg * 8);
    }
    {
      int row = tid >> 2, seg = tid & 3;
      *(float4*)&Bs[row][seg * 8] =
          *(const float4*)(Bt + (size_t)(gn + row) * K + kt + seg * 8);
    }
    __syncthreads();
    s8v af[2], bf[4];
#pragma unroll
    for (int rt = 0; rt < 2; rt++) af[rt] = *(const s8v*)&As[w * 32 + rt * 16 + l15][koff];
#pragma unroll
    for (int ct = 0; ct < 4; ct++) bf[ct] = *(const s8v*)&Bs[ct * 16 + l15][koff];
#pragma unroll
    for (int rt = 0; rt < 2; rt++)
#pragma unroll
      for (int ct = 0; ct < 4; ct++) acc[rt][ct] = MFMA16(af[rt], bf[ct], acc[rt][ct]);
    __syncthreads();
  }
#pragma unroll
  for (int rt = 0; rt < 2; rt++)
#pragma unroll
    for (int ct = 0; ct < 4; ct++)
#pragma unroll
      for (int r = 0; r < 4; r++) {
        int row = gm + w * 32 + rt * 16 + (lane >> 4) * 4 + r;
        int col = gn + ct * 16 + l15;
        float v = acc[rt][ct][r];
        if (OUT_F32) ((float*)Cv)[zc + (size_t)row * Nc + col] = v + bias[col];
        else         ((bf16*)Cv)[zc + (size_t)row * Nc + col] = __float2bfloat16(v);
      }
}

// ---------------- fused GRU: B-only LDS staging, A/H direct from L2 ---------
// r7 post-mortem: __launch_bounds__(256,3) capped unified regs at ~170 while
// live state = 128 acc f32 + ~100 arch -> allocator spilled to scratch ->
// 540 MB of HBM spill round-trip (WRITE_SIZE 370 MB), dur 88->210 us.
// Fix: (256,2) -> 256-reg cap, no spill. 128-f32 accumulators make 2 waves/EU
// this kernel's occupancy ceiling; never request 3.
// Structure otherwise: B tile (6 mats) in LDS via gl16; A/H fragments read
// directly from global (L2-resident thanks to T1 swizzle) into registers,
// double-buffered across the proven 2-phase loop.
#define GRU_STAGE_B(Barr, kt)                             \
  {                                                       \
    gl16(&Barr[tid * 8],            BiP + (kt));          \
    gl16(&Barr[2048 + tid * 8],     BiP + HH + (kt));     \
    gl16(&Barr[2 * 2048 + tid * 8], BiP + 2 * HH + (kt)); \
    gl16(&Barr[3 * 2048 + tid * 8], BhP + (kt));          \
    gl16(&Barr[4 * 2048 + tid * 8], BhP + HH + (kt));     \
    gl16(&Barr[5 * 2048 + tid * 8], BhP + 2 * HH + (kt)); \
  }

#define GRU_LOADA(fa, fh, kt)                             \
  {                                                       \
    fa[0] = *(const s8v*)(ApF + (kt));                    \
    fa[1] = *(const s8v*)(ApF + rtF + (kt));              \
    fh[0] = *(const s8v*)(HpF + (kt));                    \
    fh[1] = *(const s8v*)(HpF + rtF + (kt));              \
  }

#define GRU_COMPUTE(Barr, fa, fh)                                           \
  {                                                                         \
    _Pragma("unroll")                                                       \
    for (int ct = 0; ct < 4; ct++) {                                        \
      int brow = (ct * 16 + l15) * 32 + koff;                               \
      s8v bRi = *(const s8v*)&Barr[brow];                                   \
      s8v bZi = *(const s8v*)&Barr[2048 + brow];                            \
      s8v bNi = *(const s8v*)&Barr[2 * 2048 + brow];                        \
      s8v bRh = *(const s8v*)&Barr[3 * 2048 + brow];                        \
      s8v bZh = *(const s8v*)&Barr[4 * 2048 + brow];                        \
      s8v bNh = *(const s8v*)&Barr[5 * 2048 + brow];                        \
      _Pragma("unroll")                                                     \
      for (int rt = 0; rt < 2; rt++) {                                      \
        accR[rt][ct]  = MFMA16(fa[rt], bRi, accR[rt][ct]);                  \
        accR[rt][ct]  = MFMA16(fh[rt], bRh, accR[rt][ct]);                  \
        accZ[rt][ct]  = MFMA16(fa[rt], bZi, accZ[rt][ct]);                  \
        accZ[rt][ct]  = MFMA16(fh[rt], bZh, accZ[rt][ct]);                  \
        accNi[rt][ct] = MFMA16(fa[rt], bNi, accNi[rt][ct]);                 \
        accNh[rt][ct] = MFMA16(fh[rt], bNh, accNh[rt][ct]);                 \
      }                                                                     \
    }                                                                       \
  }

__global__ __launch_bounds__(256, 2) void k_gru_mfma(const bf16* __restrict__ Ash,
                                                     const bf16* __restrict__ Ah,
                                                     const bf16* __restrict__ Wi,  // Ucomb_l [3H][H]
                                                     const bf16* __restrict__ Wh,  // w_hh [3H][H]
                                                     const float* __restrict__ bi,
                                                     const float* __restrict__ bh,
                                                     bf16* __restrict__ hn,
                                                     int M, int H) {
  __shared__ __align__(16) short Bs0[6 * 64 * 32], Bs1[6 * 64 * 32];

  // XCD-chunked bijective swizzle (grid is 1D: nwgx * nwgy blocks)
  int nwgx = H >> 6;                      // gcol blocks (4)
  int nwg = gridDim.x;
  int bid = blockIdx.x;
  int wg = bid;
  if ((nwg & 7) == 0) { int cpx = nwg >> 3; wg = (bid & 7) * cpx + (bid >> 3); }
  int gcol = (wg % nwgx) * 64;
  int gm = (wg / nwgx) * 128;

  int tid = threadIdx.x, w = tid >> 6, lane = tid & 63;
  int l15 = lane & 15, koff = (lane >> 4) * 8;
  f4v accR[2][4], accZ[2][4], accNi[2][4], accNh[2][4];
#pragma unroll
  for (int rt = 0; rt < 2; rt++)
#pragma unroll
    for (int ct = 0; ct < 4; ct++) {
      accR[rt][ct] = (f4v)0.f; accZ[rt][ct] = (f4v)0.f;
      accNi[rt][ct] = (f4v)0.f; accNh[rt][ct] = (f4v)0.f;
    }

  // B staging source pointers (per-lane, 16B slots; row = tid>>2, seg = tid&3)
  int arow = tid >> 2, aseg = tid & 3;
  const bf16* BiP = Wi + (size_t)(gcol + arow) * H + aseg * 8;
  const bf16* BhP = Wh + (size_t)(gcol + arow) * H + aseg * 8;
  size_t HH = (size_t)H * H;

  // A/H fragment pointers (per-lane; row = gm + w*32 + l15, 16B at koff)
  const bf16* ApF = Ash + (size_t)(gm + w * 32 + l15) * H + koff;
  const bf16* HpF = Ah  + (size_t)(gm + w * 32 + l15) * H + koff;
  size_t rtF = (size_t)16 * H;            // rt row-tile stride

  int nk = H >> 5;                        // K-steps (8)
  s8v faA[2], fhA[2], faB[2], fhB[2];

  GRU_STAGE_B(Bs0, 0);
  GRU_LOADA(faA, fhA, 0);
  __syncthreads();                        // drains vmcnt: tile 0 + frags ready
  for (int t = 0; t < nk; t += 2) {
    int kt = t << 5;
    if (t + 1 < nk) { GRU_STAGE_B(Bs1, kt + 32); GRU_LOADA(faB, fhB, kt + 32); }
    GRU_COMPUTE(Bs0, faA, fhA);           // overlaps with in-flight loads
    __syncthreads();
    if (t + 2 < nk) { GRU_STAGE_B(Bs0, kt + 64); GRU_LOADA(faA, fhA, kt + 64); }
    if (t + 1 < nk) GRU_COMPUTE(Bs1, faB, fhB);
    __syncthreads();
  }

#pragma unroll
  for (int ct = 0; ct < 4; ct++) {
    int col = gcol + ct * 16 + l15;
    float br  = bi[col] + bh[col];
    float bz  = bi[H + col] + bh[H + col];
    float bin = bi[2 * H + col], bhn = bh[2 * H + col];
#pragma unroll
    for (int rt = 0; rt < 2; rt++)
#pragma unroll
      for (int r = 0; r < 4; r++) {
        int row = gm + w * 32 + rt * 16 + (lane >> 4) * 4 + r;
        float rr = sigm(accR[rt][ct][r] + br);
        float zz = sigm(accZ[rt][ct][r] + bz);
        float nn = tanhf(accNi[rt][ct][r] + bin + rr * (accNh[rt][ct][r] + bhn));
        float hv = b2f(Ah[(size_t)row * H + col]);
        hn[(size_t)row * H + col] = __float2bfloat16((1.f - zz) * nn + zz * hv);
      }
  }
}

static inline size_t alg(size_t x) { return (x + 255) & ~(size_t)255; }
static inline int cdiv(int a, int b) { return (a + b - 1) / b; }

extern "C" void kernel_launch(void* const* d_in, const int* in_sizes, int n_in,
                              void* d_out, int out_size, void* d_ws, size_t ws_size,
                              hipStream_t stream) {
  (void)out_size; (void)ws_size;
  int s = (n_in >= 14) ? 0 : -1;
  const int*   x     = (const int*)d_in[0];
  const int*   ei    = (const int*)d_in[1];
  const float* ew    = (const float*)d_in[2];
  const int*   gidx  = (const int*)d_in[3];
  const float* enc   = (const float*)d_in[5 + s];
  const float* emb   = (const float*)d_in[6 + s];
  const float* ggcw  = (const float*)d_in[7 + s];
  const float* w_ih  = (const float*)d_in[8 + s];
  const float* w_hh  = (const float*)d_in[9 + s];
  const float* b_ih  = (const float*)d_in[10 + s];
  const float* b_hh  = (const float*)d_in[11 + s];
  const float* out_w = (const float*)d_in[12 + s];
  const float* out_b = (const float*)d_in[13 + s];
  float* out = (float*)d_out;

  int N   = in_sizes[0];
  int E   = in_sizes[2];
  int BL  = in_sizes[3];
  int H   = in_sizes[5 + s] / BL;
  int LG  = in_sizes[7 + s] / (H * H);
  int OUT = in_sizes[12 + s] / (2 * H);

  size_t nh = (size_t)N * H;
  size_t hh3 = (size_t)3 * H * H;
  int nb = cdiv(N, 256);
  char* p = (char*)d_ws;
  size_t off = 0;
  bf16* wihB  = (bf16*)(p + off); off = alg(off + hh3 * 2);
  bf16* whhB  = (bf16*)(p + off); off = alg(off + hh3 * 2);
  bf16* outwB = (bf16*)(p + off); off = alg(off + (size_t)OUT * 2 * H * 2);
  bf16* ggcwB = (bf16*)(p + off); off = alg(off + (size_t)LG * H * H * 2);
  bf16* Ucomb = (bf16*)(p + off); off = alg(off + (size_t)LG * hh3 * 2);
  bf16* hA    = (bf16*)(p + off); off = alg(off + nh * 2);
  bf16* hB    = (bf16*)(p + off); off = alg(off + nh * 2);
  bf16* shB   = (bf16*)(p + off); off = alg(off + nh * 2);
  bf16* catA  = (bf16*)(p + off); off = alg(off + (size_t)BL * 2 * H * 2);
  int* deg    = (int*)(p + off);  off = alg(off + (size_t)N * 4);
  int* rowptr = (int*)(p + off);  off = alg(off + (size_t)(N + 1) * 4);
  int* cursor = (int*)(p + off);  off = alg(off + (size_t)N * 4);
  int* srcs   = (int*)(p + off);  off = alg(off + (size_t)E * 4);
  float* wts  = (float*)(p + off); off = alg(off + (size_t)E * 4);
  int* bsum   = (int*)(p + off);  off = alg(off + (size_t)nb * 4);
  int* boff   = (int*)(p + off);  off = alg(off + (size_t)nb * 4);

  // weight prep
  k_cast<<<cdiv((int)hh3, 256), 256, 0, stream>>>(w_ih, wihB, (int)hh3);
  k_cast<<<cdiv((int)hh3, 256), 256, 0, stream>>>(w_hh, whhB, (int)hh3);
  k_cast<<<cdiv(OUT * 2 * H, 256), 256, 0, stream>>>(out_w, outwB, OUT * 2 * H);
  k_cast<<<cdiv(LG * H * H, 256), 256, 0, stream>>>(ggcw, ggcwB, LG * H * H);
  // Ucomb_l[c][k] = sum_p w_ih[c][p] * ggcw_l[k][p] -- all LG layers in ONE launch
  k_gemm<0><<<dim3(3 * H / 128, H / 64, LG), 256, 0, stream>>>(
      wihB, ggcwB, Ucomb, nullptr, 3 * H, H, H, (size_t)H * H, hh3);

  // embedding + CSR build (parallel hierarchical scan)
  k_embed<<<cdiv(N * H, 256), 256, 0, stream>>>(x, emb, hA, N, H);
  k_zero_i32<<<cdiv(N, 256), 256, 0, stream>>>(deg, N);
  k_hist<<<cdiv(E, 256), 256, 0, stream>>>(ei, deg, E);
  k_scan1<<<nb, 256, 0, stream>>>(deg, bsum, N);
  k_scan2<<<1, 256, 0, stream>>>(bsum, boff, nb);
  k_scan3<<<nb, 256, 0, stream>>>(deg, boff, rowptr, cursor, N);
  k_fill<<<cdiv(E, 256), 256, 0, stream>>>(ei, ew, cursor, srcs, wts, E);

  bf16* h = hA;
  bf16* hn = hB;
  for (int l = 0; l < LG; l++) {
    k_aggregate<<<cdiv(N, 4), 256, 0, stream>>>(rowptr, srcs, wts, h, shB, N, H);
    k_gru_mfma<<<dim3((H / 64) * (N / 128)), 256, 0, stream>>>(
        shB, h, Ucomb + (size_t)l * hh3, whhB, b_ih, b_hh, hn, N, H);
    bf16* t = h; h = hn; hn = t;
  }
  k_cat<<<cdiv(BL * 2 * H, 256), 256, 0, stream>>>(h, gidx, enc, catA, BL, H);
  k_gemm<1><<<dim3(BL / 128, OUT / 64, 1), 256, 0, stream>>>(
      catA, outwB, out, out_b, BL, 2 * H, OUT, 0, 0);
}

// Round 9
// 892.621 us; speedup vs baseline: 1.4776x; 1.0483x over previous
//
#include <hip/hip_runtime.h>
#include <hip/hip_bf16.h>

typedef __hip_bfloat16 bf16;
typedef unsigned short u16;
typedef __attribute__((ext_vector_type(8))) short s8v;   // 8 bf16 = 4 VGPR
typedef __attribute__((ext_vector_type(4))) float f4v;   // MFMA accumulator

#define MFMA16(a, b, c) __builtin_amdgcn_mfma_f32_16x16x32_bf16((a), (b), (c), 0, 0, 0)

__device__ __forceinline__ float b2f(bf16 v) { return __bfloat162float(v); }
__device__ __forceinline__ float sigm(float x) { return 1.0f / (1.0f + __expf(-x)); }
// fast tanh: 2*sigmoid(2x)-1 (error ~1e-7, invisible at bf16 tolerance; ~8 VALU
// ops vs ocml tanhf's branchy ~30)
__device__ __forceinline__ float ftanh(float x) {
  return __builtin_fmaf(2.f, sigm(2.f * x), -1.f);
}
__device__ __forceinline__ float u2f(u16 u) {
  union { float f; unsigned int i; } v; v.i = ((unsigned int)u) << 16; return v.f;
}
__device__ __forceinline__ u16 f2u(float f) {
  bf16 b = __float2bfloat16(f);
  union { bf16 b; u16 u; } v; v.b = b; return v.u;
}

// async global -> LDS, 16B per lane (global_load_lds_dwordx4)
__device__ __forceinline__ void gl16(void* lds, const void* g) {
  __builtin_amdgcn_global_load_lds(
      (const __attribute__((address_space(1))) unsigned int*)g,
      (__attribute__((address_space(3))) unsigned int*)lds, 16, 0, 0);
}

// ---------------- small utility kernels ----------------
__global__ __launch_bounds__(256) void k_cast(const float* __restrict__ s,
                                              bf16* __restrict__ d, int n) {
  int i = blockIdx.x * 256 + threadIdx.x;
  if (i < n) d[i] = __float2bfloat16(s[i]);
}

__global__ __launch_bounds__(256) void k_embed(const int* __restrict__ x,
                                               const float* __restrict__ emb,
                                               bf16* __restrict__ h, int N, int H) {
  int idx = blockIdx.x * 256 + threadIdx.x;
  if (idx >= N * H) return;
  int n = idx / H, c = idx - n * H;
  h[idx] = __float2bfloat16(emb[(size_t)x[n] * H + c]);
}

// catA[r][k] = k<H ? h[gidx[r]][k] : bf16(enc[r][k-H])
__global__ __launch_bounds__(256) void k_cat(const bf16* __restrict__ h,
                                             const int* __restrict__ gidx,
                                             const float* __restrict__ enc,
                                             bf16* __restrict__ catA, int BL, int H) {
  int i = blockIdx.x * 256 + threadIdx.x;
  if (i >= BL * 2 * H) return;
  int r = i / (2 * H), k = i - r * 2 * H;
  catA[i] = (k < H) ? h[(size_t)gidx[r] * H + k]
                    : __float2bfloat16(enc[(size_t)r * H + (k - H)]);
}

// ---------------- CSR build (once per call) ----------------
__global__ __launch_bounds__(256) void k_zero_i32(int* __restrict__ p, int n) {
  int i = blockIdx.x * 256 + threadIdx.x;
  if (i < n) p[i] = 0;
}
__global__ __launch_bounds__(256) void k_hist(const int* __restrict__ ei,
                                              int* __restrict__ deg, int E) {
  int e = blockIdx.x * 256 + threadIdx.x;
  if (e < E) atomicAdd(&deg[ei[E + e]], 1);
}

// hierarchical exclusive scan of deg[N] -> rowptr[N+1] and cursor[N]
__global__ __launch_bounds__(256) void k_scan1(const int* __restrict__ deg,
                                               int* __restrict__ bsum, int N) {
  int t = threadIdx.x;
  int i = blockIdx.x * 256 + t;
  int v = (i < N) ? deg[i] : 0;
#pragma unroll
  for (int o = 32; o > 0; o >>= 1) v += __shfl_down(v, o, 64);
  __shared__ int ws[4];
  if ((t & 63) == 0) ws[t >> 6] = v;
  __syncthreads();
  if (t == 0) bsum[blockIdx.x] = ws[0] + ws[1] + ws[2] + ws[3];
}
__global__ __launch_bounds__(256) void k_scan2(const int* __restrict__ bsum,
                                               int* __restrict__ boff, int nb) {
  __shared__ int s[256];
  int t = threadIdx.x;
  int carry = 0;
  for (int base = 0; base < nb; base += 256) {
    int v = (base + t < nb) ? bsum[base + t] : 0;
    s[t] = v;
    __syncthreads();
    for (int o = 1; o < 256; o <<= 1) {
      int u = (t >= o) ? s[t - o] : 0;
      __syncthreads();
      s[t] += u;
      __syncthreads();
    }
    if (base + t < nb) boff[base + t] = carry + s[t] - v;
    carry += s[255];
    __syncthreads();
  }
}
__global__ __launch_bounds__(256) void k_scan3(const int* __restrict__ deg,
                                               const int* __restrict__ boff,
                                               int* __restrict__ rowptr,
                                               int* __restrict__ cursor, int N) {
  __shared__ int s[256];
  int t = threadIdx.x;
  int i = blockIdx.x * 256 + t;
  int v = (i < N) ? deg[i] : 0;
  s[t] = v;
  __syncthreads();
  for (int o = 1; o < 256; o <<= 1) {
    int u = (t >= o) ? s[t - o] : 0;
    __syncthreads();
    s[t] += u;
    __syncthreads();
  }
  int ex = boff[blockIdx.x] + s[t] - v;
  if (i < N) { rowptr[i] = ex; cursor[i] = ex; }
  if (i == N - 1) rowptr[N] = ex + v;
}

__global__ __launch_bounds__(256) void k_fill(const int* __restrict__ ei,
                                              const float* __restrict__ ew,
                                              int* __restrict__ cursor,
                                              int* __restrict__ srcs,
                                              float* __restrict__ wts, int E) {
  int e = blockIdx.x * 256 + threadIdx.x;
  if (e >= E) return;
  int d = ei[E + e];
  int pos = atomicAdd(&cursor[d], 1);
  srcs[pos] = ei[e];
  wts[pos] = ew[e];
}

// sh[d][:] = sum_e wts[e] * h[srcs[e]][:]
// Half-wave split: 32 lanes x 16B cover one 512B row; the two wave halves
// process edges i and i+1 simultaneously; 2x unroll -> 4 edges in flight.
// Halves combined with one shfl_xor(32) per column octet at the end.
__global__ __launch_bounds__(256) void k_aggregate(const int* __restrict__ rowptr,
                                                   const int* __restrict__ srcs,
                                                   const float* __restrict__ wts,
                                                   const bf16* __restrict__ hsrc,
                                                   bf16* __restrict__ sh,
                                                   int N, int H) {
  int wv = threadIdx.x >> 6, lane = threadIdx.x & 63;
  int d = blockIdx.x * 4 + wv;
  if (d >= N) return;
  int beg = rowptr[d], end = rowptr[d + 1];
  int half = lane >> 5;                    // 0 or 1: edge parity
  const u16* hp = (const u16*)hsrc;
  for (int c0 = (lane & 31) * 8; c0 < H; c0 += 256) {
    float f0 = 0.f, f1 = 0.f, f2 = 0.f, f3 = 0.f;
    float f4 = 0.f, f5 = 0.f, f6 = 0.f, f7 = 0.f;
    int i = beg;
    for (; i + 4 <= end; i += 4) {
      int   sA = srcs[i + half],     sB = srcs[i + 2 + half];
      float wA = wts[i + half],      wB = wts[i + 2 + half];
      s8v rA = *(const s8v*)(hp + (size_t)sA * H + c0);
      s8v rB = *(const s8v*)(hp + (size_t)sB * H + c0);
      f0 += wA * u2f((u16)rA[0]) + wB * u2f((u16)rB[0]);
      f1 += wA * u2f((u16)rA[1]) + wB * u2f((u16)rB[1]);
      f2 += wA * u2f((u16)rA[2]) + wB * u2f((u16)rB[2]);
      f3 += wA * u2f((u16)rA[3]) + wB * u2f((u16)rB[3]);
      f4 += wA * u2f((u16)rA[4]) + wB * u2f((u16)rB[4]);
      f5 += wA * u2f((u16)rA[5]) + wB * u2f((u16)rB[5]);
      f6 += wA * u2f((u16)rA[6]) + wB * u2f((u16)rB[6]);
      f7 += wA * u2f((u16)rA[7]) + wB * u2f((u16)rB[7]);
    }
    for (; i + 2 <= end; i += 2) {
      int   sA = srcs[i + half];
      float wA = wts[i + half];
      s8v rA = *(const s8v*)(hp + (size_t)sA * H + c0);
      f0 += wA * u2f((u16)rA[0]); f1 += wA * u2f((u16)rA[1]);
      f2 += wA * u2f((u16)rA[2]); f3 += wA * u2f((u16)rA[3]);
      f4 += wA * u2f((u16)rA[4]); f5 += wA * u2f((u16)rA[5]);
      f6 += wA * u2f((u16)rA[6]); f7 += wA * u2f((u16)rA[7]);
    }
    if (i < end && half == 0) {            // odd-degree tail: half 0 only
      int   sA = srcs[i];
      float wA = wts[i];
      s8v rA = *(const s8v*)(hp + (size_t)sA * H + c0);
      f0 += wA * u2f((u16)rA[0]); f1 += wA * u2f((u16)rA[1]);
      f2 += wA * u2f((u16)rA[2]); f3 += wA * u2f((u16)rA[3]);
      f4 += wA * u2f((u16)rA[4]); f5 += wA * u2f((u16)rA[5]);
      f6 += wA * u2f((u16)rA[6]); f7 += wA * u2f((u16)rA[7]);
    }
    f0 += __shfl_xor(f0, 32); f1 += __shfl_xor(f1, 32);
    f2 += __shfl_xor(f2, 32); f3 += __shfl_xor(f3, 32);
    f4 += __shfl_xor(f4, 32); f5 += __shfl_xor(f5, 32);
    f6 += __shfl_xor(f6, 32); f7 += __shfl_xor(f7, 32);
    if (half == 0) {
      s8v o;
      o[0] = (short)f2u(f0); o[1] = (short)f2u(f1);
      o[2] = (short)f2u(f2); o[3] = (short)f2u(f3);
      o[4] = (short)f2u(f4); o[5] = (short)f2u(f5);
      o[6] = (short)f2u(f6); o[7] = (short)f2u(f7);
      *(s8v*)((u16*)sh + (size_t)d * H + c0) = o;
    }
  }
}

// ---------------- MFMA GEMM: C[M,Nc] = A[M,K] @ Bt[Nc,K]^T ----------------
template <int OUT_F32>
__global__ __launch_bounds__(256) void k_gemm(const bf16* __restrict__ A,
                                              const bf16* __restrict__ Bt,
                                              void* __restrict__ Cv,
                                              const float* __restrict__ bias,
                                              int M, int K, int Nc,
                                              size_t sBt, size_t sC) {
  __shared__ short As[128][40];
  __shared__ short Bs[64][40];
  int gm = blockIdx.x * 128, gn = blockIdx.y * 64;
  Bt += (size_t)blockIdx.z * sBt;
  size_t zc = (size_t)blockIdx.z * sC;
  int tid = threadIdx.x, w = tid >> 6, lane = tid & 63;
  int l15 = lane & 15, koff = (lane >> 4) * 8;
  f4v acc[2][4];
#pragma unroll
  for (int i = 0; i < 2; i++)
#pragma unroll
    for (int j = 0; j < 4; j++) acc[i][j] = (f4v)0.f;

  for (int kt = 0; kt < K; kt += 32) {
#pragma unroll
    for (int c = 0; c < 2; c++) {
      int ch = tid + c * 256;
      int row = ch >> 2, seg = ch & 3;
      *(float4*)&As[row][seg * 8] =
          *(const float4*)(A + (size_t)(gm + row) * K + kt + seg * 8);
    }
    {
      int row = tid >> 2, seg = tid & 3;
      *(float4*)&Bs[row][seg * 8] =
          *(const float4*)(Bt + (size_t)(gn + row) * K + kt + seg * 8);
    }
    __syncthreads();
    s8v af[2], bf[4];
#pragma unroll
    for (int rt = 0; rt < 2; rt++) af[rt] = *(const s8v*)&As[w * 32 + rt * 16 + l15][koff];
#pragma unroll
    for (int ct = 0; ct < 4; ct++) bf[ct] = *(const s8v*)&Bs[ct * 16 + l15][koff];
#pragma unroll
    for (int rt = 0; rt < 2; rt++)
#pragma unroll
      for (int ct = 0; ct < 4; ct++) acc[rt][ct] = MFMA16(af[rt], bf[ct], acc[rt][ct]);
    __syncthreads();
  }
#pragma unroll
  for (int rt = 0; rt < 2; rt++)
#pragma unroll
    for (int ct = 0; ct < 4; ct++)
#pragma unroll
      for (int r = 0; r < 4; r++) {
        int row = gm + w * 32 + rt * 16 + (lane >> 4) * 4 + r;
        int col = gn + ct * 16 + l15;
        float v = acc[rt][ct][r];
        if (OUT_F32) ((float*)Cv)[zc + (size_t)row * Nc + col] = v + bias[col];
        else         ((bf16*)Cv)[zc + (size_t)row * Nc + col] = __float2bfloat16(v);
      }
}

// ---------------- fused GRU, 128x64 tile, 2-phase pipelined staging ---------
// REVERT (r8 post-mortem): full-LDS staging + __launch_bounds__(256,2) is the
// validated optimum (88.4 us/layer, r6). B-only-LDS with A/H direct from L2
// measured 99 us (r8) -- un-hidden L2 latency, no occupancy gain. The 128-f32
// accumulator footprint makes 2 waves/EU this kernel's ceiling; (256,3)
// spills to scratch (r7: 540 MB HBM round-trip).
#define GRU_STAGE(Aarr, Harr, Barr, kt)                   \
  {                                                       \
    gl16(&Aarr[tid * 8],            Ap  + (kt));          \
    gl16(&Aarr[2048 + tid * 8],     Ap  + rstep + (kt));  \
    gl16(&Harr[tid * 8],            Hp  + (kt));          \
    gl16(&Harr[2048 + tid * 8],     Hp  + rstep + (kt));  \
    gl16(&Barr[tid * 8],            BiP + (kt));          \
    gl16(&Barr[2048 + tid * 8],     BiP + HH + (kt));     \
    gl16(&Barr[2 * 2048 + tid * 8], BiP + 2 * HH + (kt)); \
    gl16(&Barr[3 * 2048 + tid * 8], BhP + (kt));          \
    gl16(&Barr[4 * 2048 + tid * 8], BhP + HH + (kt));     \
    gl16(&Barr[5 * 2048 + tid * 8], BhP + 2 * HH + (kt)); \
  }

#define GRU_COMPUTE(Aarr, Harr, Barr)                                       \
  {                                                                         \
    s8v fa[2], fh[2];                                                       \
    _Pragma("unroll")                                                       \
    for (int rt = 0; rt < 2; rt++) {                                        \
      fa[rt] = *(const s8v*)&Aarr[(w * 32 + rt * 16 + l15) * 32 + koff];    \
      fh[rt] = *(const s8v*)&Harr[(w * 32 + rt * 16 + l15) * 32 + koff];    \
    }                                                                       \
    _Pragma("unroll")                                                       \
    for (int ct = 0; ct < 4; ct++) {                                        \
      int brow = (ct * 16 + l15) * 32 + koff;                               \
      s8v bRi = *(const s8v*)&Barr[brow];                                   \
      s8v bZi = *(const s8v*)&Barr[2048 + brow];                            \
      s8v bNi = *(const s8v*)&Barr[2 * 2048 + brow];                        \
      s8v bRh = *(const s8v*)&Barr[3 * 2048 + brow];                        \
      s8v bZh = *(const s8v*)&Barr[4 * 2048 + brow];                        \
      s8v bNh = *(const s8v*)&Barr[5 * 2048 + brow];                        \
      _Pragma("unroll")                                                     \
      for (int rt = 0; rt < 2; rt++) {                                      \
        accR[rt][ct]  = MFMA16(fa[rt], bRi, accR[rt][ct]);                  \
        accR[rt][ct]  = MFMA16(fh[rt], bRh, accR[rt][ct]);                  \
        accZ[rt][ct]  = MFMA16(fa[rt], bZi, accZ[rt][ct]);                  \
        accZ[rt][ct]  = MFMA16(fh[rt], bZh, accZ[rt][ct]);                  \
        accNi[rt][ct] = MFMA16(fa[rt], bNi, accNi[rt][ct]);                 \
        accNh[rt][ct] = MFMA16(fh[rt], bNh, accNh[rt][ct]);                 \
      }                                                                     \
    }                                                                       \
  }

__global__ __launch_bounds__(256, 2) void k_gru_mfma(const bf16* __restrict__ Ash,
                                                     const bf16* __restrict__ Ah,
                                                     const bf16* __restrict__ Wi,  // Ucomb_l [3H][H]
                                                     const bf16* __restrict__ Wh,  // w_hh [3H][H]
                                                     const float* __restrict__ bi,
                                                     const float* __restrict__ bh,
                                                     bf16* __restrict__ hn,
                                                     int M, int H) {
  __shared__ __align__(16) short Aa0[128 * 32], Aa1[128 * 32];
  __shared__ __align__(16) short Hs0[128 * 32], Hs1[128 * 32];
  __shared__ __align__(16) short Bs0[6 * 64 * 32], Bs1[6 * 64 * 32];

  // XCD-chunked bijective swizzle (grid is 1D: nwgx * nwgy blocks)
  int nwgx = H >> 6;                      // gcol blocks (4)
  int nwg = gridDim.x;
  int bid = blockIdx.x;
  int wg = bid;
  if ((nwg & 7) == 0) { int cpx = nwg >> 3; wg = (bid & 7) * cpx + (bid >> 3); }
  int gcol = (wg % nwgx) * 64;
  int gm = (wg / nwgx) * 128;

  int tid = threadIdx.x, w = tid >> 6, lane = tid & 63;
  int l15 = lane & 15, koff = (lane >> 4) * 8;
  f4v accR[2][4], accZ[2][4], accNi[2][4], accNh[2][4];
#pragma unroll
  for (int rt = 0; rt < 2; rt++)
#pragma unroll
    for (int ct = 0; ct < 4; ct++) {
      accR[rt][ct] = (f4v)0.f; accZ[rt][ct] = (f4v)0.f;
      accNi[rt][ct] = (f4v)0.f; accNh[rt][ct] = (f4v)0.f;
    }

  // per-lane staging source pointers (16B-aligned)
  int arow = tid >> 2, aseg = tid & 3;
  const bf16* Ap  = Ash + (size_t)(gm + arow) * H + aseg * 8;
  const bf16* Hp  = Ah  + (size_t)(gm + arow) * H + aseg * 8;
  const bf16* BiP = Wi  + (size_t)(gcol + arow) * H + aseg * 8;  // rows 0..63
  const bf16* BhP = Wh  + (size_t)(gcol + arow) * H + aseg * 8;
  size_t HH = (size_t)H * H;
  size_t rstep = (size_t)64 * H;

  int nk = H >> 5;                         // K-steps (8)
  GRU_STAGE(Aa0, Hs0, Bs0, 0);
  __syncthreads();                         // drains vmcnt: tile 0 ready
  for (int t = 0; t < nk; t += 2) {
    int kt = t << 5;
    if (t + 1 < nk) GRU_STAGE(Aa1, Hs1, Bs1, kt + 32);  // issue next FIRST
    GRU_COMPUTE(Aa0, Hs0, Bs0);                          // overlap with loads
    __syncthreads();                                     // one drain per step
    if (t + 2 < nk) GRU_STAGE(Aa0, Hs0, Bs0, kt + 64);
    if (t + 1 < nk) GRU_COMPUTE(Aa1, Hs1, Bs1);
    __syncthreads();
  }

#pragma unroll
  for (int ct = 0; ct < 4; ct++) {
    int col = gcol + ct * 16 + l15;
    float br  = bi[col] + bh[col];
    float bz  = bi[H + col] + bh[H + col];
    float bin = bi[2 * H + col], bhn = bh[2 * H + col];
#pragma unroll
    for (int rt = 0; rt < 2; rt++)
#pragma unroll
      for (int r = 0; r < 4; r++) {
        int row = gm + w * 32 + rt * 16 + (lane >> 4) * 4 + r;
        float rr = sigm(accR[rt][ct][r] + br);
        float zz = sigm(accZ[rt][ct][r] + bz);
        float nn = ftanh(accNi[rt][ct][r] + bin + rr * (accNh[rt][ct][r] + bhn));
        float hv = b2f(Ah[(size_t)row * H + col]);
        hn[(size_t)row * H + col] = __float2bfloat16((1.f - zz) * nn + zz * hv);
      }
  }
}

static inline size_t alg(size_t x) { return (x + 255) & ~(size_t)255; }
static inline int cdiv(int a, int b) { return (a + b - 1) / b; }

extern "C" void kernel_launch(void* const* d_in, const int* in_sizes, int n_in,
                              void* d_out, int out_size, void* d_ws, size_t ws_size,
                              hipStream_t stream) {
  (void)out_size; (void)ws_size;
  int s = (n_in >= 14) ? 0 : -1;
  const int*   x     = (const int*)d_in[0];
  const int*   ei    = (const int*)d_in[1];
  const float* ew    = (const float*)d_in[2];
  const int*   gidx  = (const int*)d_in[3];
  const float* enc   = (const float*)d_in[5 + s];
  const float* emb   = (const float*)d_in[6 + s];
  const float* ggcw  = (const float*)d_in[7 + s];
  const float* w_ih  = (const float*)d_in[8 + s];
  const float* w_hh  = (const float*)d_in[9 + s];
  const float* b_ih  = (const float*)d_in[10 + s];
  const float* b_hh  = (const float*)d_in[11 + s];
  const float* out_w = (const float*)d_in[12 + s];
  const float* out_b = (const float*)d_in[13 + s];
  float* out = (float*)d_out;

  int N   = in_sizes[0];
  int E   = in_sizes[2];
  int BL  = in_sizes[3];
  int H   = in_sizes[5 + s] / BL;
  int LG  = in_sizes[7 + s] / (H * H);
  int OUT = in_sizes[12 + s] / (2 * H);

  size_t nh = (size_t)N * H;
  size_t hh3 = (size_t)3 * H * H;
  int nb = cdiv(N, 256);
  char* p = (char*)d_ws;
  size_t off = 0;
  bf16* wihB  = (bf16*)(p + off); off = alg(off + hh3 * 2);
  bf16* whhB  = (bf16*)(p + off); off = alg(off + hh3 * 2);
  bf16* outwB = (bf16*)(p + off); off = alg(off + (size_t)OUT * 2 * H * 2);
  bf16* ggcwB = (bf16*)(p + off); off = alg(off + (size_t)LG * H * H * 2);
  bf16* Ucomb = (bf16*)(p + off); off = alg(off + (size_t)LG * hh3 * 2);
  bf16* hA    = (bf16*)(p + off); off = alg(off + nh * 2);
  bf16* hB    = (bf16*)(p + off); off = alg(off + nh * 2);
  bf16* shB   = (bf16*)(p + off); off = alg(off + nh * 2);
  bf16* catA  = (bf16*)(p + off); off = alg(off + (size_t)BL * 2 * H * 2);
  int* deg    = (int*)(p + off);  off = alg(off + (size_t)N * 4);
  int* rowptr = (int*)(p + off);  off = alg(off + (size_t)(N + 1) * 4);
  int* cursor = (int*)(p + off);  off = alg(off + (size_t)N * 4);
  int* srcs   = (int*)(p + off);  off = alg(off + (size_t)E * 4);
  float* wts  = (float*)(p + off); off = alg(off + (size_t)E * 4);
  int* bsum   = (int*)(p + off);  off = alg(off + (size_t)nb * 4);
  int* boff   = (int*)(p + off);  off = alg(off + (size_t)nb * 4);

  // weight prep
  k_cast<<<cdiv((int)hh3, 256), 256, 0, stream>>>(w_ih, wihB, (int)hh3);
  k_cast<<<cdiv((int)hh3, 256), 256, 0, stream>>>(w_hh, whhB, (int)hh3);
  k_cast<<<cdiv(OUT * 2 * H, 256), 256, 0, stream>>>(out_w, outwB, OUT * 2 * H);
  k_cast<<<cdiv(LG * H * H, 256), 256, 0, stream>>>(ggcw, ggcwB, LG * H * H);
  // Ucomb_l[c][k] = sum_p w_ih[c][p] * ggcw_l[k][p] -- all LG layers in ONE launch
  k_gemm<0><<<dim3(3 * H / 128, H / 64, LG), 256, 0, stream>>>(
      wihB, ggcwB, Ucomb, nullptr, 3 * H, H, H, (size_t)H * H, hh3);

  // embedding + CSR build (parallel hierarchical scan)
  k_embed<<<cdiv(N * H, 256), 256, 0, stream>>>(x, emb, hA, N, H);
  k_zero_i32<<<cdiv(N, 256), 256, 0, stream>>>(deg, N);
  k_hist<<<cdiv(E, 256), 256, 0, stream>>>(ei, deg, E);
  k_scan1<<<nb, 256, 0, stream>>>(deg, bsum, N);
  k_scan2<<<1, 256, 0, stream>>>(bsum, boff, nb);
  k_scan3<<<nb, 256, 0, stream>>>(deg, boff, rowptr, cursor, N);
  k_fill<<<cdiv(E, 256), 256, 0, stream>>>(ei, ew, cursor, srcs, wts, E);

  bf16* h = hA;
  bf16* hn = hB;
  for (int l = 0; l < LG; l++) {
    k_aggregate<<<cdiv(N, 4), 256, 0, stream>>>(rowptr, srcs, wts, h, shB, N, H);
    k_gru_mfma<<<dim3((H / 64) * (N / 128)), 256, 0, stream>>>(
        shB, h, Ucomb + (size_t)l * hh3, whhB, b_ih, b_hh, hn, N, H);
    bf16* t = h; h = hn; hn = t;
  }
  k_cat<<<cdiv(BL * 2 * H, 256), 256, 0, stream>>>(h, gidx, enc, catA, BL, H);
  k_gemm<1><<<dim3(BL / 128, OUT / 64, 1), 256, 0, stream>>>(
      catA, outwB, out, out_b, BL, 2 * H, OUT, 0, 0);
}

// Round 10
// 865.655 us; speedup vs baseline: 1.5236x; 1.0312x over previous
//
#include <hip/hip_runtime.h>
#include <hip/hip_bf16.h>

typedef __hip_bfloat16 bf16;
typedef unsigned short u16;
typedef __attribute__((ext_vector_type(8))) short s8v;   // 8 bf16 = 4 VGPR
typedef __attribute__((ext_vector_type(4))) float f4v;   // MFMA accumulator

#define MFMA16(a, b, c) __builtin_amdgcn_mfma_f32_16x16x32_bf16((a), (b), (c), 0, 0, 0)

__device__ __forceinline__ float b2f(bf16 v) { return __bfloat162float(v); }
// fast sigmoid: v_rcp_f32 instead of IEEE divide (no fast-math flag, so 1.f/x
// would emit div_scale+fmas+fixup ~10 VALU + 2 trans per divide; rcpf is 1
// trans op, ~1 ulp -- invisible at bf16 tolerance)
__device__ __forceinline__ float sigm(float x) {
  return __builtin_amdgcn_rcpf(1.0f + __expf(-x));
}
// fast tanh: 2*sigmoid(2x)-1
__device__ __forceinline__ float ftanh(float x) {
  return __builtin_fmaf(2.f, sigm(2.f * x), -1.f);
}
__device__ __forceinline__ float u2f(u16 u) {
  union { float f; unsigned int i; } v; v.i = ((unsigned int)u) << 16; return v.f;
}
__device__ __forceinline__ u16 f2u(float f) {
  bf16 b = __float2bfloat16(f);
  union { bf16 b; u16 u; } v; v.b = b; return v.u;
}

// async global -> LDS, 16B per lane (global_load_lds_dwordx4)
__device__ __forceinline__ void gl16(void* lds, const void* g) {
  __builtin_amdgcn_global_load_lds(
      (const __attribute__((address_space(1))) unsigned int*)g,
      (__attribute__((address_space(3))) unsigned int*)lds, 16, 0, 0);
}

// ---------------- small utility kernels ----------------
__global__ __launch_bounds__(256) void k_cast(const float* __restrict__ s,
                                              bf16* __restrict__ d, int n) {
  int i = blockIdx.x * 256 + threadIdx.x;
  if (i < n) d[i] = __float2bfloat16(s[i]);
}

__global__ __launch_bounds__(256) void k_embed(const int* __restrict__ x,
                                               const float* __restrict__ emb,
                                               bf16* __restrict__ h, int N, int H) {
  int idx = blockIdx.x * 256 + threadIdx.x;
  if (idx >= N * H) return;
  int n = idx / H, c = idx - n * H;
  h[idx] = __float2bfloat16(emb[(size_t)x[n] * H + c]);
}

// catA[r][k] = k<H ? h[gidx[r]][k] : bf16(enc[r][k-H])
__global__ __launch_bounds__(256) void k_cat(const bf16* __restrict__ h,
                                             const int* __restrict__ gidx,
                                             const float* __restrict__ enc,
                                             bf16* __restrict__ catA, int BL, int H) {
  int i = blockIdx.x * 256 + threadIdx.x;
  if (i >= BL * 2 * H) return;
  int r = i / (2 * H), k = i - r * 2 * H;
  catA[i] = (k < H) ? h[(size_t)gidx[r] * H + k]
                    : __float2bfloat16(enc[(size_t)r * H + (k - H)]);
}

// ---------------- CSR build (once per call) ----------------
__global__ __launch_bounds__(256) void k_zero_i32(int* __restrict__ p, int n) {
  int i = blockIdx.x * 256 + threadIdx.x;
  if (i < n) p[i] = 0;
}
__global__ __launch_bounds__(256) void k_hist(const int* __restrict__ ei,
                                              int* __restrict__ deg, int E) {
  int e = blockIdx.x * 256 + threadIdx.x;
  if (e < E) atomicAdd(&deg[ei[E + e]], 1);
}

// hierarchical exclusive scan of deg[N] -> rowptr[N+1] and cursor[N]
__global__ __launch_bounds__(256) void k_scan1(const int* __restrict__ deg,
                                               int* __restrict__ bsum, int N) {
  int t = threadIdx.x;
  int i = blockIdx.x * 256 + t;
  int v = (i < N) ? deg[i] : 0;
#pragma unroll
  for (int o = 32; o > 0; o >>= 1) v += __shfl_down(v, o, 64);
  __shared__ int ws[4];
  if ((t & 63) == 0) ws[t >> 6] = v;
  __syncthreads();
  if (t == 0) bsum[blockIdx.x] = ws[0] + ws[1] + ws[2] + ws[3];
}
__global__ __launch_bounds__(256) void k_scan2(const int* __restrict__ bsum,
                                               int* __restrict__ boff, int nb) {
  __shared__ int s[256];
  int t = threadIdx.x;
  int carry = 0;
  for (int base = 0; base < nb; base += 256) {
    int v = (base + t < nb) ? bsum[base + t] : 0;
    s[t] = v;
    __syncthreads();
    for (int o = 1; o < 256; o <<= 1) {
      int u = (t >= o) ? s[t - o] : 0;
      __syncthreads();
      s[t] += u;
      __syncthreads();
    }
    if (base + t < nb) boff[base + t] = carry + s[t] - v;
    carry += s[255];
    __syncthreads();
  }
}
__global__ __launch_bounds__(256) void k_scan3(const int* __restrict__ deg,
                                               const int* __restrict__ boff,
                                               int* __restrict__ rowptr,
                                               int* __restrict__ cursor, int N) {
  __shared__ int s[256];
  int t = threadIdx.x;
  int i = blockIdx.x * 256 + t;
  int v = (i < N) ? deg[i] : 0;
  s[t] = v;
  __syncthreads();
  for (int o = 1; o < 256; o <<= 1) {
    int u = (t >= o) ? s[t - o] : 0;
    __syncthreads();
    s[t] += u;
    __syncthreads();
  }
  int ex = boff[blockIdx.x] + s[t] - v;
  if (i < N) { rowptr[i] = ex; cursor[i] = ex; }
  if (i == N - 1) rowptr[N] = ex + v;
}

__global__ __launch_bounds__(256) void k_fill(const int* __restrict__ ei,
                                              const float* __restrict__ ew,
                                              int* __restrict__ cursor,
                                              int* __restrict__ srcs,
                                              float* __restrict__ wts, int E) {
  int e = blockIdx.x * 256 + threadIdx.x;
  if (e >= E) return;
  int d = ei[E + e];
  int pos = atomicAdd(&cursor[d], 1);
  srcs[pos] = ei[e];
  wts[pos] = ew[e];
}

// sh[d][:] = sum_e wts[e] * h[srcs[e]][:]
// Half-wave split: 32 lanes x 16B cover one 512B row; halves take edge parity.
// 8-edge unroll -> 4 row-loads in flight per lane (kernel is latency-bound,
// not L2-BW-bound: theoretical BW cost ~15us/layer).
__global__ __launch_bounds__(256) void k_aggregate(const int* __restrict__ rowptr,
                                                   const int* __restrict__ srcs,
                                                   const float* __restrict__ wts,
                                                   const bf16* __restrict__ hsrc,
                                                   bf16* __restrict__ sh,
                                                   int N, int H) {
  int wv = threadIdx.x >> 6, lane = threadIdx.x & 63;
  int d = blockIdx.x * 4 + wv;
  if (d >= N) return;
  int beg = rowptr[d], end = rowptr[d + 1];
  int half = lane >> 5;                    // 0 or 1: edge parity
  const u16* hp = (const u16*)hsrc;
  for (int c0 = (lane & 31) * 8; c0 < H; c0 += 256) {
    float f0 = 0.f, f1 = 0.f, f2 = 0.f, f3 = 0.f;
    float f4 = 0.f, f5 = 0.f, f6 = 0.f, f7 = 0.f;
    int i = beg;
    for (; i + 8 <= end; i += 8) {
      int   sA = srcs[i + half],     sB = srcs[i + 2 + half];
      int   sC = srcs[i + 4 + half], sD = srcs[i + 6 + half];
      float wA = wts[i + half],      wB = wts[i + 2 + half];
      float wC = wts[i + 4 + half],  wD = wts[i + 6 + half];
      s8v rA = *(const s8v*)(hp + (size_t)sA * H + c0);
      s8v rB = *(const s8v*)(hp + (size_t)sB * H + c0);
      s8v rC = *(const s8v*)(hp + (size_t)sC * H + c0);
      s8v rD = *(const s8v*)(hp + (size_t)sD * H + c0);
      f0 += wA * u2f((u16)rA[0]) + wB * u2f((u16)rB[0]) + wC * u2f((u16)rC[0]) + wD * u2f((u16)rD[0]);
      f1 += wA * u2f((u16)rA[1]) + wB * u2f((u16)rB[1]) + wC * u2f((u16)rC[1]) + wD * u2f((u16)rD[1]);
      f2 += wA * u2f((u16)rA[2]) + wB * u2f((u16)rB[2]) + wC * u2f((u16)rC[2]) + wD * u2f((u16)rD[2]);
      f3 += wA * u2f((u16)rA[3]) + wB * u2f((u16)rB[3]) + wC * u2f((u16)rC[3]) + wD * u2f((u16)rD[3]);
      f4 += wA * u2f((u16)rA[4]) + wB * u2f((u16)rB[4]) + wC * u2f((u16)rC[4]) + wD * u2f((u16)rD[4]);
      f5 += wA * u2f((u16)rA[5]) + wB * u2f((u16)rB[5]) + wC * u2f((u16)rC[5]) + wD * u2f((u16)rD[5]);
      f6 += wA * u2f((u16)rA[6]) + wB * u2f((u16)rB[6]) + wC * u2f((u16)rC[6]) + wD * u2f((u16)rD[6]);
      f7 += wA * u2f((u16)rA[7]) + wB * u2f((u16)rB[7]) + wC * u2f((u16)rC[7]) + wD * u2f((u16)rD[7]);
    }
    for (; i + 2 <= end; i += 2) {
      int   sA = srcs[i + half];
      float wA = wts[i + half];
      s8v rA = *(const s8v*)(hp + (size_t)sA * H + c0);
      f0 += wA * u2f((u16)rA[0]); f1 += wA * u2f((u16)rA[1]);
      f2 += wA * u2f((u16)rA[2]); f3 += wA * u2f((u16)rA[3]);
      f4 += wA * u2f((u16)rA[4]); f5 += wA * u2f((u16)rA[5]);
      f6 += wA * u2f((u16)rA[6]); f7 += wA * u2f((u16)rA[7]);
    }
    if (i < end && half == 0) {            // odd-degree tail: half 0 only
      int   sA = srcs[i];
      float wA = wts[i];
      s8v rA = *(const s8v*)(hp + (size_t)sA * H + c0);
      f0 += wA * u2f((u16)rA[0]); f1 += wA * u2f((u16)rA[1]);
      f2 += wA * u2f((u16)rA[2]); f3 += wA * u2f((u16)rA[3]);
      f4 += wA * u2f((u16)rA[4]); f5 += wA * u2f((u16)rA[5]);
      f6 += wA * u2f((u16)rA[6]); f7 += wA * u2f((u16)rA[7]);
    }
    f0 += __shfl_xor(f0, 32); f1 += __shfl_xor(f1, 32);
    f2 += __shfl_xor(f2, 32); f3 += __shfl_xor(f3, 32);
    f4 += __shfl_xor(f4, 32); f5 += __shfl_xor(f5, 32);
    f6 += __shfl_xor(f6, 32); f7 += __shfl_xor(f7, 32);
    if (half == 0) {
      s8v o;
      o[0] = (short)f2u(f0); o[1] = (short)f2u(f1);
      o[2] = (short)f2u(f2); o[3] = (short)f2u(f3);
      o[4] = (short)f2u(f4); o[5] = (short)f2u(f5);
      o[6] = (short)f2u(f6); o[7] = (short)f2u(f7);
      *(s8v*)((u16*)sh + (size_t)d * H + c0) = o;
    }
  }
}

// ---------------- MFMA GEMM: C[M,Nc] = A[M,K] @ Bt[Nc,K]^T ----------------
template <int OUT_F32>
__global__ __launch_bounds__(256) void k_gemm(const bf16* __restrict__ A,
                                              const bf16* __restrict__ Bt,
                                              void* __restrict__ Cv,
                                              const float* __restrict__ bias,
                                              int M, int K, int Nc,
                                              size_t sBt, size_t sC) {
  __shared__ short As[128][40];
  __shared__ short Bs[64][40];
  int gm = blockIdx.x * 128, gn = blockIdx.y * 64;
  Bt += (size_t)blockIdx.z * sBt;
  size_t zc = (size_t)blockIdx.z * sC;
  int tid = threadIdx.x, w = tid >> 6, lane = tid & 63;
  int l15 = lane & 15, koff = (lane >> 4) * 8;
  f4v acc[2][4];
#pragma unroll
  for (int i = 0; i < 2; i++)
#pragma unroll
    for (int j = 0; j < 4; j++) acc[i][j] = (f4v)0.f;

  for (int kt = 0; kt < K; kt += 32) {
#pragma unroll
    for (int c = 0; c < 2; c++) {
      int ch = tid + c * 256;
      int row = ch >> 2, seg = ch & 3;
      *(float4*)&As[row][seg * 8] =
          *(const float4*)(A + (size_t)(gm + row) * K + kt + seg * 8);
    }
    {
      int row = tid >> 2, seg = tid & 3;
      *(float4*)&Bs[row][seg * 8] =
          *(const float4*)(Bt + (size_t)(gn + row) * K + kt + seg * 8);
    }
    __syncthreads();
    s8v af[2], bf[4];
#pragma unroll
    for (int rt = 0; rt < 2; rt++) af[rt] = *(const s8v*)&As[w * 32 + rt * 16 + l15][koff];
#pragma unroll
    for (int ct = 0; ct < 4; ct++) bf[ct] = *(const s8v*)&Bs[ct * 16 + l15][koff];
#pragma unroll
    for (int rt = 0; rt < 2; rt++)
#pragma unroll
      for (int ct = 0; ct < 4; ct++) acc[rt][ct] = MFMA16(af[rt], bf[ct], acc[rt][ct]);
    __syncthreads();
  }
#pragma unroll
  for (int rt = 0; rt < 2; rt++)
#pragma unroll
    for (int ct = 0; ct < 4; ct++)
#pragma unroll
      for (int r = 0; r < 4; r++) {
        int row = gm + w * 32 + rt * 16 + (lane >> 4) * 4 + r;
        int col = gn + ct * 16 + l15;
        float v = acc[rt][ct][r];
        if (OUT_F32) ((float*)Cv)[zc + (size_t)row * Nc + col] = v + bias[col];
        else         ((bf16*)Cv)[zc + (size_t)row * Nc + col] = __float2bfloat16(v);
      }
}

// ---------------- fused GRU, 128x64 tile, 2-phase pipelined staging ---------
// Validated optimum structure (r6/r8): full-LDS gl16 staging, static dbuf,
// one barrier per K-step, T1 XCD swizzle, __launch_bounds__(256,2).
// (256,3) spills (r7); B-only-LDS is -12% (r8). Epilogue uses rcpf-sigm.
#define GRU_STAGE(Aarr, Harr, Barr, kt)                   \
  {                                                       \
    gl16(&Aarr[tid * 8],            Ap  + (kt));          \
    gl16(&Aarr[2048 + tid * 8],     Ap  + rstep + (kt));  \
    gl16(&Harr[tid * 8],            Hp  + (kt));          \
    gl16(&Harr[2048 + tid * 8],     Hp  + rstep + (kt));  \
    gl16(&Barr[tid * 8],            BiP + (kt));          \
    gl16(&Barr[2048 + tid * 8],     BiP + HH + (kt));     \
    gl16(&Barr[2 * 2048 + tid * 8], BiP + 2 * HH + (kt)); \
    gl16(&Barr[3 * 2048 + tid * 8], BhP + (kt));          \
    gl16(&Barr[4 * 2048 + tid * 8], BhP + HH + (kt));     \
    gl16(&Barr[5 * 2048 + tid * 8], BhP + 2 * HH + (kt)); \
  }

#define GRU_COMPUTE(Aarr, Harr, Barr)                                       \
  {                                                                         \
    s8v fa[2], fh[2];                                                       \
    _Pragma("unroll")                                                       \
    for (int rt = 0; rt < 2; rt++) {                                        \
      fa[rt] = *(const s8v*)&Aarr[(w * 32 + rt * 16 + l15) * 32 + koff];    \
      fh[rt] = *(const s8v*)&Harr[(w * 32 + rt * 16 + l15) * 32 + koff];    \
    }                                                                       \
    _Pragma("unroll")                                                       \
    for (int ct = 0; ct < 4; ct++) {                                        \
      int brow = (ct * 16 + l15) * 32 + koff;                               \
      s8v bRi = *(const s8v*)&Barr[brow];                                   \
      s8v bZi = *(const s8v*)&Barr[2048 + brow];                            \
      s8v bNi = *(const s8v*)&Barr[2 * 2048 + brow];                        \
      s8v bRh = *(const s8v*)&Barr[3 * 2048 + brow];                        \
      s8v bZh = *(const s8v*)&Barr[4 * 2048 + brow];                        \
      s8v bNh = *(const s8v*)&Barr[5 * 2048 + brow];                        \
      _Pragma("unroll")                                                     \
      for (int rt = 0; rt < 2; rt++) {                                      \
        accR[rt][ct]  = MFMA16(fa[rt], bRi, accR[rt][ct]);                  \
        accR[rt][ct]  = MFMA16(fh[rt], bRh, accR[rt][ct]);                  \
        accZ[rt][ct]  = MFMA16(fa[rt], bZi, accZ[rt][ct]);                  \
        accZ[rt][ct]  = MFMA16(fh[rt], bZh, accZ[rt][ct]);                  \
        accNi[rt][ct] = MFMA16(fa[rt], bNi, accNi[rt][ct]);                 \
        accNh[rt][ct] = MFMA16(fh[rt], bNh, accNh[rt][ct]);                 \
      }                                                                     \
    }                                                                       \
  }

__global__ __launch_bounds__(256, 2) void k_gru_mfma(const bf16* __restrict__ Ash,
                                                     const bf16* __restrict__ Ah,
                                                     const bf16* __restrict__ Wi,  // Ucomb_l [3H][H]
                                                     const bf16* __restrict__ Wh,  // w_hh [3H][H]
                                                     const float* __restrict__ bi,
                                                     const float* __restrict__ bh,
                                                     bf16* __restrict__ hn,
                                                     int M, int H) {
  __shared__ __align__(16) short Aa0[128 * 32], Aa1[128 * 32];
  __shared__ __align__(16) short Hs0[128 * 32], Hs1[128 * 32];
  __shared__ __align__(16) short Bs0[6 * 64 * 32], Bs1[6 * 64 * 32];

  // XCD-chunked bijective swizzle (grid is 1D: nwgx * nwgy blocks)
  int nwgx = H >> 6;                      // gcol blocks (4)
  int nwg = gridDim.x;
  int bid = blockIdx.x;
  int wg = bid;
  if ((nwg & 7) == 0) { int cpx = nwg >> 3; wg = (bid & 7) * cpx + (bid >> 3); }
  int gcol = (wg % nwgx) * 64;
  int gm = (wg / nwgx) * 128;

  int tid = threadIdx.x, w = tid >> 6, lane = tid & 63;
  int l15 = lane & 15, koff = (lane >> 4) * 8;
  f4v accR[2][4], accZ[2][4], accNi[2][4], accNh[2][4];
#pragma unroll
  for (int rt = 0; rt < 2; rt++)
#pragma unroll
    for (int ct = 0; ct < 4; ct++) {
      accR[rt][ct] = (f4v)0.f; accZ[rt][ct] = (f4v)0.f;
      accNi[rt][ct] = (f4v)0.f; accNh[rt][ct] = (f4v)0.f;
    }

  // per-lane staging source pointers (16B-aligned)
  int arow = tid >> 2, aseg = tid & 3;
  const bf16* Ap  = Ash + (size_t)(gm + arow) * H + aseg * 8;
  const bf16* Hp  = Ah  + (size_t)(gm + arow) * H + aseg * 8;
  const bf16* BiP = Wi  + (size_t)(gcol + arow) * H + aseg * 8;  // rows 0..63
  const bf16* BhP = Wh  + (size_t)(gcol + arow) * H + aseg * 8;
  size_t HH = (size_t)H * H;
  size_t rstep = (size_t)64 * H;

  int nk = H >> 5;                         // K-steps (8)
  GRU_STAGE(Aa0, Hs0, Bs0, 0);
  __syncthreads();                         // drains vmcnt: tile 0 ready
  for (int t = 0; t < nk; t += 2) {
    int kt = t << 5;
    if (t + 1 < nk) GRU_STAGE(Aa1, Hs1, Bs1, kt + 32);  // issue next FIRST
    GRU_COMPUTE(Aa0, Hs0, Bs0);                          // overlap with loads
    __syncthreads();                                     // one drain per step
    if (t + 2 < nk) GRU_STAGE(Aa0, Hs0, Bs0, kt + 64);
    if (t + 1 < nk) GRU_COMPUTE(Aa1, Hs1, Bs1);
    __syncthreads();
  }

#pragma unroll
  for (int ct = 0; ct < 4; ct++) {
    int col = gcol + ct * 16 + l15;
    float br  = bi[col] + bh[col];
    float bz  = bi[H + col] + bh[H + col];
    float bin = bi[2 * H + col], bhn = bh[2 * H + col];
#pragma unroll
    for (int rt = 0; rt < 2; rt++)
#pragma unroll
      for (int r = 0; r < 4; r++) {
        int row = gm + w * 32 + rt * 16 + (lane >> 4) * 4 + r;
        float rr = sigm(accR[rt][ct][r] + br);
        float zz = sigm(accZ[rt][ct][r] + bz);
        float nn = ftanh(accNi[rt][ct][r] + bin + rr * (accNh[rt][ct][r] + bhn));
        float hv = b2f(Ah[(size_t)row * H + col]);
        hn[(size_t)row * H + col] = __float2bfloat16((1.f - zz) * nn + zz * hv);
      }
  }
}

static inline size_t alg(size_t x) { return (x + 255) & ~(size_t)255; }
static inline int cdiv(int a, int b) { return (a + b - 1) / b; }

extern "C" void kernel_launch(void* const* d_in, const int* in_sizes, int n_in,
                              void* d_out, int out_size, void* d_ws, size_t ws_size,
                              hipStream_t stream) {
  (void)out_size; (void)ws_size;
  int s = (n_in >= 14) ? 0 : -1;
  const int*   x     = (const int*)d_in[0];
  const int*   ei    = (const int*)d_in[1];
  const float* ew    = (const float*)d_in[2];
  const int*   gidx  = (const int*)d_in[3];
  const float* enc   = (const float*)d_in[5 + s];
  const float* emb   = (const float*)d_in[6 + s];
  const float* ggcw  = (const float*)d_in[7 + s];
  const float* w_ih  = (const float*)d_in[8 + s];
  const float* w_hh  = (const float*)d_in[9 + s];
  const float* b_ih  = (const float*)d_in[10 + s];
  const float* b_hh  = (const float*)d_in[11 + s];
  const float* out_w = (const float*)d_in[12 + s];
  const float* out_b = (const float*)d_in[13 + s];
  float* out = (float*)d_out;

  int N   = in_sizes[0];
  int E   = in_sizes[2];
  int BL  = in_sizes[3];
  int H   = in_sizes[5 + s] / BL;
  int LG  = in_sizes[7 + s] / (H * H);
  int OUT = in_sizes[12 + s] / (2 * H);

  size_t nh = (size_t)N * H;
  size_t hh3 = (size_t)3 * H * H;
  int nb = cdiv(N, 256);
  char* p = (char*)d_ws;
  size_t off = 0;
  bf16* wihB  = (bf16*)(p + off); off = alg(off + hh3 * 2);
  bf16* whhB  = (bf16*)(p + off); off = alg(off + hh3 * 2);
  bf16* outwB = (bf16*)(p + off); off = alg(off + (size_t)OUT * 2 * H * 2);
  bf16* ggcwB = (bf16*)(p + off); off = alg(off + (size_t)LG * H * H * 2);
  bf16* Ucomb = (bf16*)(p + off); off = alg(off + (size_t)LG * hh3 * 2);
  bf16* hA    = (bf16*)(p + off); off = alg(off + nh * 2);
  bf16* hB    = (bf16*)(p + off); off = alg(off + nh * 2);
  bf16* shB   = (bf16*)(p + off); off = alg(off + nh * 2);
  bf16* catA  = (bf16*)(p + off); off = alg(off + (size_t)BL * 2 * H * 2);
  int* deg    = (int*)(p + off);  off = alg(off + (size_t)N * 4);
  int* rowptr = (int*)(p + off);  off = alg(off + (size_t)(N + 1) * 4);
  int* cursor = (int*)(p + off);  off = alg(off + (size_t)N * 4);
  int* srcs   = (int*)(p + off);  off = alg(off + (size_t)E * 4);
  float* wts  = (float*)(p + off); off = alg(off + (size_t)E * 4);
  int* bsum   = (int*)(p + off);  off = alg(off + (size_t)nb * 4);
  int* boff   = (int*)(p + off);  off = alg(off + (size_t)nb * 4);

  // weight prep
  k_cast<<<cdiv((int)hh3, 256), 256, 0, stream>>>(w_ih, wihB, (int)hh3);
  k_cast<<<cdiv((int)hh3, 256), 256, 0, stream>>>(w_hh, whhB, (int)hh3);
  k_cast<<<cdiv(OUT * 2 * H, 256), 256, 0, stream>>>(out_w, outwB, OUT * 2 * H);
  k_cast<<<cdiv(LG * H * H, 256), 256, 0, stream>>>(ggcw, ggcwB, LG * H * H);
  // Ucomb_l[c][k] = sum_p w_ih[c][p] * ggcw_l[k][p] -- all LG layers in ONE launch
  k_gemm<0><<<dim3(3 * H / 128, H / 64, LG), 256, 0, stream>>>(
      wihB, ggcwB, Ucomb, nullptr, 3 * H, H, H, (size_t)H * H, hh3);

  // embedding + CSR build (parallel hierarchical scan)
  k_embed<<<cdiv(N * H, 256), 256, 0, stream>>>(x, emb, hA, N, H);
  k_zero_i32<<<cdiv(N, 256), 256, 0, stream>>>(deg, N);
  k_hist<<<cdiv(E, 256), 256, 0, stream>>>(ei, deg, E);
  k_scan1<<<nb, 256, 0, stream>>>(deg, bsum, N);
  k_scan2<<<1, 256, 0, stream>>>(bsum, boff, nb);
  k_scan3<<<nb, 256, 0, stream>>>(deg, boff, rowptr, cursor, N);
  k_fill<<<cdiv(E, 256), 256, 0, stream>>>(ei, ew, cursor, srcs, wts, E);

  bf16* h = hA;
  bf16* hn = hB;
  for (int l = 0; l < LG; l++) {
    k_aggregate<<<cdiv(N, 4), 256, 0, stream>>>(rowptr, srcs, wts, h, shB, N, H);
    k_gru_mfma<<<dim3((H / 64) * (N / 128)), 256, 0, stream>>>(
        shB, h, Ucomb + (size_t)l * hh3, whhB, b_ih, b_hh, hn, N, H);
    bf16* t = h; h = hn; hn = t;
  }
  k_cat<<<cdiv(BL * 2 * H, 256), 256, 0, stream>>>(h, gidx, enc, catA, BL, H);
  k_gemm<1><<<dim3(BL / 128, OUT / 64, 1), 256, 0, stream>>>(
      catA, outwB, out, out_b, BL, 2 * H, OUT, 0, 0);
}

// Round 11
// 822.773 us; speedup vs baseline: 1.6030x; 1.0521x over previous
//
#include <hip/hip_runtime.h>
#include <hip/hip_bf16.h>

typedef __hip_bfloat16 bf16;
typedef unsigned short u16;
typedef __attribute__((ext_vector_type(8))) short s8v;   // 8 bf16 = 4 VGPR
typedef __attribute__((ext_vector_type(4))) float f4v;   // MFMA accumulator

#define MFMA16(a, b, c) __builtin_amdgcn_mfma_f32_16x16x32_bf16((a), (b), (c), 0, 0, 0)

__device__ __forceinline__ float b2f(bf16 v) { return __bfloat162float(v); }
// fast sigmoid via v_rcp_f32 (r10: IEEE divide was the GRU epilogue cost)
__device__ __forceinline__ float sigm(float x) {
  return __builtin_amdgcn_rcpf(1.0f + __expf(-x));
}
__device__ __forceinline__ float ftanh(float x) {
  return __builtin_fmaf(2.f, sigm(2.f * x), -1.f);
}
__device__ __forceinline__ float u2f(u16 u) {
  union { float f; unsigned int i; } v; v.i = ((unsigned int)u) << 16; return v.f;
}
__device__ __forceinline__ u16 f2u(float f) {
  bf16 b = __float2bfloat16(f);
  union { bf16 b; u16 u; } v; v.b = b; return v.u;
}

// async global -> LDS, 16B per lane (global_load_lds_dwordx4)
__device__ __forceinline__ void gl16(void* lds, const void* g) {
  __builtin_amdgcn_global_load_lds(
      (const __attribute__((address_space(1))) unsigned int*)g,
      (__attribute__((address_space(3))) unsigned int*)lds, 16, 0, 0);
}

// ---------------- small utility kernels ----------------
// batched cast: 4 (src,dst) segments, one launch, 4 floats/thread
__global__ __launch_bounds__(256) void k_cast4(const float* __restrict__ s0,
                                               const float* __restrict__ s1,
                                               const float* __restrict__ s2,
                                               const float* __restrict__ s3,
                                               bf16* __restrict__ d0,
                                               bf16* __restrict__ d1,
                                               bf16* __restrict__ d2,
                                               bf16* __restrict__ d3,
                                               int q0, int q1, int q2, int q3) {
  int i = blockIdx.x * 256 + threadIdx.x;     // quad index
  const float* s; bf16* d;
  if (i < q0)            { s = s0; d = d0; }
  else if ((i -= q0) < q1) { s = s1; d = d1; }
  else if ((i -= q1) < q2) { s = s2; d = d2; }
  else if ((i -= q2) < q3) { s = s3; d = d3; }
  else return;
  float4 v = *(const float4*)(s + (size_t)i * 4);
  ushort4 o;
  o.x = f2u(v.x); o.y = f2u(v.y); o.z = f2u(v.z); o.w = f2u(v.w);
  *(ushort4*)((u16*)d + (size_t)i * 4) = o;
}

// vectorized embed: 4 elems/thread (float4 gather row-segment, 8B store)
__global__ __launch_bounds__(256) void k_embed(const int* __restrict__ x,
                                               const float* __restrict__ emb,
                                               bf16* __restrict__ h, int N, int H) {
  int idx = blockIdx.x * 256 + threadIdx.x;   // quad index
  int hq = H >> 2;
  if (idx >= N * hq) return;
  int n = idx / hq, c4 = idx - n * hq;
  float4 v = *(const float4*)(emb + (size_t)x[n] * H + c4 * 4);
  ushort4 o;
  o.x = f2u(v.x); o.y = f2u(v.y); o.z = f2u(v.z); o.w = f2u(v.w);
  *(ushort4*)((u16*)h + (size_t)idx * 4) = o;
}

// catA[r][k] = k<H ? h[gidx[r]][k] : bf16(enc[r][k-H])
__global__ __launch_bounds__(256) void k_cat(const bf16* __restrict__ h,
                                             const int* __restrict__ gidx,
                                             const float* __restrict__ enc,
                                             bf16* __restrict__ catA, int BL, int H) {
  int i = blockIdx.x * 256 + threadIdx.x;
  if (i >= BL * 2 * H) return;
  int r = i / (2 * H), k = i - r * 2 * H;
  catA[i] = (k < H) ? h[(size_t)gidx[r] * H + k]
                    : __float2bfloat16(enc[(size_t)r * H + (k - H)]);
}

// ---------------- CSR build (once per call) ----------------
__global__ __launch_bounds__(256) void k_zero_i32(int* __restrict__ p, int n) {
  int i = blockIdx.x * 256 + threadIdx.x;
  if (i < n) p[i] = 0;
}
__global__ __launch_bounds__(256) void k_hist(const int* __restrict__ ei,
                                              int* __restrict__ deg, int E) {
  int e = blockIdx.x * 256 + threadIdx.x;
  if (e < E) atomicAdd(&deg[ei[E + e]], 1);
}

// hierarchical exclusive scan of deg[N] -> rowptr[N+1] and cursor[N]
__global__ __launch_bounds__(256) void k_scan1(const int* __restrict__ deg,
                                               int* __restrict__ bsum, int N) {
  int t = threadIdx.x;
  int i = blockIdx.x * 256 + t;
  int v = (i < N) ? deg[i] : 0;
#pragma unroll
  for (int o = 32; o > 0; o >>= 1) v += __shfl_down(v, o, 64);
  __shared__ int ws[4];
  if ((t & 63) == 0) ws[t >> 6] = v;
  __syncthreads();
  if (t == 0) bsum[blockIdx.x] = ws[0] + ws[1] + ws[2] + ws[3];
}
__global__ __launch_bounds__(256) void k_scan2(const int* __restrict__ bsum,
                                               int* __restrict__ boff, int nb) {
  __shared__ int s[256];
  int t = threadIdx.x;
  int carry = 0;
  for (int base = 0; base < nb; base += 256) {
    int v = (base + t < nb) ? bsum[base + t] : 0;
    s[t] = v;
    __syncthreads();
    for (int o = 1; o < 256; o <<= 1) {
      int u = (t >= o) ? s[t - o] : 0;
      __syncthreads();
      s[t] += u;
      __syncthreads();
    }
    if (base + t < nb) boff[base + t] = carry + s[t] - v;
    carry += s[255];
    __syncthreads();
  }
}
__global__ __launch_bounds__(256) void k_scan3(const int* __restrict__ deg,
                                               const int* __restrict__ boff,
                                               int* __restrict__ rowptr,
                                               int* __restrict__ cursor, int N) {
  __shared__ int s[256];
  int t = threadIdx.x;
  int i = blockIdx.x * 256 + t;
  int v = (i < N) ? deg[i] : 0;
  s[t] = v;
  __syncthreads();
  for (int o = 1; o < 256; o <<= 1) {
    int u = (t >= o) ? s[t - o] : 0;
    __syncthreads();
    s[t] += u;
    __syncthreads();
  }
  int ex = boff[blockIdx.x] + s[t] - v;
  if (i < N) { rowptr[i] = ex; cursor[i] = ex; }
  if (i == N - 1) rowptr[N] = ex + v;
}

// fill interleaved (src, wt) pairs: ONE 8B scattered write per edge
// (was two 4B writes = two 64B-line RMWs)
__global__ __launch_bounds__(256) void k_fill(const int* __restrict__ ei,
                                              const float* __restrict__ ew,
                                              int* __restrict__ cursor,
                                              int2* __restrict__ ef, int E) {
  int e = blockIdx.x * 256 + threadIdx.x;
  if (e >= E) return;
  int d = ei[E + e];
  int pos = atomicAdd(&cursor[d], 1);
  ef[pos] = make_int2(ei[e], __float_as_int(ew[e]));
}

// sh[d][:] = sum_e wts[e] * h[srcs[e]][:]
// Half-wave split: 32 lanes x 16B cover one 512B row; halves take edge parity.
// 8-edge unroll -> 4 row-loads in flight per lane. Edge list is int2 pairs.
__global__ __launch_bounds__(256) void k_aggregate(const int* __restrict__ rowptr,
                                                   const int2* __restrict__ ef,
                                                   const bf16* __restrict__ hsrc,
                                                   bf16* __restrict__ sh,
                                                   int N, int H) {
  int wv = threadIdx.x >> 6, lane = threadIdx.x & 63;
  int d = blockIdx.x * 4 + wv;
  if (d >= N) return;
  int beg = rowptr[d], end = rowptr[d + 1];
  int half = lane >> 5;                    // 0 or 1: edge parity
  const u16* hp = (const u16*)hsrc;
  for (int c0 = (lane & 31) * 8; c0 < H; c0 += 256) {
    float f0 = 0.f, f1 = 0.f, f2 = 0.f, f3 = 0.f;
    float f4 = 0.f, f5 = 0.f, f6 = 0.f, f7 = 0.f;
    int i = beg;
    for (; i + 8 <= end; i += 8) {
      int2 eA = ef[i + half],     eB = ef[i + 2 + half];
      int2 eC = ef[i + 4 + half], eD = ef[i + 6 + half];
      float wA = __int_as_float(eA.y), wB = __int_as_float(eB.y);
      float wC = __int_as_float(eC.y), wD = __int_as_float(eD.y);
      s8v rA = *(const s8v*)(hp + (size_t)eA.x * H + c0);
      s8v rB = *(const s8v*)(hp + (size_t)eB.x * H + c0);
      s8v rC = *(const s8v*)(hp + (size_t)eC.x * H + c0);
      s8v rD = *(const s8v*)(hp + (size_t)eD.x * H + c0);
      f0 += wA * u2f((u16)rA[0]) + wB * u2f((u16)rB[0]) + wC * u2f((u16)rC[0]) + wD * u2f((u16)rD[0]);
      f1 += wA * u2f((u16)rA[1]) + wB * u2f((u16)rB[1]) + wC * u2f((u16)rC[1]) + wD * u2f((u16)rD[1]);
      f2 += wA * u2f((u16)rA[2]) + wB * u2f((u16)rB[2]) + wC * u2f((u16)rC[2]) + wD * u2f((u16)rD[2]);
      f3 += wA * u2f((u16)rA[3]) + wB * u2f((u16)rB[3]) + wC * u2f((u16)rC[3]) + wD * u2f((u16)rD[3]);
      f4 += wA * u2f((u16)rA[4]) + wB * u2f((u16)rB[4]) + wC * u2f((u16)rC[4]) + wD * u2f((u16)rD[4]);
      f5 += wA * u2f((u16)rA[5]) + wB * u2f((u16)rB[5]) + wC * u2f((u16)rC[5]) + wD * u2f((u16)rD[5]);
      f6 += wA * u2f((u16)rA[6]) + wB * u2f((u16)rB[6]) + wC * u2f((u16)rC[6]) + wD * u2f((u16)rD[6]);
      f7 += wA * u2f((u16)rA[7]) + wB * u2f((u16)rB[7]) + wC * u2f((u16)rC[7]) + wD * u2f((u16)rD[7]);
    }
    for (; i + 2 <= end; i += 2) {
      int2 eA = ef[i + half];
      float wA = __int_as_float(eA.y);
      s8v rA = *(const s8v*)(hp + (size_t)eA.x * H + c0);
      f0 += wA * u2f((u16)rA[0]); f1 += wA * u2f((u16)rA[1]);
      f2 += wA * u2f((u16)rA[2]); f3 += wA * u2f((u16)rA[3]);
      f4 += wA * u2f((u16)rA[4]); f5 += wA * u2f((u16)rA[5]);
      f6 += wA * u2f((u16)rA[6]); f7 += wA * u2f((u16)rA[7]);
    }
    if (i < end && half == 0) {            // odd-degree tail: half 0 only
      int2 eA = ef[i];
      float wA = __int_as_float(eA.y);
      s8v rA = *(const s8v*)(hp + (size_t)eA.x * H + c0);
      f0 += wA * u2f((u16)rA[0]); f1 += wA * u2f((u16)rA[1]);
      f2 += wA * u2f((u16)rA[2]); f3 += wA * u2f((u16)rA[3]);
      f4 += wA * u2f((u16)rA[4]); f5 += wA * u2f((u16)rA[5]);
      f6 += wA * u2f((u16)rA[6]); f7 += wA * u2f((u16)rA[7]);
    }
    f0 += __shfl_xor(f0, 32); f1 += __shfl_xor(f1, 32);
    f2 += __shfl_xor(f2, 32); f3 += __shfl_xor(f3, 32);
    f4 += __shfl_xor(f4, 32); f5 += __shfl_xor(f5, 32);
    f6 += __shfl_xor(f6, 32); f7 += __shfl_xor(f7, 32);
    if (half == 0) {
      s8v o;
      o[0] = (short)f2u(f0); o[1] = (short)f2u(f1);
      o[2] = (short)f2u(f2); o[3] = (short)f2u(f3);
      o[4] = (short)f2u(f4); o[5] = (short)f2u(f5);
      o[6] = (short)f2u(f6); o[7] = (short)f2u(f7);
      *(s8v*)((u16*)sh + (size_t)d * H + c0) = o;
    }
  }
}

// ---------------- MFMA GEMM: C[M,Nc] = A[M,K] @ Bt[Nc,K]^T ----------------
template <int OUT_F32>
__global__ __launch_bounds__(256) void k_gemm(const bf16* __restrict__ A,
                                              const bf16* __restrict__ Bt,
                                              void* __restrict__ Cv,
                                              const float* __restrict__ bias,
                                              int M, int K, int Nc,
                                              size_t sBt, size_t sC) {
  __shared__ short As[128][40];
  __shared__ short Bs[64][40];
  int gm = blockIdx.x * 128, gn = blockIdx.y * 64;
  Bt += (size_t)blockIdx.z * sBt;
  size_t zc = (size_t)blockIdx.z * sC;
  int tid = threadIdx.x, w = tid >> 6, lane = tid & 63;
  int l15 = lane & 15, koff = (lane >> 4) * 8;
  f4v acc[2][4];
#pragma unroll
  for (int i = 0; i < 2; i++)
#pragma unroll
    for (int j = 0; j < 4; j++) acc[i][j] = (f4v)0.f;

  for (int kt = 0; kt < K; kt += 32) {
#pragma unroll
    for (int c = 0; c < 2; c++) {
      int ch = tid + c * 256;
      int row = ch >> 2, seg = ch & 3;
      *(float4*)&As[row][seg * 8] =
          *(const float4*)(A + (size_t)(gm + row) * K + kt + seg * 8);
    }
    {
      int row = tid >> 2, seg = tid & 3;
      *(float4*)&Bs[row][seg * 8] =
          *(const float4*)(Bt + (size_t)(gn + row) * K + kt + seg * 8);
    }
    __syncthreads();
    s8v af[2], bf[4];
#pragma unroll
    for (int rt = 0; rt < 2; rt++) af[rt] = *(const s8v*)&As[w * 32 + rt * 16 + l15][koff];
#pragma unroll
    for (int ct = 0; ct < 4; ct++) bf[ct] = *(const s8v*)&Bs[ct * 16 + l15][koff];
#pragma unroll
    for (int rt = 0; rt < 2; rt++)
#pragma unroll
      for (int ct = 0; ct < 4; ct++) acc[rt][ct] = MFMA16(af[rt], bf[ct], acc[rt][ct]);
    __syncthreads();
  }
#pragma unroll
  for (int rt = 0; rt < 2; rt++)
#pragma unroll
    for (int ct = 0; ct < 4; ct++)
#pragma unroll
      for (int r = 0; r < 4; r++) {
        int row = gm + w * 32 + rt * 16 + (lane >> 4) * 4 + r;
        int col = gn + ct * 16 + l15;
        float v = acc[rt][ct][r];
        if (OUT_F32) ((float*)Cv)[zc + (size_t)row * Nc + col] = v + bias[col];
        else         ((bf16*)Cv)[zc + (size_t)row * Nc + col] = __float2bfloat16(v);
      }
}

// ---------------- fused GRU, 128x64 tile, 2-phase pipelined staging ---------
// Validated optimum structure (r6/r8/r10): full-LDS gl16 staging, static dbuf,
// one barrier per K-step, T1 XCD swizzle, __launch_bounds__(256,2), rcpf-sigm.
// (256,3) spills (r7); B-only-LDS is -12% (r8).
#define GRU_STAGE(Aarr, Harr, Barr, kt)                   \
  {                                                       \
    gl16(&Aarr[tid * 8],            Ap  + (kt));          \
    gl16(&Aarr[2048 + tid * 8],     Ap  + rstep + (kt));  \
    gl16(&Harr[tid * 8],            Hp  + (kt));          \
    gl16(&Harr[2048 + tid * 8],     Hp  + rstep + (kt));  \
    gl16(&Barr[tid * 8],            BiP + (kt));          \
    gl16(&Barr[2048 + tid * 8],     BiP + HH + (kt));     \
    gl16(&Barr[2 * 2048 + tid * 8], BiP + 2 * HH + (kt)); \
    gl16(&Barr[3 * 2048 + tid * 8], BhP + (kt));          \
    gl16(&Barr[4 * 2048 + tid * 8], BhP + HH + (kt));     \
    gl16(&Barr[5 * 2048 + tid * 8], BhP + 2 * HH + (kt)); \
  }

#define GRU_COMPUTE(Aarr, Harr, Barr)                                       \
  {                                                                         \
    s8v fa[2], fh[2];                                                       \
    _Pragma("unroll")                                                       \
    for (int rt = 0; rt < 2; rt++) {                                        \
      fa[rt] = *(const s8v*)&Aarr[(w * 32 + rt * 16 + l15) * 32 + koff];    \
      fh[rt] = *(const s8v*)&Harr[(w * 32 + rt * 16 + l15) * 32 + koff];    \
    }                                                                       \
    _Pragma("unroll")                                                       \
    for (int ct = 0; ct < 4; ct++) {                                        \
      int brow = (ct * 16 + l15) * 32 + koff;                               \
      s8v bRi = *(const s8v*)&Barr[brow];                                   \
      s8v bZi = *(const s8v*)&Barr[2048 + brow];                            \
      s8v bNi = *(const s8v*)&Barr[2 * 2048 + brow];                        \
      s8v bRh = *(const s8v*)&Barr[3 * 2048 + brow];                        \
      s8v bZh = *(const s8v*)&Barr[4 * 2048 + brow];                        \
      s8v bNh = *(const s8v*)&Barr[5 * 2048 + brow];                        \
      _Pragma("unroll")                                                     \
      for (int rt = 0; rt < 2; rt++) {                                      \
        accR[rt][ct]  = MFMA16(fa[rt], bRi, accR[rt][ct]);                  \
        accR[rt][ct]  = MFMA16(fh[rt], bRh, accR[rt][ct]);                  \
        accZ[rt][ct]  = MFMA16(fa[rt], bZi, accZ[rt][ct]);                  \
        accZ[rt][ct]  = MFMA16(fh[rt], bZh, accZ[rt][ct]);                  \
        accNi[rt][ct] = MFMA16(fa[rt], bNi, accNi[rt][ct]);                 \
        accNh[rt][ct] = MFMA16(fh[rt], bNh, accNh[rt][ct]);                 \
      }                                                                     \
    }                                                                       \
  }

__global__ __launch_bounds__(256, 2) void k_gru_mfma(const bf16* __restrict__ Ash,
                                                     const bf16* __restrict__ Ah,
                                                     const bf16* __restrict__ Wi,  // Ucomb_l [3H][H]
                                                     const bf16* __restrict__ Wh,  // w_hh [3H][H]
                                                     const float* __restrict__ bi,
                                                     const float* __restrict__ bh,
                                                     bf16* __restrict__ hn,
                                                     int M, int H) {
  __shared__ __align__(16) short Aa0[128 * 32], Aa1[128 * 32];
  __shared__ __align__(16) short Hs0[128 * 32], Hs1[128 * 32];
  __shared__ __align__(16) short Bs0[6 * 64 * 32], Bs1[6 * 64 * 32];

  // XCD-chunked bijective swizzle (grid is 1D: nwgx * nwgy blocks)
  int nwgx = H >> 6;                      // gcol blocks (4)
  int nwg = gridDim.x;
  int bid = blockIdx.x;
  int wg = bid;
  if ((nwg & 7) == 0) { int cpx = nwg >> 3; wg = (bid & 7) * cpx + (bid >> 3); }
  int gcol = (wg % nwgx) * 64;
  int gm = (wg / nwgx) * 128;

  int tid = threadIdx.x, w = tid >> 6, lane = tid & 63;
  int l15 = lane & 15, koff = (lane >> 4) * 8;
  f4v accR[2][4], accZ[2][4], accNi[2][4], accNh[2][4];
#pragma unroll
  for (int rt = 0; rt < 2; rt++)
#pragma unroll
    for (int ct = 0; ct < 4; ct++) {
      accR[rt][ct] = (f4v)0.f; accZ[rt][ct] = (f4v)0.f;
      accNi[rt][ct] = (f4v)0.f; accNh[rt][ct] = (f4v)0.f;
    }

  // per-lane staging source pointers (16B-aligned)
  int arow = tid >> 2, aseg = tid & 3;
  const bf16* Ap  = Ash + (size_t)(gm + arow) * H + aseg * 8;
  const bf16* Hp  = Ah  + (size_t)(gm + arow) * H + aseg * 8;
  const bf16* BiP = Wi  + (size_t)(gcol + arow) * H + aseg * 8;  // rows 0..63
  const bf16* BhP = Wh  + (size_t)(gcol + arow) * H + aseg * 8;
  size_t HH = (size_t)H * H;
  size_t rstep = (size_t)64 * H;

  int nk = H >> 5;                         // K-steps (8)
  GRU_STAGE(Aa0, Hs0, Bs0, 0);
  __syncthreads();                         // drains vmcnt: tile 0 ready
  for (int t = 0; t < nk; t += 2) {
    int kt = t << 5;
    if (t + 1 < nk) GRU_STAGE(Aa1, Hs1, Bs1, kt + 32);  // issue next FIRST
    GRU_COMPUTE(Aa0, Hs0, Bs0);                          // overlap with loads
    __syncthreads();                                     // one drain per step
    if (t + 2 < nk) GRU_STAGE(Aa0, Hs0, Bs0, kt + 64);
    if (t + 1 < nk) GRU_COMPUTE(Aa1, Hs1, Bs1);
    __syncthreads();
  }

#pragma unroll
  for (int ct = 0; ct < 4; ct++) {
    int col = gcol + ct * 16 + l15;
    float br  = bi[col] + bh[col];
    float bz  = bi[H + col] + bh[H + col];
    float bin = bi[2 * H + col], bhn = bh[2 * H + col];
#pragma unroll
    for (int rt = 0; rt < 2; rt++)
#pragma unroll
      for (int r = 0; r < 4; r++) {
        int row = gm + w * 32 + rt * 16 + (lane >> 4) * 4 + r;
        float rr = sigm(accR[rt][ct][r] + br);
        float zz = sigm(accZ[rt][ct][r] + bz);
        float nn = ftanh(accNi[rt][ct][r] + bin + rr * (accNh[rt][ct][r] + bhn));
        float hv = b2f(Ah[(size_t)row * H + col]);
        hn[(size_t)row * H + col] = __float2bfloat16((1.f - zz) * nn + zz * hv);
      }
  }
}

static inline size_t alg(size_t x) { return (x + 255) & ~(size_t)255; }
static inline int cdiv(int a, int b) { return (a + b - 1) / b; }

extern "C" void kernel_launch(void* const* d_in, const int* in_sizes, int n_in,
                              void* d_out, int out_size, void* d_ws, size_t ws_size,
                              hipStream_t stream) {
  (void)out_size; (void)ws_size;
  int s = (n_in >= 14) ? 0 : -1;
  const int*   x     = (const int*)d_in[0];
  const int*   ei    = (const int*)d_in[1];
  const float* ew    = (const float*)d_in[2];
  const int*   gidx  = (const int*)d_in[3];
  const float* enc   = (const float*)d_in[5 + s];
  const float* emb   = (const float*)d_in[6 + s];
  const float* ggcw  = (const float*)d_in[7 + s];
  const float* w_ih  = (const float*)d_in[8 + s];
  const float* w_hh  = (const float*)d_in[9 + s];
  const float* b_ih  = (const float*)d_in[10 + s];
  const float* b_hh  = (const float*)d_in[11 + s];
  const float* out_w = (const float*)d_in[12 + s];
  const float* out_b = (const float*)d_in[13 + s];
  float* out = (float*)d_out;

  int N   = in_sizes[0];
  int E   = in_sizes[2];
  int BL  = in_sizes[3];
  int H   = in_sizes[5 + s] / BL;
  int LG  = in_sizes[7 + s] / (H * H);
  int OUT = in_sizes[12 + s] / (2 * H);

  size_t nh = (size_t)N * H;
  size_t hh3 = (size_t)3 * H * H;
  int nb = cdiv(N, 256);
  char* p = (char*)d_ws;
  size_t off = 0;
  bf16* wihB  = (bf16*)(p + off); off = alg(off + hh3 * 2);
  bf16* whhB  = (bf16*)(p + off); off = alg(off + hh3 * 2);
  bf16* outwB = (bf16*)(p + off); off = alg(off + (size_t)OUT * 2 * H * 2);
  bf16* ggcwB = (bf16*)(p + off); off = alg(off + (size_t)LG * H * H * 2);
  bf16* Ucomb = (bf16*)(p + off); off = alg(off + (size_t)LG * hh3 * 2);
  bf16* hA    = (bf16*)(p + off); off = alg(off + nh * 2);
  bf16* hB    = (bf16*)(p + off); off = alg(off + nh * 2);
  bf16* shB   = (bf16*)(p + off); off = alg(off + nh * 2);
  bf16* catA  = (bf16*)(p + off); off = alg(off + (size_t)BL * 2 * H * 2);
  int* deg    = (int*)(p + off);  off = alg(off + (size_t)N * 4);
  int* rowptr = (int*)(p + off);  off = alg(off + (size_t)(N + 1) * 4);
  int* cursor = (int*)(p + off);  off = alg(off + (size_t)N * 4);
  int2* ef    = (int2*)(p + off); off = alg(off + (size_t)E * 8);
  int* bsum   = (int*)(p + off);  off = alg(off + (size_t)nb * 4);
  int* boff   = (int*)(p + off);  off = alg(off + (size_t)nb * 4);

  // weight prep: all four casts in ONE launch (4 floats/thread)
  int q0 = (int)(hh3 >> 2), q1 = q0, q2 = (OUT * 2 * H) >> 2,
      q3 = (LG * H * H) >> 2;
  k_cast4<<<cdiv(q0 + q1 + q2 + q3, 256), 256, 0, stream>>>(
      w_ih, w_hh, out_w, ggcw, wihB, whhB, outwB, ggcwB, q0, q1, q2, q3);
  // Ucomb_l[c][k] = sum_p w_ih[c][p] * ggcw_l[k][p] -- all LG layers in ONE launch
  k_gemm<0><<<dim3(3 * H / 128, H / 64, LG), 256, 0, stream>>>(
      wihB, ggcwB, Ucomb, nullptr, 3 * H, H, H, (size_t)H * H, hh3);

  // embedding + CSR build (parallel hierarchical scan)
  k_embed<<<cdiv(N * (H >> 2), 256), 256, 0, stream>>>(x, emb, hA, N, H);
  k_zero_i32<<<cdiv(N, 256), 256, 0, stream>>>(deg, N);
  k_hist<<<cdiv(E, 256), 256, 0, stream>>>(ei, deg, E);
  k_scan1<<<nb, 256, 0, stream>>>(deg, bsum, N);
  k_scan2<<<1, 256, 0, stream>>>(bsum, boff, nb);
  k_scan3<<<nb, 256, 0, stream>>>(deg, boff, rowptr, cursor, N);
  k_fill<<<cdiv(E, 256), 256, 0, stream>>>(ei, ew, cursor, ef, E);

  bf16* h = hA;
  bf16* hn = hB;
  for (int l = 0; l < LG; l++) {
    k_aggregate<<<cdiv(N, 4), 256, 0, stream>>>(rowptr, ef, h, shB, N, H);
    k_gru_mfma<<<dim3((H / 64) * (N / 128)), 256, 0, stream>>>(
        shB, h, Ucomb + (size_t)l * hh3, whhB, b_ih, b_hh, hn, N, H);
    bf16* t = h; h = hn; hn = t;
  }
  k_cat<<<cdiv(BL * 2 * H, 256), 256, 0, stream>>>(h, gidx, enc, catA, BL, H);
  k_gemm<1><<<dim3(BL / 128, OUT / 64, 1), 256, 0, stream>>>(
      catA, outwB, out, out_b, BL, 2 * H, OUT, 0, 0);
}

// Round 12
// 795.082 us; speedup vs baseline: 1.6589x; 1.0348x over previous
//
#include <hip/hip_runtime.h>
#include <hip/hip_bf16.h>

typedef __hip_bfloat16 bf16;
typedef unsigned short u16;
typedef __attribute__((ext_vector_type(8))) short s8v;   // 8 bf16 = 4 VGPR
typedef __attribute__((ext_vector_type(4))) float f4v;   // MFMA accumulator

#define MFMA16(a, b, c) __builtin_amdgcn_mfma_f32_16x16x32_bf16((a), (b), (c), 0, 0, 0)

__device__ __forceinline__ float b2f(bf16 v) { return __bfloat162float(v); }
// fast sigmoid via v_rcp_f32 (r10: IEEE divide was the GRU epilogue cost)
__device__ __forceinline__ float sigm(float x) {
  return __builtin_amdgcn_rcpf(1.0f + __expf(-x));
}
__device__ __forceinline__ float ftanh(float x) {
  return __builtin_fmaf(2.f, sigm(2.f * x), -1.f);
}
__device__ __forceinline__ float u2f(u16 u) {
  union { float f; unsigned int i; } v; v.i = ((unsigned int)u) << 16; return v.f;
}
__device__ __forceinline__ u16 f2u(float f) {
  bf16 b = __float2bfloat16(f);
  union { bf16 b; u16 u; } v; v.b = b; return v.u;
}

// async global -> LDS, 16B per lane (global_load_lds_dwordx4)
__device__ __forceinline__ void gl16(void* lds, const void* g) {
  __builtin_amdgcn_global_load_lds(
      (const __attribute__((address_space(1))) unsigned int*)g,
      (__attribute__((address_space(3))) unsigned int*)lds, 16, 0, 0);
}

// ---------------- fused front-of-stream prep ----------------
// embed (N*H/4 quads) + 4 weight casts (qc quads) + deg zero (nz int4s),
// all independent -> one launch.
__global__ __launch_bounds__(256) void k_prep(const int* __restrict__ x,
                                              const float* __restrict__ emb,
                                              bf16* __restrict__ h,
                                              const float* __restrict__ s0,
                                              const float* __restrict__ s1,
                                              const float* __restrict__ s2,
                                              const float* __restrict__ s3,
                                              bf16* __restrict__ d0,
                                              bf16* __restrict__ d1,
                                              bf16* __restrict__ d2,
                                              bf16* __restrict__ d3,
                                              int q0, int q1, int q2, int q3,
                                              int4* __restrict__ degz,
                                              int N, int H, int nz) {
  int i = blockIdx.x * 256 + threadIdx.x;
  int hq = H >> 2;
  int nEmb = N * hq;
  if (i < nEmb) {
    int n = i / hq, c4 = i - n * hq;
    float4 v = *(const float4*)(emb + (size_t)x[n] * H + c4 * 4);
    ushort4 o;
    o.x = f2u(v.x); o.y = f2u(v.y); o.z = f2u(v.z); o.w = f2u(v.w);
    *(ushort4*)((u16*)h + (size_t)i * 4) = o;
    return;
  }
  i -= nEmb;
  const float* s; bf16* d;
  if (i < q0)            { s = s0; d = d0; }
  else if ((i -= q0) < q1) { s = s1; d = d1; }
  else if ((i -= q1) < q2) { s = s2; d = d2; }
  else if ((i -= q2) < q3) { s = s3; d = d3; }
  else {
    i -= q3;
    if (i < nz) degz[i] = make_int4(0, 0, 0, 0);
    return;
  }
  float4 v = *(const float4*)(s + (size_t)i * 4);
  ushort4 o;
  o.x = f2u(v.x); o.y = f2u(v.y); o.z = f2u(v.z); o.w = f2u(v.w);
  *(ushort4*)((u16*)d + (size_t)i * 4) = o;
}

// catA[r][k] = k<H ? h[gidx[r]][k] : bf16(enc[r][k-H])
__global__ __launch_bounds__(256) void k_cat(const bf16* __restrict__ h,
                                             const int* __restrict__ gidx,
                                             const float* __restrict__ enc,
                                             bf16* __restrict__ catA, int BL, int H) {
  int i = blockIdx.x * 256 + threadIdx.x;
  if (i >= BL * 2 * H) return;
  int r = i / (2 * H), k = i - r * 2 * H;
  catA[i] = (k < H) ? h[(size_t)gidx[r] * H + k]
                    : __float2bfloat16(enc[(size_t)r * H + (k - H)]);
}

// ---------------- CSR build (once per call) ----------------
// XCD-partitioned histogram: block handles dest-range (blockIdx&7) only.
// blockIdx%8 == XCD (same heuristic as the GRU T1 swizzle, validated r6) ->
// all atomics to a given deg region come from ONE XCD -> no L2 line bouncing.
// Correct regardless of the actual block->XCD mapping.
__global__ __launch_bounds__(256) void k_hist(const int* __restrict__ ei,
                                              int* __restrict__ deg, int E, int N) {
  int range = blockIdx.x & 7;
  int seg = (N + 7) >> 3;
  int lo = range * seg, hi = min(N, lo + seg);
  int nb = gridDim.x >> 3, bslot = blockIdx.x >> 3;
  for (int e = bslot * 256 + threadIdx.x; e < E; e += nb * 256) {
    int d = ei[E + e];
    if (d >= lo && d < hi) atomicAdd(&deg[d], 1);
  }
}

// hierarchical exclusive scan of deg[N] -> rowptr[N+1] and cursor[N]
__global__ __launch_bounds__(256) void k_scan1(const int* __restrict__ deg,
                                               int* __restrict__ bsum, int N) {
  int t = threadIdx.x;
  int i = blockIdx.x * 256 + t;
  int v = (i < N) ? deg[i] : 0;
#pragma unroll
  for (int o = 32; o > 0; o >>= 1) v += __shfl_down(v, o, 64);
  __shared__ int ws[4];
  if ((t & 63) == 0) ws[t >> 6] = v;
  __syncthreads();
  if (t == 0) bsum[blockIdx.x] = ws[0] + ws[1] + ws[2] + ws[3];
}
__global__ __launch_bounds__(256) void k_scan2(const int* __restrict__ bsum,
                                               int* __restrict__ boff, int nb) {
  __shared__ int s[256];
  int t = threadIdx.x;
  int carry = 0;
  for (int base = 0; base < nb; base += 256) {
    int v = (base + t < nb) ? bsum[base + t] : 0;
    s[t] = v;
    __syncthreads();
    for (int o = 1; o < 256; o <<= 1) {
      int u = (t >= o) ? s[t - o] : 0;
      __syncthreads();
      s[t] += u;
      __syncthreads();
    }
    if (base + t < nb) boff[base + t] = carry + s[t] - v;
    carry += s[255];
    __syncthreads();
  }
}
__global__ __launch_bounds__(256) void k_scan3(const int* __restrict__ deg,
                                               const int* __restrict__ boff,
                                               int* __restrict__ rowptr,
                                               int* __restrict__ cursor, int N) {
  __shared__ int s[256];
  int t = threadIdx.x;
  int i = blockIdx.x * 256 + t;
  int v = (i < N) ? deg[i] : 0;
  s[t] = v;
  __syncthreads();
  for (int o = 1; o < 256; o <<= 1) {
    int u = (t >= o) ? s[t - o] : 0;
    __syncthreads();
    s[t] += u;
    __syncthreads();
  }
  int ex = boff[blockIdx.x] + s[t] - v;
  if (i < N) { rowptr[i] = ex; cursor[i] = ex; }
  if (i == N - 1) rowptr[N] = ex + v;
}

// XCD-partitioned CSR fill (r11 post-mortem): k_fill's 8x write amplification
// (WRITE 65.8 MB for an 8 MB array) came from CSR-line sharing across XCDs'
// non-coherent L2s. Partition dest space into 8 ranges; only blocks with
// blockIdx%8 == r write range r -> same-line writes come from one XCD ->
// lines coalesce in its L2 (~1x writeback). Cost: 8x streaming re-read of the
// dst array (+~5us). Correct even if block->XCD mapping differs.
__global__ __launch_bounds__(256) void k_fill(const int* __restrict__ ei,
                                              const float* __restrict__ ew,
                                              int* __restrict__ cursor,
                                              int2* __restrict__ ef, int E, int N) {
  int range = blockIdx.x & 7;
  int seg = (N + 7) >> 3;
  int lo = range * seg, hi = min(N, lo + seg);
  int nb = gridDim.x >> 3, bslot = blockIdx.x >> 3;
  for (int e = bslot * 256 + threadIdx.x; e < E; e += nb * 256) {
    int d = ei[E + e];
    if (d >= lo && d < hi) {
      int pos = atomicAdd(&cursor[d], 1);
      ef[pos] = make_int2(ei[e], __float_as_int(ew[e]));
    }
  }
}

// sh[d][:] = sum_e wts[e] * h[srcs[e]][:]
// Half-wave split: 32 lanes x 16B cover one 512B row; halves take edge parity.
// 8-edge unroll -> 4 row-loads in flight per lane. Edge list is int2 pairs.
__global__ __launch_bounds__(256) void k_aggregate(const int* __restrict__ rowptr,
                                                   const int2* __restrict__ ef,
                                                   const bf16* __restrict__ hsrc,
                                                   bf16* __restrict__ sh,
                                                   int N, int H) {
  int wv = threadIdx.x >> 6, lane = threadIdx.x & 63;
  int d = blockIdx.x * 4 + wv;
  if (d >= N) return;
  int beg = rowptr[d], end = rowptr[d + 1];
  int half = lane >> 5;                    // 0 or 1: edge parity
  const u16* hp = (const u16*)hsrc;
  for (int c0 = (lane & 31) * 8; c0 < H; c0 += 256) {
    float f0 = 0.f, f1 = 0.f, f2 = 0.f, f3 = 0.f;
    float f4 = 0.f, f5 = 0.f, f6 = 0.f, f7 = 0.f;
    int i = beg;
    for (; i + 8 <= end; i += 8) {
      int2 eA = ef[i + half],     eB = ef[i + 2 + half];
      int2 eC = ef[i + 4 + half], eD = ef[i + 6 + half];
      float wA = __int_as_float(eA.y), wB = __int_as_float(eB.y);
      float wC = __int_as_float(eC.y), wD = __int_as_float(eD.y);
      s8v rA = *(const s8v*)(hp + (size_t)eA.x * H + c0);
      s8v rB = *(const s8v*)(hp + (size_t)eB.x * H + c0);
      s8v rC = *(const s8v*)(hp + (size_t)eC.x * H + c0);
      s8v rD = *(const s8v*)(hp + (size_t)eD.x * H + c0);
      f0 += wA * u2f((u16)rA[0]) + wB * u2f((u16)rB[0]) + wC * u2f((u16)rC[0]) + wD * u2f((u16)rD[0]);
      f1 += wA * u2f((u16)rA[1]) + wB * u2f((u16)rB[1]) + wC * u2f((u16)rC[1]) + wD * u2f((u16)rD[1]);
      f2 += wA * u2f((u16)rA[2]) + wB * u2f((u16)rB[2]) + wC * u2f((u16)rC[2]) + wD * u2f((u16)rD[2]);
      f3 += wA * u2f((u16)rA[3]) + wB * u2f((u16)rB[3]) + wC * u2f((u16)rC[3]) + wD * u2f((u16)rD[3]);
      f4 += wA * u2f((u16)rA[4]) + wB * u2f((u16)rB[4]) + wC * u2f((u16)rC[4]) + wD * u2f((u16)rD[4]);
      f5 += wA * u2f((u16)rA[5]) + wB * u2f((u16)rB[5]) + wC * u2f((u16)rC[5]) + wD * u2f((u16)rD[5]);
      f6 += wA * u2f((u16)rA[6]) + wB * u2f((u16)rB[6]) + wC * u2f((u16)rC[6]) + wD * u2f((u16)rD[6]);
      f7 += wA * u2f((u16)rA[7]) + wB * u2f((u16)rB[7]) + wC * u2f((u16)rC[7]) + wD * u2f((u16)rD[7]);
    }
    for (; i + 2 <= end; i += 2) {
      int2 eA = ef[i + half];
      float wA = __int_as_float(eA.y);
      s8v rA = *(const s8v*)(hp + (size_t)eA.x * H + c0);
      f0 += wA * u2f((u16)rA[0]); f1 += wA * u2f((u16)rA[1]);
      f2 += wA * u2f((u16)rA[2]); f3 += wA * u2f((u16)rA[3]);
      f4 += wA * u2f((u16)rA[4]); f5 += wA * u2f((u16)rA[5]);
      f6 += wA * u2f((u16)rA[6]); f7 += wA * u2f((u16)rA[7]);
    }
    if (i < end && half == 0) {            // odd-degree tail: half 0 only
      int2 eA = ef[i];
      float wA = __int_as_float(eA.y);
      s8v rA = *(const s8v*)(hp + (size_t)eA.x * H + c0);
      f0 += wA * u2f((u16)rA[0]); f1 += wA * u2f((u16)rA[1]);
      f2 += wA * u2f((u16)rA[2]); f3 += wA * u2f((u16)rA[3]);
      f4 += wA * u2f((u16)rA[4]); f5 += wA * u2f((u16)rA[5]);
      f6 += wA * u2f((u16)rA[6]); f7 += wA * u2f((u16)rA[7]);
    }
    f0 += __shfl_xor(f0, 32); f1 += __shfl_xor(f1, 32);
    f2 += __shfl_xor(f2, 32); f3 += __shfl_xor(f3, 32);
    f4 += __shfl_xor(f4, 32); f5 += __shfl_xor(f5, 32);
    f6 += __shfl_xor(f6, 32); f7 += __shfl_xor(f7, 32);
    if (half == 0) {
      s8v o;
      o[0] = (short)f2u(f0); o[1] = (short)f2u(f1);
      o[2] = (short)f2u(f2); o[3] = (short)f2u(f3);
      o[4] = (short)f2u(f4); o[5] = (short)f2u(f5);
      o[6] = (short)f2u(f6); o[7] = (short)f2u(f7);
      *(s8v*)((u16*)sh + (size_t)d * H + c0) = o;
    }
  }
}

// ---------------- MFMA GEMM: C[M,Nc] = A[M,K] @ Bt[Nc,K]^T ----------------
template <int OUT_F32>
__global__ __launch_bounds__(256) void k_gemm(const bf16* __restrict__ A,
                                              const bf16* __restrict__ Bt,
                                              void* __restrict__ Cv,
                                              const float* __restrict__ bias,
                                              int M, int K, int Nc,
                                              size_t sBt, size_t sC) {
  __shared__ short As[128][40];
  __shared__ short Bs[64][40];
  int gm = blockIdx.x * 128, gn = blockIdx.y * 64;
  Bt += (size_t)blockIdx.z * sBt;
  size_t zc = (size_t)blockIdx.z * sC;
  int tid = threadIdx.x, w = tid >> 6, lane = tid & 63;
  int l15 = lane & 15, koff = (lane >> 4) * 8;
  f4v acc[2][4];
#pragma unroll
  for (int i = 0; i < 2; i++)
#pragma unroll
    for (int j = 0; j < 4; j++) acc[i][j] = (f4v)0.f;

  for (int kt = 0; kt < K; kt += 32) {
#pragma unroll
    for (int c = 0; c < 2; c++) {
      int ch = tid + c * 256;
      int row = ch >> 2, seg = ch & 3;
      *(float4*)&As[row][seg * 8] =
          *(const float4*)(A + (size_t)(gm + row) * K + kt + seg * 8);
    }
    {
      int row = tid >> 2, seg = tid & 3;
      *(float4*)&Bs[row][seg * 8] =
          *(const float4*)(Bt + (size_t)(gn + row) * K + kt + seg * 8);
    }
    __syncthreads();
    s8v af[2], bf[4];
#pragma unroll
    for (int rt = 0; rt < 2; rt++) af[rt] = *(const s8v*)&As[w * 32 + rt * 16 + l15][koff];
#pragma unroll
    for (int ct = 0; ct < 4; ct++) bf[ct] = *(const s8v*)&Bs[ct * 16 + l15][koff];
#pragma unroll
    for (int rt = 0; rt < 2; rt++)
#pragma unroll
      for (int ct = 0; ct < 4; ct++) acc[rt][ct] = MFMA16(af[rt], bf[ct], acc[rt][ct]);
    __syncthreads();
  }
#pragma unroll
  for (int rt = 0; rt < 2; rt++)
#pragma unroll
    for (int ct = 0; ct < 4; ct++)
#pragma unroll
      for (int r = 0; r < 4; r++) {
        int row = gm + w * 32 + rt * 16 + (lane >> 4) * 4 + r;
        int col = gn + ct * 16 + l15;
        float v = acc[rt][ct][r];
        if (OUT_F32) ((float*)Cv)[zc + (size_t)row * Nc + col] = v + bias[col];
        else         ((bf16*)Cv)[zc + (size_t)row * Nc + col] = __float2bfloat16(v);
      }
}

// ---------------- fused GRU, 128x64 tile, 2-phase pipelined staging ---------
// Validated optimum structure (r6/r8/r10): full-LDS gl16 staging, static dbuf,
// one barrier per K-step, T1 XCD swizzle, __launch_bounds__(256,2), rcpf-sigm.
// (256,3) spills (r7); B-only-LDS is -12% (r8).
#define GRU_STAGE(Aarr, Harr, Barr, kt)                   \
  {                                                       \
    gl16(&Aarr[tid * 8],            Ap  + (kt));          \
    gl16(&Aarr[2048 + tid * 8],     Ap  + rstep + (kt));  \
    gl16(&Harr[tid * 8],            Hp  + (kt));          \
    gl16(&Harr[2048 + tid * 8],     Hp  + rstep + (kt));  \
    gl16(&Barr[tid * 8],            BiP + (kt));          \
    gl16(&Barr[2048 + tid * 8],     BiP + HH + (kt));     \
    gl16(&Barr[2 * 2048 + tid * 8], BiP + 2 * HH + (kt)); \
    gl16(&Barr[3 * 2048 + tid * 8], BhP + (kt));          \
    gl16(&Barr[4 * 2048 + tid * 8], BhP + HH + (kt));     \
    gl16(&Barr[5 * 2048 + tid * 8], BhP + 2 * HH + (kt)); \
  }

#define GRU_COMPUTE(Aarr, Harr, Barr)                                       \
  {                                                                         \
    s8v fa[2], fh[2];                                                       \
    _Pragma("unroll")                                                       \
    for (int rt = 0; rt < 2; rt++) {                                        \
      fa[rt] = *(const s8v*)&Aarr[(w * 32 + rt * 16 + l15) * 32 + koff];    \
      fh[rt] = *(const s8v*)&Harr[(w * 32 + rt * 16 + l15) * 32 + koff];    \
    }                                                                       \
    _Pragma("unroll")                                                       \
    for (int ct = 0; ct < 4; ct++) {                                        \
      int brow = (ct * 16 + l15) * 32 + koff;                               \
      s8v bRi = *(const s8v*)&Barr[brow];                                   \
      s8v bZi = *(const s8v*)&Barr[2048 + brow];                            \
      s8v bNi = *(const s8v*)&Barr[2 * 2048 + brow];                        \
      s8v bRh = *(const s8v*)&Barr[3 * 2048 + brow];                        \
      s8v bZh = *(const s8v*)&Barr[4 * 2048 + brow];                        \
      s8v bNh = *(const s8v*)&Barr[5 * 2048 + brow];                        \
      _Pragma("unroll")                                                     \
      for (int rt = 0; rt < 2; rt++) {                                      \
        accR[rt][ct]  = MFMA16(fa[rt], bRi, accR[rt][ct]);                  \
        accR[rt][ct]  = MFMA16(fh[rt], bRh, accR[rt][ct]);                  \
        accZ[rt][ct]  = MFMA16(fa[rt], bZi, accZ[rt][ct]);                  \
        accZ[rt][ct]  = MFMA16(fh[rt], bZh, accZ[rt][ct]);                  \
        accNi[rt][ct] = MFMA16(fa[rt], bNi, accNi[rt][ct]);                 \
        accNh[rt][ct] = MFMA16(fh[rt], bNh, accNh[rt][ct]);                 \
      }                                                                     \
    }                                                                       \
  }

__global__ __launch_bounds__(256, 2) void k_gru_mfma(const bf16* __restrict__ Ash,
                                                     const bf16* __restrict__ Ah,
                                                     const bf16* __restrict__ Wi,  // Ucomb_l [3H][H]
                                                     const bf16* __restrict__ Wh,  // w_hh [3H][H]
                                                     const float* __restrict__ bi,
                                                     const float* __restrict__ bh,
                                                     bf16* __restrict__ hn,
                                                     int M, int H) {
  __shared__ __align__(16) short Aa0[128 * 32], Aa1[128 * 32];
  __shared__ __align__(16) short Hs0[128 * 32], Hs1[128 * 32];
  __shared__ __align__(16) short Bs0[6 * 64 * 32], Bs1[6 * 64 * 32];

  // XCD-chunked bijective swizzle (grid is 1D: nwgx * nwgy blocks)
  int nwgx = H >> 6;                      // gcol blocks (4)
  int nwg = gridDim.x;
  int bid = blockIdx.x;
  int wg = bid;
  if ((nwg & 7) == 0) { int cpx = nwg >> 3; wg = (bid & 7) * cpx + (bid >> 3); }
  int gcol = (wg % nwgx) * 64;
  int gm = (wg / nwgx) * 128;

  int tid = threadIdx.x, w = tid >> 6, lane = tid & 63;
  int l15 = lane & 15, koff = (lane >> 4) * 8;
  f4v accR[2][4], accZ[2][4], accNi[2][4], accNh[2][4];
#pragma unroll
  for (int rt = 0; rt < 2; rt++)
#pragma unroll
    for (int ct = 0; ct < 4; ct++) {
      accR[rt][ct] = (f4v)0.f; accZ[rt][ct] = (f4v)0.f;
      accNi[rt][ct] = (f4v)0.f; accNh[rt][ct] = (f4v)0.f;
    }

  // per-lane staging source pointers (16B-aligned)
  int arow = tid >> 2, aseg = tid & 3;
  const bf16* Ap  = Ash + (size_t)(gm + arow) * H + aseg * 8;
  const bf16* Hp  = Ah  + (size_t)(gm + arow) * H + aseg * 8;
  const bf16* BiP = Wi  + (size_t)(gcol + arow) * H + aseg * 8;  // rows 0..63
  const bf16* BhP = Wh  + (size_t)(gcol + arow) * H + aseg * 8;
  size_t HH = (size_t)H * H;
  size_t rstep = (size_t)64 * H;

  int nk = H >> 5;                         // K-steps (8)
  GRU_STAGE(Aa0, Hs0, Bs0, 0);
  __syncthreads();                         // drains vmcnt: tile 0 ready
  for (int t = 0; t < nk; t += 2) {
    int kt = t << 5;
    if (t + 1 < nk) GRU_STAGE(Aa1, Hs1, Bs1, kt + 32);  // issue next FIRST
    GRU_COMPUTE(Aa0, Hs0, Bs0);                          // overlap with loads
    __syncthreads();                                     // one drain per step
    if (t + 2 < nk) GRU_STAGE(Aa0, Hs0, Bs0, kt + 64);
    if (t + 1 < nk) GRU_COMPUTE(Aa1, Hs1, Bs1);
    __syncthreads();
  }

#pragma unroll
  for (int ct = 0; ct < 4; ct++) {
    int col = gcol + ct * 16 + l15;
    float br  = bi[col] + bh[col];
    float bz  = bi[H + col] + bh[H + col];
    float bin = bi[2 * H + col], bhn = bh[2 * H + col];
#pragma unroll
    for (int rt = 0; rt < 2; rt++)
#pragma unroll
      for (int r = 0; r < 4; r++) {
        int row = gm + w * 32 + rt * 16 + (lane >> 4) * 4 + r;
        float rr = sigm(accR[rt][ct][r] + br);
        float zz = sigm(accZ[rt][ct][r] + bz);
        float nn = ftanh(accNi[rt][ct][r] + bin + rr * (accNh[rt][ct][r] + bhn));
        float hv = b2f(Ah[(size_t)row * H + col]);
        hn[(size_t)row * H + col] = __float2bfloat16((1.f - zz) * nn + zz * hv);
      }
  }
}

static inline size_t alg(size_t x) { return (x + 255) & ~(size_t)255; }
static inline int cdiv(int a, int b) { return (a + b - 1) / b; }

extern "C" void kernel_launch(void* const* d_in, const int* in_sizes, int n_in,
                              void* d_out, int out_size, void* d_ws, size_t ws_size,
                              hipStream_t stream) {
  (void)out_size; (void)ws_size;
  int s = (n_in >= 14) ? 0 : -1;
  const int*   x     = (const int*)d_in[0];
  const int*   ei    = (const int*)d_in[1];
  const float* ew    = (const float*)d_in[2];
  const int*   gidx  = (const int*)d_in[3];
  const float* enc   = (const float*)d_in[5 + s];
  const float* emb   = (const float*)d_in[6 + s];
  const float* ggcw  = (const float*)d_in[7 + s];
  const float* w_ih  = (const float*)d_in[8 + s];
  const float* w_hh  = (const float*)d_in[9 + s];
  const float* b_ih  = (const float*)d_in[10 + s];
  const float* b_hh  = (const float*)d_in[11 + s];
  const float* out_w = (const float*)d_in[12 + s];
  const float* out_b = (const float*)d_in[13 + s];
  float* out = (float*)d_out;

  int N   = in_sizes[0];
  int E   = in_sizes[2];
  int BL  = in_sizes[3];
  int H   = in_sizes[5 + s] / BL;
  int LG  = in_sizes[7 + s] / (H * H);
  int OUT = in_sizes[12 + s] / (2 * H);

  size_t nh = (size_t)N * H;
  size_t hh3 = (size_t)3 * H * H;
  int nb = cdiv(N, 256);
  char* p = (char*)d_ws;
  size_t off = 0;
  bf16* wihB  = (bf16*)(p + off); off = alg(off + hh3 * 2);
  bf16* whhB  = (bf16*)(p + off); off = alg(off + hh3 * 2);
  bf16* outwB = (bf16*)(p + off); off = alg(off + (size_t)OUT * 2 * H * 2);
  bf16* ggcwB = (bf16*)(p + off); off = alg(off + (size_t)LG * H * H * 2);
  bf16* Ucomb = (bf16*)(p + off); off = alg(off + (size_t)LG * hh3 * 2);
  bf16* hA    = (bf16*)(p + off); off = alg(off + nh * 2);
  bf16* hB    = (bf16*)(p + off); off = alg(off + nh * 2);
  bf16* shB   = (bf16*)(p + off); off = alg(off + nh * 2);
  bf16* catA  = (bf16*)(p + off); off = alg(off + (size_t)BL * 2 * H * 2);
  int* deg    = (int*)(p + off);  off = alg(off + (size_t)cdiv(N, 4) * 16);
  int* rowptr = (int*)(p + off);  off = alg(off + (size_t)(N + 1) * 4);
  int* cursor = (int*)(p + off);  off = alg(off + (size_t)N * 4);
  int2* ef    = (int2*)(p + off); off = alg(off + (size_t)E * 8);
  int* bsum   = (int*)(p + off);  off = alg(off + (size_t)nb * 4);
  int* boff   = (int*)(p + off);  off = alg(off + (size_t)nb * 4);

  // fused prep: embed + 4 weight casts + deg zero, one launch
  int q0 = (int)(hh3 >> 2), q1 = q0, q2 = (OUT * 2 * H) >> 2,
      q3 = (LG * H * H) >> 2;
  int nz = cdiv(N, 4);
  int prep_total = N * (H >> 2) + q0 + q1 + q2 + q3 + nz;
  k_prep<<<cdiv(prep_total, 256), 256, 0, stream>>>(
      x, emb, hA, w_ih, w_hh, out_w, ggcw, wihB, whhB, outwB, ggcwB,
      q0, q1, q2, q3, (int4*)deg, N, H, nz);
  // Ucomb_l[c][k] = sum_p w_ih[c][p] * ggcw_l[k][p] -- all LG layers in ONE launch
  k_gemm<0><<<dim3(3 * H / 128, H / 64, LG), 256, 0, stream>>>(
      wihB, ggcwB, Ucomb, nullptr, 3 * H, H, H, (size_t)H * H, hh3);

  // CSR build (XCD-partitioned hist/fill + parallel hierarchical scan)
  k_hist<<<2048, 256, 0, stream>>>(ei, deg, E, N);
  k_scan1<<<nb, 256, 0, stream>>>(deg, bsum, N);
  k_scan2<<<1, 256, 0, stream>>>(bsum, boff, nb);
  k_scan3<<<nb, 256, 0, stream>>>(deg, boff, rowptr, cursor, N);
  k_fill<<<2048, 256, 0, stream>>>(ei, ew, cursor, ef, E, N);

  bf16* h = hA;
  bf16* hn = hB;
  for (int l = 0; l < LG; l++) {
    k_aggregate<<<cdiv(N, 4), 256, 0, stream>>>(rowptr, ef, h, shB, N, H);
    k_gru_mfma<<<dim3((H / 64) * (N / 128)), 256, 0, stream>>>(
        shB, h, Ucomb + (size_t)l * hh3, whhB, b_ih, b_hh, hn, N, H);
    bf16* t = h; h = hn; hn = t;
  }
  k_cat<<<cdiv(BL * 2 * H, 256), 256, 0, stream>>>(h, gidx, enc, catA, BL, H);
  k_gemm<1><<<dim3(BL / 128, OUT / 64, 1), 256, 0, stream>>>(
      catA, outwB, out, out_b, BL, 2 * H, OUT, 0, 0);
}

// Round 13
// 781.174 us; speedup vs baseline: 1.6884x; 1.0178x over previous
//
#include <hip/hip_runtime.h>
#include <hip/hip_bf16.h>

typedef __hip_bfloat16 bf16;
typedef unsigned short u16;
typedef __attribute__((ext_vector_type(8))) short s8v;   // 8 bf16 = 4 VGPR
typedef __attribute__((ext_vector_type(4))) float f4v;   // MFMA accumulator

#define MFMA16(a, b, c) __builtin_amdgcn_mfma_f32_16x16x32_bf16((a), (b), (c), 0, 0, 0)

__device__ __forceinline__ float b2f(bf16 v) { return __bfloat162float(v); }
// fast sigmoid via v_rcp_f32 (r10: IEEE divide was the GRU epilogue cost)
__device__ __forceinline__ float sigm(float x) {
  return __builtin_amdgcn_rcpf(1.0f + __expf(-x));
}
__device__ __forceinline__ float ftanh(float x) {
  return __builtin_fmaf(2.f, sigm(2.f * x), -1.f);
}
__device__ __forceinline__ float u2f(u16 u) {
  union { float f; unsigned int i; } v; v.i = ((unsigned int)u) << 16; return v.f;
}
__device__ __forceinline__ u16 f2u(float f) {
  bf16 b = __float2bfloat16(f);
  union { bf16 b; u16 u; } v; v.b = b; return v.u;
}

// async global -> LDS, 16B per lane (global_load_lds_dwordx4)
__device__ __forceinline__ void gl16(void* lds, const void* g) {
  __builtin_amdgcn_global_load_lds(
      (const __attribute__((address_space(1))) unsigned int*)g,
      (__attribute__((address_space(3))) unsigned int*)lds, 16, 0, 0);
}

// ---------------- fused front-of-stream prep ----------------
// embed (N*H/4 quads) + 4 weight casts (qc quads) + deg zero (nz int4s),
// all independent -> one launch.
__global__ __launch_bounds__(256) void k_prep(const int* __restrict__ x,
                                              const float* __restrict__ emb,
                                              bf16* __restrict__ h,
                                              const float* __restrict__ s0,
                                              const float* __restrict__ s1,
                                              const float* __restrict__ s2,
                                              const float* __restrict__ s3,
                                              bf16* __restrict__ d0,
                                              bf16* __restrict__ d1,
                                              bf16* __restrict__ d2,
                                              bf16* __restrict__ d3,
                                              int q0, int q1, int q2, int q3,
                                              int4* __restrict__ degz,
                                              int N, int H, int nz) {
  int i = blockIdx.x * 256 + threadIdx.x;
  int hq = H >> 2;
  int nEmb = N * hq;
  if (i < nEmb) {
    int n = i / hq, c4 = i - n * hq;
    float4 v = *(const float4*)(emb + (size_t)x[n] * H + c4 * 4);
    ushort4 o;
    o.x = f2u(v.x); o.y = f2u(v.y); o.z = f2u(v.z); o.w = f2u(v.w);
    *(ushort4*)((u16*)h + (size_t)i * 4) = o;
    return;
  }
  i -= nEmb;
  const float* s; bf16* d;
  if (i < q0)            { s = s0; d = d0; }
  else if ((i -= q0) < q1) { s = s1; d = d1; }
  else if ((i -= q1) < q2) { s = s2; d = d2; }
  else if ((i -= q2) < q3) { s = s3; d = d3; }
  else {
    i -= q3;
    if (i < nz) degz[i] = make_int4(0, 0, 0, 0);
    return;
  }
  float4 v = *(const float4*)(s + (size_t)i * 4);
  ushort4 o;
  o.x = f2u(v.x); o.y = f2u(v.y); o.z = f2u(v.z); o.w = f2u(v.w);
  *(ushort4*)((u16*)d + (size_t)i * 4) = o;
}

// catA[r][k] = k<H ? h[gidx[r]][k] : bf16(enc[r][k-H])
__global__ __launch_bounds__(256) void k_cat(const bf16* __restrict__ h,
                                             const int* __restrict__ gidx,
                                             const float* __restrict__ enc,
                                             bf16* __restrict__ catA, int BL, int H) {
  int i = blockIdx.x * 256 + threadIdx.x;
  if (i >= BL * 2 * H) return;
  int r = i / (2 * H), k = i - r * 2 * H;
  catA[i] = (k < H) ? h[(size_t)gidx[r] * H + k]
                    : __float2bfloat16(enc[(size_t)r * H + (k - H)]);
}

// ---------------- CSR build (once per call) ----------------
// r12 post-mortem: fill's residual cost over its streaming floor is the 1M
// cursor atomicAdd RMWs on its critical path. The hist atomic's RETURN VALUE
// is the edge's rank within its dst -- free. hist captures rank[e] (dense
// coalesced 4 MB write); fill becomes a pure atomic-free scatter with
// slot = rowptr[d] + rank[e]. Sum order within a node changes (rank vs cursor
// order) -- irrelevant: f32 accumulation order was already nondeterministic.
__global__ __launch_bounds__(256) void k_hist(const int* __restrict__ ei,
                                              int* __restrict__ deg,
                                              int* __restrict__ rank, int E) {
  int e = blockIdx.x * 256 + threadIdx.x;
  if (e < E) rank[e] = atomicAdd(&deg[ei[E + e]], 1);
}

// hierarchical exclusive scan of deg[N] -> rowptr[N+1]
__global__ __launch_bounds__(256) void k_scan1(const int* __restrict__ deg,
                                               int* __restrict__ bsum, int N) {
  int t = threadIdx.x;
  int i = blockIdx.x * 256 + t;
  int v = (i < N) ? deg[i] : 0;
#pragma unroll
  for (int o = 32; o > 0; o >>= 1) v += __shfl_down(v, o, 64);
  __shared__ int ws[4];
  if ((t & 63) == 0) ws[t >> 6] = v;
  __syncthreads();
  if (t == 0) bsum[blockIdx.x] = ws[0] + ws[1] + ws[2] + ws[3];
}
__global__ __launch_bounds__(256) void k_scan2(const int* __restrict__ bsum,
                                               int* __restrict__ boff, int nb) {
  __shared__ int s[256];
  int t = threadIdx.x;
  int carry = 0;
  for (int base = 0; base < nb; base += 256) {
    int v = (base + t < nb) ? bsum[base + t] : 0;
    s[t] = v;
    __syncthreads();
    for (int o = 1; o < 256; o <<= 1) {
      int u = (t >= o) ? s[t - o] : 0;
      __syncthreads();
      s[t] += u;
      __syncthreads();
    }
    if (base + t < nb) boff[base + t] = carry + s[t] - v;
    carry += s[255];
    __syncthreads();
  }
}
__global__ __launch_bounds__(256) void k_scan3(const int* __restrict__ deg,
                                               const int* __restrict__ boff,
                                               int* __restrict__ rowptr, int N) {
  __shared__ int s[256];
  int t = threadIdx.x;
  int i = blockIdx.x * 256 + t;
  int v = (i < N) ? deg[i] : 0;
  s[t] = v;
  __syncthreads();
  for (int o = 1; o < 256; o <<= 1) {
    int u = (t >= o) ? s[t - o] : 0;
    __syncthreads();
    s[t] += u;
    __syncthreads();
  }
  int ex = boff[blockIdx.x] + s[t] - v;
  if (i < N) rowptr[i] = ex;
  if (i == N - 1) rowptr[N] = ex + v;
}

// atomic-free XCD-partitioned CSR scatter (write locality per r11: dest-range
// r handled only by blocks with blockIdx%8==r -> same-line writes from one XCD)
__global__ __launch_bounds__(256) void k_fill(const int* __restrict__ ei,
                                              const float* __restrict__ ew,
                                              const int* __restrict__ rowptr,
                                              const int* __restrict__ rank,
                                              int2* __restrict__ ef, int E, int N) {
  int range = blockIdx.x & 7;
  int seg = (N + 7) >> 3;
  int lo = range * seg, hi = min(N, lo + seg);
  int nb = gridDim.x >> 3, bslot = blockIdx.x >> 3;
  for (int e = bslot * 256 + threadIdx.x; e < E; e += nb * 256) {
    int d = ei[E + e];
    if (d >= lo && d < hi)
      ef[rowptr[d] + rank[e]] = make_int2(ei[e], __float_as_int(ew[e]));
  }
}

// sh[d][:] = sum_e wts[e] * h[srcs[e]][:]
// Half-wave split: 32 lanes x 16B cover one 512B row; halves take edge parity.
// 8-edge unroll -> 4 row-loads in flight per lane. Edge list is int2 pairs.
__global__ __launch_bounds__(256) void k_aggregate(const int* __restrict__ rowptr,
                                                   const int2* __restrict__ ef,
                                                   const bf16* __restrict__ hsrc,
                                                   bf16* __restrict__ sh,
                                                   int N, int H) {
  int wv = threadIdx.x >> 6, lane = threadIdx.x & 63;
  int d = blockIdx.x * 4 + wv;
  if (d >= N) return;
  int beg = rowptr[d], end = rowptr[d + 1];
  int half = lane >> 5;                    // 0 or 1: edge parity
  const u16* hp = (const u16*)hsrc;
  for (int c0 = (lane & 31) * 8; c0 < H; c0 += 256) {
    float f0 = 0.f, f1 = 0.f, f2 = 0.f, f3 = 0.f;
    float f4 = 0.f, f5 = 0.f, f6 = 0.f, f7 = 0.f;
    int i = beg;
    for (; i + 8 <= end; i += 8) {
      int2 eA = ef[i + half],     eB = ef[i + 2 + half];
      int2 eC = ef[i + 4 + half], eD = ef[i + 6 + half];
      float wA = __int_as_float(eA.y), wB = __int_as_float(eB.y);
      float wC = __int_as_float(eC.y), wD = __int_as_float(eD.y);
      s8v rA = *(const s8v*)(hp + (size_t)eA.x * H + c0);
      s8v rB = *(const s8v*)(hp + (size_t)eB.x * H + c0);
      s8v rC = *(const s8v*)(hp + (size_t)eC.x * H + c0);
      s8v rD = *(const s8v*)(hp + (size_t)eD.x * H + c0);
      f0 += wA * u2f((u16)rA[0]) + wB * u2f((u16)rB[0]) + wC * u2f((u16)rC[0]) + wD * u2f((u16)rD[0]);
      f1 += wA * u2f((u16)rA[1]) + wB * u2f((u16)rB[1]) + wC * u2f((u16)rC[1]) + wD * u2f((u16)rD[1]);
      f2 += wA * u2f((u16)rA[2]) + wB * u2f((u16)rB[2]) + wC * u2f((u16)rC[2]) + wD * u2f((u16)rD[2]);
      f3 += wA * u2f((u16)rA[3]) + wB * u2f((u16)rB[3]) + wC * u2f((u16)rC[3]) + wD * u2f((u16)rD[3]);
      f4 += wA * u2f((u16)rA[4]) + wB * u2f((u16)rB[4]) + wC * u2f((u16)rC[4]) + wD * u2f((u16)rD[4]);
      f5 += wA * u2f((u16)rA[5]) + wB * u2f((u16)rB[5]) + wC * u2f((u16)rC[5]) + wD * u2f((u16)rD[5]);
      f6 += wA * u2f((u16)rA[6]) + wB * u2f((u16)rB[6]) + wC * u2f((u16)rC[6]) + wD * u2f((u16)rD[6]);
      f7 += wA * u2f((u16)rA[7]) + wB * u2f((u16)rB[7]) + wC * u2f((u16)rC[7]) + wD * u2f((u16)rD[7]);
    }
    for (; i + 2 <= end; i += 2) {
      int2 eA = ef[i + half];
      float wA = __int_as_float(eA.y);
      s8v rA = *(const s8v*)(hp + (size_t)eA.x * H + c0);
      f0 += wA * u2f((u16)rA[0]); f1 += wA * u2f((u16)rA[1]);
      f2 += wA * u2f((u16)rA[2]); f3 += wA * u2f((u16)rA[3]);
      f4 += wA * u2f((u16)rA[4]); f5 += wA * u2f((u16)rA[5]);
      f6 += wA * u2f((u16)rA[6]); f7 += wA * u2f((u16)rA[7]);
    }
    if (i < end && half == 0) {            // odd-degree tail: half 0 only
      int2 eA = ef[i];
      float wA = __int_as_float(eA.y);
      s8v rA = *(const s8v*)(hp + (size_t)eA.x * H + c0);
      f0 += wA * u2f((u16)rA[0]); f1 += wA * u2f((u16)rA[1]);
      f2 += wA * u2f((u16)rA[2]); f3 += wA * u2f((u16)rA[3]);
      f4 += wA * u2f((u16)rA[4]); f5 += wA * u2f((u16)rA[5]);
      f6 += wA * u2f((u16)rA[6]); f7 += wA * u2f((u16)rA[7]);
    }
    f0 += __shfl_xor(f0, 32); f1 += __shfl_xor(f1, 32);
    f2 += __shfl_xor(f2, 32); f3 += __shfl_xor(f3, 32);
    f4 += __shfl_xor(f4, 32); f5 += __shfl_xor(f5, 32);
    f6 += __shfl_xor(f6, 32); f7 += __shfl_xor(f7, 32);
    if (half == 0) {
      s8v o;
      o[0] = (short)f2u(f0); o[1] = (short)f2u(f1);
      o[2] = (short)f2u(f2); o[3] = (short)f2u(f3);
      o[4] = (short)f2u(f4); o[5] = (short)f2u(f5);
      o[6] = (short)f2u(f6); o[7] = (short)f2u(f7);
      *(s8v*)((u16*)sh + (size_t)d * H + c0) = o;
    }
  }
}

// ---------------- MFMA GEMM: C[M,Nc] = A[M,K] @ Bt[Nc,K]^T ----------------
template <int OUT_F32>
__global__ __launch_bounds__(256) void k_gemm(const bf16* __restrict__ A,
                                              const bf16* __restrict__ Bt,
                                              void* __restrict__ Cv,
                                              const float* __restrict__ bias,
                                              int M, int K, int Nc,
                                              size_t sBt, size_t sC) {
  __shared__ short As[128][40];
  __shared__ short Bs[64][40];
  int gm = blockIdx.x * 128, gn = blockIdx.y * 64;
  Bt += (size_t)blockIdx.z * sBt;
  size_t zc = (size_t)blockIdx.z * sC;
  int tid = threadIdx.x, w = tid >> 6, lane = tid & 63;
  int l15 = lane & 15, koff = (lane >> 4) * 8;
  f4v acc[2][4];
#pragma unroll
  for (int i = 0; i < 2; i++)
#pragma unroll
    for (int j = 0; j < 4; j++) acc[i][j] = (f4v)0.f;

  for (int kt = 0; kt < K; kt += 32) {
#pragma unroll
    for (int c = 0; c < 2; c++) {
      int ch = tid + c * 256;
      int row = ch >> 2, seg = ch & 3;
      *(float4*)&As[row][seg * 8] =
          *(const float4*)(A + (size_t)(gm + row) * K + kt + seg * 8);
    }
    {
      int row = tid >> 2, seg = tid & 3;
      *(float4*)&Bs[row][seg * 8] =
          *(const float4*)(Bt + (size_t)(gn + row) * K + kt + seg * 8);
    }
    __syncthreads();
    s8v af[2], bf[4];
#pragma unroll
    for (int rt = 0; rt < 2; rt++) af[rt] = *(const s8v*)&As[w * 32 + rt * 16 + l15][koff];
#pragma unroll
    for (int ct = 0; ct < 4; ct++) bf[ct] = *(const s8v*)&Bs[ct * 16 + l15][koff];
#pragma unroll
    for (int rt = 0; rt < 2; rt++)
#pragma unroll
      for (int ct = 0; ct < 4; ct++) acc[rt][ct] = MFMA16(af[rt], bf[ct], acc[rt][ct]);
    __syncthreads();
  }
#pragma unroll
  for (int rt = 0; rt < 2; rt++)
#pragma unroll
    for (int ct = 0; ct < 4; ct++)
#pragma unroll
      for (int r = 0; r < 4; r++) {
        int row = gm + w * 32 + rt * 16 + (lane >> 4) * 4 + r;
        int col = gn + ct * 16 + l15;
        float v = acc[rt][ct][r];
        if (OUT_F32) ((float*)Cv)[zc + (size_t)row * Nc + col] = v + bias[col];
        else         ((bf16*)Cv)[zc + (size_t)row * Nc + col] = __float2bfloat16(v);
      }
}

// ---------------- fused GRU, 128x64 tile, 2-phase pipelined staging ---------
// Validated optimum structure (r6/r8/r10): full-LDS gl16 staging, static dbuf,
// one barrier per K-step, T1 XCD swizzle, __launch_bounds__(256,2), rcpf-sigm.
// (256,3) spills (r7); B-only-LDS is -12% (r8). 8-phase rejected: 4-wave/128-
// tile quadrant is measured-null (m232); LDS-read restructure rejected: 2-phase
// critical path is stage+vmcnt+barrier (m233), not LDS reads.
#define GRU_STAGE(Aarr, Harr, Barr, kt)                   \
  {                                                       \
    gl16(&Aarr[tid * 8],            Ap  + (kt));          \
    gl16(&Aarr[2048 + tid * 8],     Ap  + rstep + (kt));  \
    gl16(&Harr[tid * 8],            Hp  + (kt));          \
    gl16(&Harr[2048 + tid * 8],     Hp  + rstep + (kt));  \
    gl16(&Barr[tid * 8],            BiP + (kt));          \
    gl16(&Barr[2048 + tid * 8],     BiP + HH + (kt));     \
    gl16(&Barr[2 * 2048 + tid * 8], BiP + 2 * HH + (kt)); \
    gl16(&Barr[3 * 2048 + tid * 8], BhP + (kt));          \
    gl16(&Barr[4 * 2048 + tid * 8], BhP + HH + (kt));     \
    gl16(&Barr[5 * 2048 + tid * 8], BhP + 2 * HH + (kt)); \
  }

#define GRU_COMPUTE(Aarr, Harr, Barr)                                       \
  {                                                                         \
    s8v fa[2], fh[2];                                                       \
    _Pragma("unroll")                                                       \
    for (int rt = 0; rt < 2; rt++) {                                        \
      fa[rt] = *(const s8v*)&Aarr[(w * 32 + rt * 16 + l15) * 32 + koff];    \
      fh[rt] = *(const s8v*)&Harr[(w * 32 + rt * 16 + l15) * 32 + koff];    \
    }                                                                       \
    _Pragma("unroll")                                                       \
    for (int ct = 0; ct < 4; ct++) {                                        \
      int brow = (ct * 16 + l15) * 32 + koff;                               \
      s8v bRi = *(const s8v*)&Barr[brow];                                   \
      s8v bZi = *(const s8v*)&Barr[2048 + brow];                            \
      s8v bNi = *(const s8v*)&Barr[2 * 2048 + brow];                        \
      s8v bRh = *(const s8v*)&Barr[3 * 2048 + brow];                        \
      s8v bZh = *(const s8v*)&Barr[4 * 2048 + brow];                        \
      s8v bNh = *(const s8v*)&Barr[5 * 2048 + brow];                        \
      _Pragma("unroll")                                                     \
      for (int rt = 0; rt < 2; rt++) {                                      \
        accR[rt][ct]  = MFMA16(fa[rt], bRi, accR[rt][ct]);                  \
        accR[rt][ct]  = MFMA16(fh[rt], bRh, accR[rt][ct]);                  \
        accZ[rt][ct]  = MFMA16(fa[rt], bZi, accZ[rt][ct]);                  \
        accZ[rt][ct]  = MFMA16(fh[rt], bZh, accZ[rt][ct]);                  \
        accNi[rt][ct] = MFMA16(fa[rt], bNi, accNi[rt][ct]);                 \
        accNh[rt][ct] = MFMA16(fh[rt], bNh, accNh[rt][ct]);                 \
      }                                                                     \
    }                                                                       \
  }

__global__ __launch_bounds__(256, 2) void k_gru_mfma(const bf16* __restrict__ Ash,
                                                     const bf16* __restrict__ Ah,
                                                     const bf16* __restrict__ Wi,  // Ucomb_l [3H][H]
                                                     const bf16* __restrict__ Wh,  // w_hh [3H][H]
                                                     const float* __restrict__ bi,
                                                     const float* __restrict__ bh,
                                                     bf16* __restrict__ hn,
                                                     int M, int H) {
  __shared__ __align__(16) short Aa0[128 * 32], Aa1[128 * 32];
  __shared__ __align__(16) short Hs0[128 * 32], Hs1[128 * 32];
  __shared__ __align__(16) short Bs0[6 * 64 * 32], Bs1[6 * 64 * 32];

  // XCD-chunked bijective swizzle (grid is 1D: nwgx * nwgy blocks)
  int nwgx = H >> 6;                      // gcol blocks (4)
  int nwg = gridDim.x;
  int bid = blockIdx.x;
  int wg = bid;
  if ((nwg & 7) == 0) { int cpx = nwg >> 3; wg = (bid & 7) * cpx + (bid >> 3); }
  int gcol = (wg % nwgx) * 64;
  int gm = (wg / nwgx) * 128;

  int tid = threadIdx.x, w = tid >> 6, lane = tid & 63;
  int l15 = lane & 15, koff = (lane >> 4) * 8;
  f4v accR[2][4], accZ[2][4], accNi[2][4], accNh[2][4];
#pragma unroll
  for (int rt = 0; rt < 2; rt++)
#pragma unroll
    for (int ct = 0; ct < 4; ct++) {
      accR[rt][ct] = (f4v)0.f; accZ[rt][ct] = (f4v)0.f;
      accNi[rt][ct] = (f4v)0.f; accNh[rt][ct] = (f4v)0.f;
    }

  // per-lane staging source pointers (16B-aligned)
  int arow = tid >> 2, aseg = tid & 3;
  const bf16* Ap  = Ash + (size_t)(gm + arow) * H + aseg * 8;
  const bf16* Hp  = Ah  + (size_t)(gm + arow) * H + aseg * 8;
  const bf16* BiP = Wi  + (size_t)(gcol + arow) * H + aseg * 8;  // rows 0..63
  const bf16* BhP = Wh  + (size_t)(gcol + arow) * H + aseg * 8;
  size_t HH = (size_t)H * H;
  size_t rstep = (size_t)64 * H;

  int nk = H >> 5;                         // K-steps (8)
  GRU_STAGE(Aa0, Hs0, Bs0, 0);
  __syncthreads();                         // drains vmcnt: tile 0 ready
  for (int t = 0; t < nk; t += 2) {
    int kt = t << 5;
    if (t + 1 < nk) GRU_STAGE(Aa1, Hs1, Bs1, kt + 32);  // issue next FIRST
    GRU_COMPUTE(Aa0, Hs0, Bs0);                          // overlap with loads
    __syncthreads();                                     // one drain per step
    if (t + 2 < nk) GRU_STAGE(Aa0, Hs0, Bs0, kt + 64);
    if (t + 1 < nk) GRU_COMPUTE(Aa1, Hs1, Bs1);
    __syncthreads();
  }

#pragma unroll
  for (int ct = 0; ct < 4; ct++) {
    int col = gcol + ct * 16 + l15;
    float br  = bi[col] + bh[col];
    float bz  = bi[H + col] + bh[H + col];
    float bin = bi[2 * H + col], bhn = bh[2 * H + col];
#pragma unroll
    for (int rt = 0; rt < 2; rt++)
#pragma unroll
      for (int r = 0; r < 4; r++) {
        int row = gm + w * 32 + rt * 16 + (lane >> 4) * 4 + r;
        float rr = sigm(accR[rt][ct][r] + br);
        float zz = sigm(accZ[rt][ct][r] + bz);
        float nn = ftanh(accNi[rt][ct][r] + bin + rr * (accNh[rt][ct][r] + bhn));
        float hv = b2f(Ah[(size_t)row * H + col]);
        hn[(size_t)row * H + col] = __float2bfloat16((1.f - zz) * nn + zz * hv);
      }
  }
}

static inline size_t alg(size_t x) { return (x + 255) & ~(size_t)255; }
static inline int cdiv(int a, int b) { return (a + b - 1) / b; }

extern "C" void kernel_launch(void* const* d_in, const int* in_sizes, int n_in,
                              void* d_out, int out_size, void* d_ws, size_t ws_size,
                              hipStream_t stream) {
  (void)out_size; (void)ws_size;
  int s = (n_in >= 14) ? 0 : -1;
  const int*   x     = (const int*)d_in[0];
  const int*   ei    = (const int*)d_in[1];
  const float* ew    = (const float*)d_in[2];
  const int*   gidx  = (const int*)d_in[3];
  const float* enc   = (const float*)d_in[5 + s];
  const float* emb   = (const float*)d_in[6 + s];
  const float* ggcw  = (const float*)d_in[7 + s];
  const float* w_ih  = (const float*)d_in[8 + s];
  const float* w_hh  = (const float*)d_in[9 + s];
  const float* b_ih  = (const float*)d_in[10 + s];
  const float* b_hh  = (const float*)d_in[11 + s];
  const float* out_w = (const float*)d_in[12 + s];
  const float* out_b = (const float*)d_in[13 + s];
  float* out = (float*)d_out;

  int N   = in_sizes[0];
  int E   = in_sizes[2];
  int BL  = in_sizes[3];
  int H   = in_sizes[5 + s] / BL;
  int LG  = in_sizes[7 + s] / (H * H);
  int OUT = in_sizes[12 + s] / (2 * H);

  size_t nh = (size_t)N * H;
  size_t hh3 = (size_t)3 * H * H;
  int nb = cdiv(N, 256);
  char* p = (char*)d_ws;
  size_t off = 0;
  bf16* wihB  = (bf16*)(p + off); off = alg(off + hh3 * 2);
  bf16* whhB  = (bf16*)(p + off); off = alg(off + hh3 * 2);
  bf16* outwB = (bf16*)(p + off); off = alg(off + (size_t)OUT * 2 * H * 2);
  bf16* ggcwB = (bf16*)(p + off); off = alg(off + (size_t)LG * H * H * 2);
  bf16* Ucomb = (bf16*)(p + off); off = alg(off + (size_t)LG * hh3 * 2);
  bf16* hA    = (bf16*)(p + off); off = alg(off + nh * 2);
  bf16* hB    = (bf16*)(p + off); off = alg(off + nh * 2);
  bf16* shB   = (bf16*)(p + off); off = alg(off + nh * 2);
  bf16* catA  = (bf16*)(p + off); off = alg(off + (size_t)BL * 2 * H * 2);
  int* deg    = (int*)(p + off);  off = alg(off + (size_t)cdiv(N, 4) * 16);
  int* rowptr = (int*)(p + off);  off = alg(off + (size_t)(N + 1) * 4);
  int* rank   = (int*)(p + off);  off = alg(off + (size_t)E * 4);
  int2* ef    = (int2*)(p + off); off = alg(off + (size_t)E * 8);
  int* bsum   = (int*)(p + off);  off = alg(off + (size_t)nb * 4);
  int* boff   = (int*)(p + off);  off = alg(off + (size_t)nb * 4);

  // fused prep: embed + 4 weight casts + deg zero, one launch
  int q0 = (int)(hh3 >> 2), q1 = q0, q2 = (OUT * 2 * H) >> 2,
      q3 = (LG * H * H) >> 2;
  int nz = cdiv(N, 4);
  int prep_total = N * (H >> 2) + q0 + q1 + q2 + q3 + nz;
  k_prep<<<cdiv(prep_total, 256), 256, 0, stream>>>(
      x, emb, hA, w_ih, w_hh, out_w, ggcw, wihB, whhB, outwB, ggcwB,
      q0, q1, q2, q3, (int4*)deg, N, H, nz);
  // Ucomb_l[c][k] = sum_p w_ih[c][p] * ggcw_l[k][p] -- all LG layers in ONE launch
  k_gemm<0><<<dim3(3 * H / 128, H / 64, LG), 256, 0, stream>>>(
      wihB, ggcwB, Ucomb, nullptr, 3 * H, H, H, (size_t)H * H, hh3);

  // CSR build: hist captures per-edge rank (atomic return value); scan builds
  // rowptr; fill is an atomic-free XCD-partitioned scatter.
  k_hist<<<cdiv(E, 256), 256, 0, stream>>>(ei, deg, rank, E);
  k_scan1<<<nb, 256, 0, stream>>>(deg, bsum, N);
  k_scan2<<<1, 256, 0, stream>>>(bsum, boff, nb);
  k_scan3<<<nb, 256, 0, stream>>>(deg, boff, rowptr, N);
  k_fill<<<2048, 256, 0, stream>>>(ei, ew, rowptr, rank, ef, E, N);

  bf16* h = hA;
  bf16* hn = hB;
  for (int l = 0; l < LG; l++) {
    k_aggregate<<<cdiv(N, 4), 256, 0, stream>>>(rowptr, ef, h, shB, N, H);
    k_gru_mfma<<<dim3((H / 64) * (N / 128)), 256, 0, stream>>>(
        shB, h, Ucomb + (size_t)l * hh3, whhB, b_ih, b_hh, hn, N, H);
    bf16* t = h; h = hn; hn = t;
  }
  k_cat<<<cdiv(BL * 2 * H, 256), 256, 0, stream>>>(h, gidx, enc, catA, BL, H);
  k_gemm<1><<<dim3(BL / 128, OUT / 64, 1), 256, 0, stream>>>(
      catA, outwB, out, out_b, BL, 2 * H, OUT, 0, 0);
}

// Round 14
// 780.031 us; speedup vs baseline: 1.6909x; 1.0015x over previous
//
#include <hip/hip_runtime.h>
#include <hip/hip_bf16.h>

typedef __hip_bfloat16 bf16;
typedef unsigned short u16;
typedef __attribute__((ext_vector_type(8))) short s8v;   // 8 bf16 = 4 VGPR
typedef __attribute__((ext_vector_type(4))) float f4v;   // MFMA accumulator

#define MFMA16(a, b, c) __builtin_amdgcn_mfma_f32_16x16x32_bf16((a), (b), (c), 0, 0, 0)

__device__ __forceinline__ float b2f(bf16 v) { return __bfloat162float(v); }
// fast sigmoid via v_rcp_f32 (r10: IEEE divide was the GRU epilogue cost)
__device__ __forceinline__ float sigm(float x) {
  return __builtin_amdgcn_rcpf(1.0f + __expf(-x));
}
__device__ __forceinline__ float ftanh(float x) {
  return __builtin_fmaf(2.f, sigm(2.f * x), -1.f);
}
__device__ __forceinline__ float u2f(u16 u) {
  union { float f; unsigned int i; } v; v.i = ((unsigned int)u) << 16; return v.f;
}
__device__ __forceinline__ u16 f2u(float f) {
  bf16 b = __float2bfloat16(f);
  union { bf16 b; u16 u; } v; v.b = b; return v.u;
}

// async global -> LDS, 16B per lane (global_load_lds_dwordx4)
__device__ __forceinline__ void gl16(void* lds, const void* g) {
  __builtin_amdgcn_global_load_lds(
      (const __attribute__((address_space(1))) unsigned int*)g,
      (__attribute__((address_space(3))) unsigned int*)lds, 16, 0, 0);
}

// ---------------- fused front-of-stream prep ----------------
// embed (N*H/4 quads) + 4 weight casts (qc quads) + deg zero (nz int4s),
// all independent -> one launch.
__global__ __launch_bounds__(256) void k_prep(const int* __restrict__ x,
                                              const float* __restrict__ emb,
                                              bf16* __restrict__ h,
                                              const float* __restrict__ s0,
                                              const float* __restrict__ s1,
                                              const float* __restrict__ s2,
                                              const float* __restrict__ s3,
                                              bf16* __restrict__ d0,
                                              bf16* __restrict__ d1,
                                              bf16* __restrict__ d2,
                                              bf16* __restrict__ d3,
                                              int q0, int q1, int q2, int q3,
                                              int4* __restrict__ degz,
                                              int N, int H, int nz) {
  int i = blockIdx.x * 256 + threadIdx.x;
  int hq = H >> 2;
  int nEmb = N * hq;
  if (i < nEmb) {
    int n = i / hq, c4 = i - n * hq;
    float4 v = *(const float4*)(emb + (size_t)x[n] * H + c4 * 4);
    ushort4 o;
    o.x = f2u(v.x); o.y = f2u(v.y); o.z = f2u(v.z); o.w = f2u(v.w);
    *(ushort4*)((u16*)h + (size_t)i * 4) = o;
    return;
  }
  i -= nEmb;
  const float* s; bf16* d;
  if (i < q0)            { s = s0; d = d0; }
  else if ((i -= q0) < q1) { s = s1; d = d1; }
  else if ((i -= q1) < q2) { s = s2; d = d2; }
  else if ((i -= q2) < q3) { s = s3; d = d3; }
  else {
    i -= q3;
    if (i < nz) degz[i] = make_int4(0, 0, 0, 0);
    return;
  }
  float4 v = *(const float4*)(s + (size_t)i * 4);
  ushort4 o;
  o.x = f2u(v.x); o.y = f2u(v.y); o.z = f2u(v.z); o.w = f2u(v.w);
  *(ushort4*)((u16*)d + (size_t)i * 4) = o;
}

// catA[r][k] = k<H ? h[gidx[r]][k] : bf16(enc[r][k-H])
__global__ __launch_bounds__(256) void k_cat(const bf16* __restrict__ h,
                                             const int* __restrict__ gidx,
                                             const float* __restrict__ enc,
                                             bf16* __restrict__ catA, int BL, int H) {
  int i = blockIdx.x * 256 + threadIdx.x;
  if (i >= BL * 2 * H) return;
  int r = i / (2 * H), k = i - r * 2 * H;
  catA[i] = (k < H) ? h[(size_t)gidx[r] * H + k]
                    : __float2bfloat16(enc[(size_t)r * H + (k - H)]);
}

// ---------------- CSR build (once per call) ----------------
// hist captures per-edge rank via the atomic's return value (r12); fill is a
// pure atomic-free scatter with slot = rowptr[d] + rank[e].
__global__ __launch_bounds__(256) void k_hist(const int* __restrict__ ei,
                                              int* __restrict__ deg,
                                              int* __restrict__ rank, int E) {
  int e = blockIdx.x * 256 + threadIdx.x;
  if (e < E) rank[e] = atomicAdd(&deg[ei[E + e]], 1);
}

// hierarchical exclusive scan of deg[N] -> rowptr[N+1]
__global__ __launch_bounds__(256) void k_scan1(const int* __restrict__ deg,
                                               int* __restrict__ bsum, int N) {
  int t = threadIdx.x;
  int i = blockIdx.x * 256 + t;
  int v = (i < N) ? deg[i] : 0;
#pragma unroll
  for (int o = 32; o > 0; o >>= 1) v += __shfl_down(v, o, 64);
  __shared__ int ws[4];
  if ((t & 63) == 0) ws[t >> 6] = v;
  __syncthreads();
  if (t == 0) bsum[blockIdx.x] = ws[0] + ws[1] + ws[2] + ws[3];
}
__global__ __launch_bounds__(256) void k_scan2(const int* __restrict__ bsum,
                                               int* __restrict__ boff, int nb) {
  __shared__ int s[256];
  int t = threadIdx.x;
  int carry = 0;
  for (int base = 0; base < nb; base += 256) {
    int v = (base + t < nb) ? bsum[base + t] : 0;
    s[t] = v;
    __syncthreads();
    for (int o = 1; o < 256; o <<= 1) {
      int u = (t >= o) ? s[t - o] : 0;
      __syncthreads();
      s[t] += u;
      __syncthreads();
    }
    if (base + t < nb) boff[base + t] = carry + s[t] - v;
    carry += s[255];
    __syncthreads();
  }
}
__global__ __launch_bounds__(256) void k_scan3(const int* __restrict__ deg,
                                               const int* __restrict__ boff,
                                               int* __restrict__ rowptr, int N) {
  __shared__ int s[256];
  int t = threadIdx.x;
  int i = blockIdx.x * 256 + t;
  int v = (i < N) ? deg[i] : 0;
  s[t] = v;
  __syncthreads();
  for (int o = 1; o < 256; o <<= 1) {
    int u = (t >= o) ? s[t - o] : 0;
    __syncthreads();
    s[t] += u;
    __syncthreads();
  }
  int ex = boff[blockIdx.x] + s[t] - v;
  if (i < N) rowptr[i] = ex;
  if (i == N - 1) rowptr[N] = ex + v;
}

// atomic-free XCD-partitioned CSR scatter (write locality per r11: dest-range
// r handled only by blocks with blockIdx%8==r -> same-line writes from one XCD)
__global__ __launch_bounds__(256) void k_fill(const int* __restrict__ ei,
                                              const float* __restrict__ ew,
                                              const int* __restrict__ rowptr,
                                              const int* __restrict__ rank,
                                              int2* __restrict__ ef, int E, int N) {
  int range = blockIdx.x & 7;
  int seg = (N + 7) >> 3;
  int lo = range * seg, hi = min(N, lo + seg);
  int nb = gridDim.x >> 3, bslot = blockIdx.x >> 3;
  for (int e = bslot * 256 + threadIdx.x; e < E; e += nb * 256) {
    int d = ei[E + e];
    if (d >= lo && d < hi)
      ef[rowptr[d] + rank[e]] = make_int2(ei[e], __float_as_int(ew[e]));
  }
}

// sh[d][:] = sum_e wts[e] * h[srcs[e]][:]
// Half-wave split: 32 lanes x 16B cover one 512B row; halves take edge parity.
// 8-edge unroll -> 4 row-loads in flight per lane. Edge list is int2 pairs.
__global__ __launch_bounds__(256) void k_aggregate(const int* __restrict__ rowptr,
                                                   const int2* __restrict__ ef,
                                                   const bf16* __restrict__ hsrc,
                                                   bf16* __restrict__ sh,
                                                   int N, int H) {
  int wv = threadIdx.x >> 6, lane = threadIdx.x & 63;
  int d = blockIdx.x * 4 + wv;
  if (d >= N) return;
  int beg = rowptr[d], end = rowptr[d + 1];
  int half = lane >> 5;                    // 0 or 1: edge parity
  const u16* hp = (const u16*)hsrc;
  for (int c0 = (lane & 31) * 8; c0 < H; c0 += 256) {
    float f0 = 0.f, f1 = 0.f, f2 = 0.f, f3 = 0.f;
    float f4 = 0.f, f5 = 0.f, f6 = 0.f, f7 = 0.f;
    int i = beg;
    for (; i + 8 <= end; i += 8) {
      int2 eA = ef[i + half],     eB = ef[i + 2 + half];
      int2 eC = ef[i + 4 + half], eD = ef[i + 6 + half];
      float wA = __int_as_float(eA.y), wB = __int_as_float(eB.y);
      float wC = __int_as_float(eC.y), wD = __int_as_float(eD.y);
      s8v rA = *(const s8v*)(hp + (size_t)eA.x * H + c0);
      s8v rB = *(const s8v*)(hp + (size_t)eB.x * H + c0);
      s8v rC = *(const s8v*)(hp + (size_t)eC.x * H + c0);
      s8v rD = *(const s8v*)(hp + (size_t)eD.x * H + c0);
      f0 += wA * u2f((u16)rA[0]) + wB * u2f((u16)rB[0]) + wC * u2f((u16)rC[0]) + wD * u2f((u16)rD[0]);
      f1 += wA * u2f((u16)rA[1]) + wB * u2f((u16)rB[1]) + wC * u2f((u16)rC[1]) + wD * u2f((u16)rD[1]);
      f2 += wA * u2f((u16)rA[2]) + wB * u2f((u16)rB[2]) + wC * u2f((u16)rC[2]) + wD * u2f((u16)rD[2]);
      f3 += wA * u2f((u16)rA[3]) + wB * u2f((u16)rB[3]) + wC * u2f((u16)rC[3]) + wD * u2f((u16)rD[3]);
      f4 += wA * u2f((u16)rA[4]) + wB * u2f((u16)rB[4]) + wC * u2f((u16)rC[4]) + wD * u2f((u16)rD[4]);
      f5 += wA * u2f((u16)rA[5]) + wB * u2f((u16)rB[5]) + wC * u2f((u16)rC[5]) + wD * u2f((u16)rD[5]);
      f6 += wA * u2f((u16)rA[6]) + wB * u2f((u16)rB[6]) + wC * u2f((u16)rC[6]) + wD * u2f((u16)rD[6]);
      f7 += wA * u2f((u16)rA[7]) + wB * u2f((u16)rB[7]) + wC * u2f((u16)rC[7]) + wD * u2f((u16)rD[7]);
    }
    for (; i + 2 <= end; i += 2) {
      int2 eA = ef[i + half];
      float wA = __int_as_float(eA.y);
      s8v rA = *(const s8v*)(hp + (size_t)eA.x * H + c0);
      f0 += wA * u2f((u16)rA[0]); f1 += wA * u2f((u16)rA[1]);
      f2 += wA * u2f((u16)rA[2]); f3 += wA * u2f((u16)rA[3]);
      f4 += wA * u2f((u16)rA[4]); f5 += wA * u2f((u16)rA[5]);
      f6 += wA * u2f((u16)rA[6]); f7 += wA * u2f((u16)rA[7]);
    }
    if (i < end && half == 0) {            // odd-degree tail: half 0 only
      int2 eA = ef[i];
      float wA = __int_as_float(eA.y);
      s8v rA = *(const s8v*)(hp + (size_t)eA.x * H + c0);
      f0 += wA * u2f((u16)rA[0]); f1 += wA * u2f((u16)rA[1]);
      f2 += wA * u2f((u16)rA[2]); f3 += wA * u2f((u16)rA[3]);
      f4 += wA * u2f((u16)rA[4]); f5 += wA * u2f((u16)rA[5]);
      f6 += wA * u2f((u16)rA[6]); f7 += wA * u2f((u16)rA[7]);
    }
    f0 += __shfl_xor(f0, 32); f1 += __shfl_xor(f1, 32);
    f2 += __shfl_xor(f2, 32); f3 += __shfl_xor(f3, 32);
    f4 += __shfl_xor(f4, 32); f5 += __shfl_xor(f5, 32);
    f6 += __shfl_xor(f6, 32); f7 += __shfl_xor(f7, 32);
    if (half == 0) {
      s8v o;
      o[0] = (short)f2u(f0); o[1] = (short)f2u(f1);
      o[2] = (short)f2u(f2); o[3] = (short)f2u(f3);
      o[4] = (short)f2u(f4); o[5] = (short)f2u(f5);
      o[6] = (short)f2u(f6); o[7] = (short)f2u(f7);
      *(s8v*)((u16*)sh + (size_t)d * H + c0) = o;
    }
  }
}

// ---------------- MFMA GEMM: C[M,Nc] = A[M,K] @ Bt[Nc,K]^T ----------------
template <int OUT_F32>
__global__ __launch_bounds__(256) void k_gemm(const bf16* __restrict__ A,
                                              const bf16* __restrict__ Bt,
                                              void* __restrict__ Cv,
                                              const float* __restrict__ bias,
                                              int M, int K, int Nc,
                                              size_t sBt, size_t sC) {
  __shared__ short As[128][40];
  __shared__ short Bs[64][40];
  int gm = blockIdx.x * 128, gn = blockIdx.y * 64;
  Bt += (size_t)blockIdx.z * sBt;
  size_t zc = (size_t)blockIdx.z * sC;
  int tid = threadIdx.x, w = tid >> 6, lane = tid & 63;
  int l15 = lane & 15, koff = (lane >> 4) * 8;
  f4v acc[2][4];
#pragma unroll
  for (int i = 0; i < 2; i++)
#pragma unroll
    for (int j = 0; j < 4; j++) acc[i][j] = (f4v)0.f;

  for (int kt = 0; kt < K; kt += 32) {
#pragma unroll
    for (int c = 0; c < 2; c++) {
      int ch = tid + c * 256;
      int row = ch >> 2, seg = ch & 3;
      *(float4*)&As[row][seg * 8] =
          *(const float4*)(A + (size_t)(gm + row) * K + kt + seg * 8);
    }
    {
      int row = tid >> 2, seg = tid & 3;
      *(float4*)&Bs[row][seg * 8] =
          *(const float4*)(Bt + (size_t)(gn + row) * K + kt + seg * 8);
    }
    __syncthreads();
    s8v af[2], bf[4];
#pragma unroll
    for (int rt = 0; rt < 2; rt++) af[rt] = *(const s8v*)&As[w * 32 + rt * 16 + l15][koff];
#pragma unroll
    for (int ct = 0; ct < 4; ct++) bf[ct] = *(const s8v*)&Bs[ct * 16 + l15][koff];
#pragma unroll
    for (int rt = 0; rt < 2; rt++)
#pragma unroll
      for (int ct = 0; ct < 4; ct++) acc[rt][ct] = MFMA16(af[rt], bf[ct], acc[rt][ct]);
    __syncthreads();
  }
#pragma unroll
  for (int rt = 0; rt < 2; rt++)
#pragma unroll
    for (int ct = 0; ct < 4; ct++)
#pragma unroll
      for (int r = 0; r < 4; r++) {
        int row = gm + w * 32 + rt * 16 + (lane >> 4) * 4 + r;
        int col = gn + ct * 16 + l15;
        float v = acc[rt][ct][r];
        if (OUT_F32) ((float*)Cv)[zc + (size_t)row * Nc + col] = v + bias[col];
        else         ((bf16*)Cv)[zc + (size_t)row * Nc + col] = __float2bfloat16(v);
      }
}

// ---------------- fused GRU, 128x64 tile, 2-phase pipelined staging ---------
// r13: GRU is LDS-read-BW-bound (112 KB/block-step; 59/73.7 us is LDS). Wave
// decomposition switched M-split -> N-SPLIT: each wave owns 16 cols x all 128
// rows, so each wave reads only its own 6 B fragments (was all 24; -75% B
// traffic) while A/H reads rise 4x (small term). Per-step reads 112->88 KB
// (-21%). Accumulator count per thread UNCHANGED (128 f32) -> no spill at
// (256,2). Staging/barrier structure untouched (validated r6/r8/r10).
#define GRU_STAGE(Aarr, Harr, Barr, kt)                   \
  {                                                       \
    gl16(&Aarr[tid * 8],            Ap  + (kt));          \
    gl16(&Aarr[2048 + tid * 8],     Ap  + rstep + (kt));  \
    gl16(&Harr[tid * 8],            Hp  + (kt));          \
    gl16(&Harr[2048 + tid * 8],     Hp  + rstep + (kt));  \
    gl16(&Barr[tid * 8],            BiP + (kt));          \
    gl16(&Barr[2048 + tid * 8],     BiP + HH + (kt));     \
    gl16(&Barr[2 * 2048 + tid * 8], BiP + 2 * HH + (kt)); \
    gl16(&Barr[3 * 2048 + tid * 8], BhP + (kt));          \
    gl16(&Barr[4 * 2048 + tid * 8], BhP + HH + (kt));     \
    gl16(&Barr[5 * 2048 + tid * 8], BhP + 2 * HH + (kt)); \
  }

// N-split compute: wave w owns output cols [w*16, w*16+16). B fragments read
// once per step (6 reads); A/H fragments streamed over 8 row-tiles.
#define GRU_COMPUTE(Aarr, Harr, Barr)                                       \
  {                                                                         \
    int brow = ((w << 4) + l15) * 32 + koff;                                \
    s8v bRi = *(const s8v*)&Barr[brow];                                     \
    s8v bZi = *(const s8v*)&Barr[2048 + brow];                              \
    s8v bNi = *(const s8v*)&Barr[2 * 2048 + brow];                          \
    s8v bRh = *(const s8v*)&Barr[3 * 2048 + brow];                          \
    s8v bZh = *(const s8v*)&Barr[4 * 2048 + brow];                          \
    s8v bNh = *(const s8v*)&Barr[5 * 2048 + brow];                          \
    _Pragma("unroll")                                                       \
    for (int rt = 0; rt < 8; rt++) {                                        \
      int arow = (rt * 16 + l15) * 32 + koff;                               \
      s8v fa = *(const s8v*)&Aarr[arow];                                    \
      s8v fh = *(const s8v*)&Harr[arow];                                    \
      accR[rt]  = MFMA16(fa, bRi, accR[rt]);                                \
      accR[rt]  = MFMA16(fh, bRh, accR[rt]);                                \
      accZ[rt]  = MFMA16(fa, bZi, accZ[rt]);                                \
      accZ[rt]  = MFMA16(fh, bZh, accZ[rt]);                                \
      accNi[rt] = MFMA16(fa, bNi, accNi[rt]);                               \
      accNh[rt] = MFMA16(fh, bNh, accNh[rt]);                               \
    }                                                                       \
  }

__global__ __launch_bounds__(256, 2) void k_gru_mfma(const bf16* __restrict__ Ash,
                                                     const bf16* __restrict__ Ah,
                                                     const bf16* __restrict__ Wi,  // Ucomb_l [3H][H]
                                                     const bf16* __restrict__ Wh,  // w_hh [3H][H]
                                                     const float* __restrict__ bi,
                                                     const float* __restrict__ bh,
                                                     bf16* __restrict__ hn,
                                                     int M, int H) {
  __shared__ __align__(16) short Aa0[128 * 32], Aa1[128 * 32];
  __shared__ __align__(16) short Hs0[128 * 32], Hs1[128 * 32];
  __shared__ __align__(16) short Bs0[6 * 64 * 32], Bs1[6 * 64 * 32];

  // XCD-chunked bijective swizzle (grid is 1D: nwgx * nwgy blocks)
  int nwgx = H >> 6;                      // gcol blocks (4)
  int nwg = gridDim.x;
  int bid = blockIdx.x;
  int wg = bid;
  if ((nwg & 7) == 0) { int cpx = nwg >> 3; wg = (bid & 7) * cpx + (bid >> 3); }
  int gcol = (wg % nwgx) * 64;
  int gm = (wg / nwgx) * 128;

  int tid = threadIdx.x, w = tid >> 6, lane = tid & 63;
  int l15 = lane & 15, koff = (lane >> 4) * 8;
  f4v accR[8], accZ[8], accNi[8], accNh[8];
#pragma unroll
  for (int rt = 0; rt < 8; rt++) {
    accR[rt] = (f4v)0.f; accZ[rt] = (f4v)0.f;
    accNi[rt] = (f4v)0.f; accNh[rt] = (f4v)0.f;
  }

  // per-lane staging source pointers (16B-aligned)
  int arow = tid >> 2, aseg = tid & 3;
  const bf16* Ap  = Ash + (size_t)(gm + arow) * H + aseg * 8;
  const bf16* Hp  = Ah  + (size_t)(gm + arow) * H + aseg * 8;
  const bf16* BiP = Wi  + (size_t)(gcol + arow) * H + aseg * 8;  // rows 0..63
  const bf16* BhP = Wh  + (size_t)(gcol + arow) * H + aseg * 8;
  size_t HH = (size_t)H * H;
  size_t rstep = (size_t)64 * H;

  int nk = H >> 5;                         // K-steps (8)
  GRU_STAGE(Aa0, Hs0, Bs0, 0);
  __syncthreads();                         // drains vmcnt: tile 0 ready
  for (int t = 0; t < nk; t += 2) {
    int kt = t << 5;
    if (t + 1 < nk) GRU_STAGE(Aa1, Hs1, Bs1, kt + 32);  // issue next FIRST
    GRU_COMPUTE(Aa0, Hs0, Bs0);                          // overlap with loads
    __syncthreads();                                     // one drain per step
    if (t + 2 < nk) GRU_STAGE(Aa0, Hs0, Bs0, kt + 64);
    if (t + 1 < nk) GRU_COMPUTE(Aa1, Hs1, Bs1);
    __syncthreads();
  }

  // epilogue: wave w owns cols [gcol + w*16, +16); bias loaded once per thread
  {
    int col = gcol + (w << 4) + l15;
    float br  = bi[col] + bh[col];
    float bz  = bi[H + col] + bh[H + col];
    float bin = bi[2 * H + col], bhn = bh[2 * H + col];
#pragma unroll
    for (int rt = 0; rt < 8; rt++)
#pragma unroll
      for (int r = 0; r < 4; r++) {
        int row = gm + rt * 16 + (lane >> 4) * 4 + r;
        float rr = sigm(accR[rt][r] + br);
        float zz = sigm(accZ[rt][r] + bz);
        float nn = ftanh(accNi[rt][r] + bin + rr * (accNh[rt][r] + bhn));
        float hv = b2f(Ah[(size_t)row * H + col]);
        hn[(size_t)row * H + col] = __float2bfloat16((1.f - zz) * nn + zz * hv);
      }
  }
}

static inline size_t alg(size_t x) { return (x + 255) & ~(size_t)255; }
static inline int cdiv(int a, int b) { return (a + b - 1) / b; }

extern "C" void kernel_launch(void* const* d_in, const int* in_sizes, int n_in,
                              void* d_out, int out_size, void* d_ws, size_t ws_size,
                              hipStream_t stream) {
  (void)out_size; (void)ws_size;
  int s = (n_in >= 14) ? 0 : -1;
  const int*   x     = (const int*)d_in[0];
  const int*   ei    = (const int*)d_in[1];
  const float* ew    = (const float*)d_in[2];
  const int*   gidx  = (const int*)d_in[3];
  const float* enc   = (const float*)d_in[5 + s];
  const float* emb   = (const float*)d_in[6 + s];
  const float* ggcw  = (const float*)d_in[7 + s];
  const float* w_ih  = (const float*)d_in[8 + s];
  const float* w_hh  = (const float*)d_in[9 + s];
  const float* b_ih  = (const float*)d_in[10 + s];
  const float* b_hh  = (const float*)d_in[11 + s];
  const float* out_w = (const float*)d_in[12 + s];
  const float* out_b = (const float*)d_in[13 + s];
  float* out = (float*)d_out;

  int N   = in_sizes[0];
  int E   = in_sizes[2];
  int BL  = in_sizes[3];
  int H   = in_sizes[5 + s] / BL;
  int LG  = in_sizes[7 + s] / (H * H);
  int OUT = in_sizes[12 + s] / (2 * H);

  size_t nh = (size_t)N * H;
  size_t hh3 = (size_t)3 * H * H;
  int nb = cdiv(N, 256);
  char* p = (char*)d_ws;
  size_t off = 0;
  bf16* wihB  = (bf16*)(p + off); off = alg(off + hh3 * 2);
  bf16* whhB  = (bf16*)(p + off); off = alg(off + hh3 * 2);
  bf16* outwB = (bf16*)(p + off); off = alg(off + (size_t)OUT * 2 * H * 2);
  bf16* ggcwB = (bf16*)(p + off); off = alg(off + (size_t)LG * H * H * 2);
  bf16* Ucomb = (bf16*)(p + off); off = alg(off + (size_t)LG * hh3 * 2);
  bf16* hA    = (bf16*)(p + off); off = alg(off + nh * 2);
  bf16* hB    = (bf16*)(p + off); off = alg(off + nh * 2);
  bf16* shB   = (bf16*)(p + off); off = alg(off + nh * 2);
  bf16* catA  = (bf16*)(p + off); off = alg(off + (size_t)BL * 2 * H * 2);
  int* deg    = (int*)(p + off);  off = alg(off + (size_t)cdiv(N, 4) * 16);
  int* rowptr = (int*)(p + off);  off = alg(off + (size_t)(N + 1) * 4);
  int* rank   = (int*)(p + off);  off = alg(off + (size_t)E * 4);
  int2* ef    = (int2*)(p + off); off = alg(off + (size_t)E * 8);
  int* bsum   = (int*)(p + off);  off = alg(off + (size_t)nb * 4);
  int* boff   = (int*)(p + off);  off = alg(off + (size_t)nb * 4);

  // fused prep: embed + 4 weight casts + deg zero, one launch
  int q0 = (int)(hh3 >> 2), q1 = q0, q2 = (OUT * 2 * H) >> 2,
      q3 = (LG * H * H) >> 2;
  int nz = cdiv(N, 4);
  int prep_total = N * (H >> 2) + q0 + q1 + q2 + q3 + nz;
  k_prep<<<cdiv(prep_total, 256), 256, 0, stream>>>(
      x, emb, hA, w_ih, w_hh, out_w, ggcw, wihB, whhB, outwB, ggcwB,
      q0, q1, q2, q3, (int4*)deg, N, H, nz);
  // Ucomb_l[c][k] = sum_p w_ih[c][p] * ggcw_l[k][p] -- all LG layers in ONE launch
  k_gemm<0><<<dim3(3 * H / 128, H / 64, LG), 256, 0, stream>>>(
      wihB, ggcwB, Ucomb, nullptr, 3 * H, H, H, (size_t)H * H, hh3);

  // CSR build: hist captures per-edge rank (atomic return value); scan builds
  // rowptr; fill is an atomic-free XCD-partitioned scatter.
  k_hist<<<cdiv(E, 256), 256, 0, stream>>>(ei, deg, rank, E);
  k_scan1<<<nb, 256, 0, stream>>>(deg, bsum, N);
  k_scan2<<<1, 256, 0, stream>>>(bsum, boff, nb);
  k_scan3<<<nb, 256, 0, stream>>>(deg, boff, rowptr, N);
  k_fill<<<2048, 256, 0, stream>>>(ei, ew, rowptr, rank, ef, E, N);

  bf16* h = hA;
  bf16* hn = hB;
  for (int l = 0; l < LG; l++) {
    k_aggregate<<<cdiv(N, 4), 256, 0, stream>>>(rowptr, ef, h, shB, N, H);
    k_gru_mfma<<<dim3((H / 64) * (N / 128)), 256, 0, stream>>>(
        shB, h, Ucomb + (size_t)l * hh3, whhB, b_ih, b_hh, hn, N, H);
    bf16* t = h; h = hn; hn = t;
  }
  k_cat<<<cdiv(BL * 2 * H, 256), 256, 0, stream>>>(h, gidx, enc, catA, BL, H);
  k_gemm<1><<<dim3(BL / 128, OUT / 64, 1), 256, 0, stream>>>(
      catA, outwB, out, out_b, BL, 2 * H, OUT, 0, 0);
}